// Round 1
// baseline (3136.880 us; speedup 1.0000x reference)
//
#include <hip/hip_runtime.h>
#include <math.h>

#define NN 100000
#define EE 800000
#define CC 47
#define HH 128

// ---------------- count labels (once) ----------------
__global__ __launch_bounds__(256) void count_kernel(const int* __restrict__ label,
                                                    float* __restrict__ cnt, int n) {
    __shared__ float lc[CC];
    if (threadIdx.x < CC) lc[threadIdx.x] = 0.0f;
    __syncthreads();
    for (int i = blockIdx.x * blockDim.x + threadIdx.x; i < n; i += gridDim.x * blockDim.x)
        atomicAdd(&lc[label[i]], 1.0f);
    __syncthreads();
    if (threadIdx.x < CC) atomicAdd(&cnt[threadIdx.x], lc[threadIdx.x]);
}

// ---------------- lin0: x = relu(xin @ W + b); also writes x0 ----------------
__global__ __launch_bounds__(256) void lin0_kernel(const float* __restrict__ xin,
                                                   const float* __restrict__ W,
                                                   const float* __restrict__ b,
                                                   float* __restrict__ x,
                                                   float* __restrict__ x0, int n) {
    __shared__ float Ws[HH * HH];
    __shared__ float xs[2][HH];
    for (int i = threadIdx.x; i < HH * HH; i += 256) Ws[i] = W[i];
    int local = threadIdx.x >> 7, h = threadIdx.x & 127;
    __syncthreads();
    for (int base = blockIdx.x * 2; base < n; base += gridDim.x * 2) {
        int nn = base + local;
        if (nn < n) xs[local][h] = xin[nn * HH + h];
        __syncthreads();
        if (nn < n) {
            float acc = b[h];
            #pragma unroll
            for (int k = 0; k < HH; k++) acc = fmaf(xs[local][k], Ws[k * HH + h], acc);
            float v = fmaxf(acc, 0.0f);
            x[nn * HH + h] = v;
            x0[nn * HH + h] = v;
        }
        __syncthreads();
    }
}

// ---------------- per-layer: segment sums of (x + 0.1*x0) by label ----------------
__global__ __launch_bounds__(256) void sums_kernel(const float* __restrict__ x,
                                                   const float* __restrict__ x0,
                                                   const int* __restrict__ label,
                                                   float* __restrict__ sums, int n) {
    __shared__ float ls[CC * HH];
    for (int i = threadIdx.x; i < CC * HH; i += 256) ls[i] = 0.0f;
    __syncthreads();
    int local = threadIdx.x >> 7, h = threadIdx.x & 127;
    for (int nn = blockIdx.x * 2 + local; nn < n; nn += gridDim.x * 2) {
        int c = label[nn];
        float v = x[nn * HH + h] + 0.1f * x0[nn * HH + h];
        atomicAdd(&ls[c * HH + h], v);
    }
    __syncthreads();
    for (int i = threadIdx.x; i < CC * HH; i += 256) atomicAdd(&sums[i], ls[i]);
}

// ---------------- centers -> normalized diffs -> cm contraction -> rcm [C,H] ----------------
__global__ __launch_bounds__(128) void rcm_kernel(const float* __restrict__ sums,
                                                  const float* __restrict__ cnt,
                                                  const float* __restrict__ cm,
                                                  float* __restrict__ rcm) {
    __shared__ float cs[CC * HH];
    __shared__ float red[HH];
    int h = threadIdx.x;
    int i = blockIdx.x;
    for (int idx = h; idx < CC * HH; idx += 128) {
        int c = idx >> 7;
        cs[idx] = sums[idx] / fmaxf(cnt[c], 1.0f);
    }
    __syncthreads();
    float ci = cs[i * HH + h];
    float acc = 0.0f;
    for (int j = 0; j < CC; j++) {
        float d = ci - cs[j * HH + h];
        red[h] = d * d;
        __syncthreads();
        for (int s = 64; s > 0; s >>= 1) {
            if (h < s) red[h] += red[h + s];
            __syncthreads();
        }
        float nrm = sqrtf(red[0]);
        if (nrm == 0.0f) nrm = 1.0f;
        acc = fmaf(cm[i * CC + j], d / nrm, acc);
        __syncthreads();
    }
    rcm[i * HH + h] = acc;
}

// ---------------- edge scatter: agg[dst] += x[src] * w ----------------
__global__ __launch_bounds__(256) void scatter_kernel(const float* __restrict__ x,
                                                      const int* __restrict__ src,
                                                      const int* __restrict__ dst,
                                                      const float* __restrict__ ew,
                                                      float* __restrict__ agg, int e) {
    int idx = blockIdx.x * 2 + (threadIdx.x >> 7);
    int h = threadIdx.x & 127;
    if (idx < e) {
        int s = src[idx], d = dst[idx];
        float w = ew[idx];
        atomicAdd(&agg[d * HH + h], x[s * HH + h] * w);
    }
}

// ---------------- combine (in place into agg): 0.9*(0.5x + 0.5 p@rcm + 0.5 agg) + 0.1 x0 ----------------
__global__ __launch_bounds__(256) void combine_kernel(const float* __restrict__ x,
                                                      const float* __restrict__ x0,
                                                      const float* __restrict__ p,
                                                      const float* __restrict__ rcm,
                                                      float* __restrict__ agg, int n) {
    __shared__ float rs[CC * HH];
    for (int i = threadIdx.x; i < CC * HH; i += 256) rs[i] = rcm[i];
    __syncthreads();
    int local = threadIdx.x >> 7, h = threadIdx.x & 127;
    for (int nn = blockIdx.x * 2 + local; nn < n; nn += gridDim.x * 2) {
        const float* pn = p + nn * CC;
        float pr = 0.0f;
        #pragma unroll
        for (int c = 0; c < CC; c++) pr = fmaf(pn[c], rs[c * HH + h], pr);
        float v = 0.5f * x[nn * HH + h] + 0.5f * pr + 0.5f * agg[nn * HH + h];
        v = 0.9f * v + 0.1f * x0[nn * HH + h];
        agg[nn * HH + h] = v;
    }
}

// ---------------- conv: x = relu((1-beta)*t + beta*(t @ W)) ----------------
__global__ __launch_bounds__(256) void conv_kernel(const float* __restrict__ t,
                                                   const float* __restrict__ W,
                                                   float* __restrict__ x, float beta, int n) {
    __shared__ float Ws[HH * HH];
    __shared__ float ts[2][HH];
    for (int i = threadIdx.x; i < HH * HH; i += 256) Ws[i] = W[i];
    int local = threadIdx.x >> 7, h = threadIdx.x & 127;
    __syncthreads();
    for (int base = blockIdx.x * 2; base < n; base += gridDim.x * 2) {
        int nn = base + local;
        if (nn < n) ts[local][h] = t[nn * HH + h];
        __syncthreads();
        if (nn < n) {
            float acc = 0.0f;
            #pragma unroll
            for (int k = 0; k < HH; k++) acc = fmaf(ts[local][k], Ws[k * HH + h], acc);
            float v = (1.0f - beta) * ts[local][h] + beta * acc;
            x[nn * HH + h] = fmaxf(v, 0.0f);
        }
        __syncthreads();
    }
}

// ---------------- final: out = x @ W1 + b1  [N,47] ----------------
__global__ __launch_bounds__(256) void final_kernel(const float* __restrict__ x,
                                                    const float* __restrict__ W,
                                                    const float* __restrict__ b,
                                                    float* __restrict__ out, int n) {
    __shared__ float Ws[HH * CC];
    for (int i = threadIdx.x; i < HH * CC; i += 256) Ws[i] = W[i];
    __syncthreads();
    int grp = threadIdx.x >> 6;
    int lane = threadIdx.x & 63;
    for (int nn = blockIdx.x * 4 + grp; nn < n; nn += gridDim.x * 4) {
        if (lane < CC) {
            const float* xr = x + nn * HH;
            float acc = b[lane];
            #pragma unroll
            for (int k = 0; k < HH; k++) acc = fmaf(xr[k], Ws[k * CC + lane], acc);
            out[nn * CC + lane] = acc;
        }
    }
}

extern "C" void kernel_launch(void* const* d_in, const int* in_sizes, int n_in,
                              void* d_out, int out_size, void* d_ws, size_t ws_size,
                              hipStream_t stream) {
    const float* x_in   = (const float*)d_in[0];
    const int*   ei     = (const int*)d_in[1];
    const float* ew     = (const float*)d_in[2];
    const int*   label  = (const int*)d_in[3];
    const float* p      = (const float*)d_in[4];
    const float* cm     = (const float*)d_in[5];
    const float* lin0_w = (const float*)d_in[6];
    const float* lin0_b = (const float*)d_in[7];
    const float* lin1_w = (const float*)d_in[8];
    const float* lin1_b = (const float*)d_in[9];
    const float* conv_w = (const float*)d_in[10];
    float* out = (float*)d_out;

    const int* src = ei;
    const int* dst = ei + EE;

    float* ws = (float*)d_ws;
    float* x    = ws;                 // N*H
    float* x0   = x + (size_t)NN * HH;
    float* agg  = x0 + (size_t)NN * HH;
    float* sums = agg + (size_t)NN * HH;
    float* cnt  = sums + CC * HH;
    float* rcm  = cnt + 64;

    // label counts (constant across layers)
    hipMemsetAsync(cnt, 0, CC * sizeof(float), stream);
    count_kernel<<<256, 256, 0, stream>>>(label, cnt, NN);

    // input linear + relu
    lin0_kernel<<<1024, 256, 0, stream>>>(x_in, lin0_w, lin0_b, x, x0, NN);

    const float betas[4] = {logf(0.5f / 1.0f + 1.0f), logf(0.5f / 2.0f + 1.0f),
                            logf(0.5f / 3.0f + 1.0f), logf(0.5f / 4.0f + 1.0f)};

    for (int i = 0; i < 4; i++) {
        hipMemsetAsync(sums, 0, CC * HH * sizeof(float), stream);
        sums_kernel<<<512, 256, 0, stream>>>(x, x0, label, sums, NN);
        rcm_kernel<<<CC, 128, 0, stream>>>(sums, cnt, cm, rcm);
        hipMemsetAsync(agg, 0, (size_t)NN * HH * sizeof(float), stream);
        scatter_kernel<<<EE / 2, 256, 0, stream>>>(x, src, dst, ew, agg, EE);
        combine_kernel<<<2048, 256, 0, stream>>>(x, x0, p, rcm, agg, NN);
        conv_kernel<<<1024, 256, 0, stream>>>(agg, conv_w + (size_t)i * HH * HH, x, betas[i], NN);
    }

    final_kernel<<<4096, 256, 0, stream>>>(x, lin1_w, lin1_b, out, NN);
}

// Round 2
// 2227.510 us; speedup vs baseline: 1.4082x; 1.4082x over previous
//
#include <hip/hip_runtime.h>
#include <math.h>

#define NN 100000
#define EE 800000
#define CC 47
#define HH 128

// ---------------- count labels (once) ----------------
__global__ __launch_bounds__(256) void count_kernel(const int* __restrict__ label,
                                                    float* __restrict__ cnt, int n) {
    __shared__ float lc[CC];
    if (threadIdx.x < CC) lc[threadIdx.x] = 0.0f;
    __syncthreads();
    for (int i = blockIdx.x * blockDim.x + threadIdx.x; i < n; i += gridDim.x * blockDim.x)
        atomicAdd(&lc[label[i]], 1.0f);
    __syncthreads();
    if (threadIdx.x < CC) atomicAdd(&cnt[threadIdx.x], lc[threadIdx.x]);
}

// ---------------- CSR build ----------------
__global__ __launch_bounds__(256) void hist_kernel(const int* __restrict__ dst,
                                                   int* __restrict__ deg, int e) {
    int i = blockIdx.x * 256 + threadIdx.x;
    if (i < e) atomicAdd(&deg[dst[i]], 1);
}

// inclusive scan of 512-element chunks; chunk-inclusive goes to rowptr[i+1], chunk total to bsum
__global__ __launch_bounds__(256) void scan_block_kernel(const int* __restrict__ deg,
                                                         int* __restrict__ rowptr,
                                                         int* __restrict__ bsum, int n) {
    __shared__ int ls[256];
    int b = blockIdx.x, t = threadIdx.x;
    int i0 = b * 512 + 2 * t;
    int a0 = (i0 < n) ? deg[i0] : 0;
    int a1 = (i0 + 1 < n) ? deg[i0 + 1] : 0;
    int val = a0 + a1;
    ls[t] = val;
    __syncthreads();
    for (int off = 1; off < 256; off <<= 1) {
        int add = (t >= off) ? ls[t - off] : 0;
        __syncthreads();
        val += add;
        ls[t] = val;
        __syncthreads();
    }
    int incl1 = val;
    int incl0 = val - a1;
    if (i0 < n) rowptr[i0 + 1] = incl0;
    if (i0 + 1 < n) rowptr[i0 + 2] = incl1;
    if (t == 255) bsum[b] = val;
}

__global__ __launch_bounds__(256) void scan_bsum_kernel(int* __restrict__ bsum, int nb) {
    __shared__ int ls[256];
    int t = threadIdx.x;
    int v = (t < nb) ? bsum[t] : 0;
    int orig = v;
    ls[t] = v;
    __syncthreads();
    for (int off = 1; off < 256; off <<= 1) {
        int add = (t >= off) ? ls[t - off] : 0;
        __syncthreads();
        v += add;
        ls[t] = v;
        __syncthreads();
    }
    if (t < nb) bsum[t] = v - orig;  // exclusive block offset
}

__global__ __launch_bounds__(256) void add_off_kernel(int* __restrict__ rowptr,
                                                      const int* __restrict__ bsum, int n) {
    int i = blockIdx.x * 256 + threadIdx.x;
    if (i < n) rowptr[i + 1] += bsum[i >> 9];
    if (i == 0) rowptr[0] = 0;
}

__global__ __launch_bounds__(256) void fill_kernel(const int* __restrict__ src,
                                                   const int* __restrict__ dst,
                                                   const float* __restrict__ ew,
                                                   const int* __restrict__ rowptr,
                                                   int* __restrict__ cur,
                                                   int2* __restrict__ csr, int e) {
    int i = blockIdx.x * 256 + threadIdx.x;
    if (i < e) {
        int d = dst[i];
        int pos = rowptr[d] + atomicAdd(&cur[d], 1);
        csr[pos] = make_int2(src[i], __float_as_int(ew[i]));
    }
}

// ---------------- lin0: x = relu(xin @ W + b); also writes x0 ----------------
__global__ __launch_bounds__(256) void lin0_kernel(const float* __restrict__ xin,
                                                   const float* __restrict__ W,
                                                   const float* __restrict__ b,
                                                   float* __restrict__ x,
                                                   float* __restrict__ x0, int n) {
    __shared__ float Ws[HH * HH];
    __shared__ float xs[2][HH];
    for (int i = threadIdx.x; i < HH * HH; i += 256) Ws[i] = W[i];
    int local = threadIdx.x >> 7, h = threadIdx.x & 127;
    __syncthreads();
    for (int base = blockIdx.x * 2; base < n; base += gridDim.x * 2) {
        int nn = base + local;
        if (nn < n) xs[local][h] = xin[nn * HH + h];
        __syncthreads();
        if (nn < n) {
            float acc = b[h];
            #pragma unroll
            for (int k = 0; k < HH; k++) acc = fmaf(xs[local][k], Ws[k * HH + h], acc);
            float v = fmaxf(acc, 0.0f);
            x[nn * HH + h] = v;
            x0[nn * HH + h] = v;
        }
        __syncthreads();
    }
}

// ---------------- per-layer: segment sums of (x + 0.1*x0) by label ----------------
__global__ __launch_bounds__(256) void sums_kernel(const float* __restrict__ x,
                                                   const float* __restrict__ x0,
                                                   const int* __restrict__ label,
                                                   float* __restrict__ sums, int n) {
    __shared__ float ls[CC * HH];
    for (int i = threadIdx.x; i < CC * HH; i += 256) ls[i] = 0.0f;
    __syncthreads();
    int local = threadIdx.x >> 7, h = threadIdx.x & 127;
    for (int nn = blockIdx.x * 2 + local; nn < n; nn += gridDim.x * 2) {
        int c = label[nn];
        float v = x[nn * HH + h] + 0.1f * x0[nn * HH + h];
        atomicAdd(&ls[c * HH + h], v);
    }
    __syncthreads();
    for (int i = threadIdx.x; i < CC * HH; i += 256) atomicAdd(&sums[i], ls[i]);
}

// ---------------- centers -> normalized diffs -> cm contraction -> rcm [C,H] ----------------
__global__ __launch_bounds__(128) void rcm_kernel(const float* __restrict__ sums,
                                                  const float* __restrict__ cnt,
                                                  const float* __restrict__ cm,
                                                  float* __restrict__ rcm) {
    __shared__ float cs[CC * HH];
    __shared__ float red[HH];
    int h = threadIdx.x;
    int i = blockIdx.x;
    for (int idx = h; idx < CC * HH; idx += 128) {
        int c = idx >> 7;
        cs[idx] = sums[idx] / fmaxf(cnt[c], 1.0f);
    }
    __syncthreads();
    float ci = cs[i * HH + h];
    float acc = 0.0f;
    for (int j = 0; j < CC; j++) {
        float d = ci - cs[j * HH + h];
        red[h] = d * d;
        __syncthreads();
        for (int s = 64; s > 0; s >>= 1) {
            if (h < s) red[h] += red[h + s];
            __syncthreads();
        }
        float nrm = sqrtf(red[0]);
        if (nrm == 0.0f) nrm = 1.0f;
        acc = fmaf(cm[i * CC + j], d / nrm, acc);
        __syncthreads();
    }
    rcm[i * HH + h] = acc;
}

// ---------------- fused: CSR gather (agg) + combine -> t ----------------
// t[n][h] = 0.45*x + 0.45*(p@rcm) + 0.45*agg + 0.1*x0
__global__ __launch_bounds__(256) void gather_combine_kernel(
    const float* __restrict__ x, const float* __restrict__ x0,
    const float* __restrict__ p, const float* __restrict__ rcm,
    const int* __restrict__ rowptr, const int2* __restrict__ csr,
    float* __restrict__ t, int n) {
    __shared__ float rs[CC * HH];
    for (int i = threadIdx.x; i < CC * HH; i += 256) rs[i] = rcm[i];
    __syncthreads();
    int wid = threadIdx.x >> 6, lane = threadIdx.x & 63;
    for (int nn = blockIdx.x * 4 + wid; nn < n; nn += gridDim.x * 4) {
        int beg = rowptr[nn], end = rowptr[nn + 1];
        float accx = 0.0f, accy = 0.0f;
        for (int chunk = beg; chunk < end; chunk += 64) {
            int cnt = min(64, end - chunk);
            int2 pr = make_int2(0, 0);
            if (lane < cnt) pr = csr[chunk + lane];
            for (int e2 = 0; e2 < cnt; e2++) {
                int s = __shfl(pr.x, e2);
                float w = __int_as_float(__shfl(pr.y, e2));
                const float2 xv = *(const float2*)(x + (size_t)s * HH + 2 * lane);
                accx = fmaf(w, xv.x, accx);
                accy = fmaf(w, xv.y, accy);
            }
        }
        // p @ rcm
        float pv = (lane < CC) ? p[(size_t)nn * CC + lane] : 0.0f;
        float prx = 0.0f, pry = 0.0f;
        #pragma unroll
        for (int c = 0; c < CC; c++) {
            float pc = __shfl(pv, c);
            const float2 rv = *(const float2*)(rs + c * HH + 2 * lane);
            prx = fmaf(pc, rv.x, prx);
            pry = fmaf(pc, rv.y, pry);
        }
        const float2 xc = *(const float2*)(x + (size_t)nn * HH + 2 * lane);
        const float2 xo = *(const float2*)(x0 + (size_t)nn * HH + 2 * lane);
        float2 outv;
        outv.x = 0.45f * xc.x + 0.45f * prx + 0.45f * accx + 0.1f * xo.x;
        outv.y = 0.45f * xc.y + 0.45f * pry + 0.45f * accy + 0.1f * xo.y;
        *(float2*)(t + (size_t)nn * HH + 2 * lane) = outv;
    }
}

// ---------------- conv: x = relu((1-beta)*t + beta*(t @ W)) ----------------
__global__ __launch_bounds__(256) void conv_kernel(const float* __restrict__ t,
                                                   const float* __restrict__ W,
                                                   float* __restrict__ x, float beta, int n) {
    __shared__ float Ws[HH * HH];
    __shared__ float ts[2][HH];
    for (int i = threadIdx.x; i < HH * HH; i += 256) Ws[i] = W[i];
    int local = threadIdx.x >> 7, h = threadIdx.x & 127;
    __syncthreads();
    for (int base = blockIdx.x * 2; base < n; base += gridDim.x * 2) {
        int nn = base + local;
        if (nn < n) ts[local][h] = t[nn * HH + h];
        __syncthreads();
        if (nn < n) {
            float acc = 0.0f;
            #pragma unroll
            for (int k = 0; k < HH; k++) acc = fmaf(ts[local][k], Ws[k * HH + h], acc);
            float v = (1.0f - beta) * ts[local][h] + beta * acc;
            x[nn * HH + h] = fmaxf(v, 0.0f);
        }
        __syncthreads();
    }
}

// ---------------- final: out = x @ W1 + b1  [N,47] ----------------
__global__ __launch_bounds__(256) void final_kernel(const float* __restrict__ x,
                                                    const float* __restrict__ W,
                                                    const float* __restrict__ b,
                                                    float* __restrict__ out, int n) {
    __shared__ float Ws[HH * CC];
    for (int i = threadIdx.x; i < HH * CC; i += 256) Ws[i] = W[i];
    __syncthreads();
    int grp = threadIdx.x >> 6;
    int lane = threadIdx.x & 63;
    for (int nn = blockIdx.x * 4 + grp; nn < n; nn += gridDim.x * 4) {
        if (lane < CC) {
            const float* xr = x + nn * HH;
            float acc = b[lane];
            #pragma unroll
            for (int k = 0; k < HH; k++) acc = fmaf(xr[k], Ws[k * CC + lane], acc);
            out[nn * CC + lane] = acc;
        }
    }
}

extern "C" void kernel_launch(void* const* d_in, const int* in_sizes, int n_in,
                              void* d_out, int out_size, void* d_ws, size_t ws_size,
                              hipStream_t stream) {
    const float* x_in   = (const float*)d_in[0];
    const int*   ei     = (const int*)d_in[1];
    const float* ew     = (const float*)d_in[2];
    const int*   label  = (const int*)d_in[3];
    const float* p      = (const float*)d_in[4];
    const float* cm     = (const float*)d_in[5];
    const float* lin0_w = (const float*)d_in[6];
    const float* lin0_b = (const float*)d_in[7];
    const float* lin1_w = (const float*)d_in[8];
    const float* lin1_b = (const float*)d_in[9];
    const float* conv_w = (const float*)d_in[10];
    float* out = (float*)d_out;

    const int* src = ei;
    const int* dst = ei + EE;

    const size_t NH = (size_t)NN * HH;
    float* ws = (float*)d_ws;
    float* x    = ws;
    float* x0   = x + NH;
    float* agg  = x0 + NH;
    float* sums = agg + NH;
    float* cnt  = sums + CC * HH;
    float* rcm  = cnt + 64;
    int*   deg    = (int*)(rcm + CC * HH);          // N ints (also cursor)
    int*   rowptr = deg + NN;                        // N+1 (+pad)
    int*   bsum   = rowptr + NN + 64;                // 256
    int2*  csr    = (int2*)(bsum + 256);             // E int2

    // ---- CSR build (once per call) ----
    hipMemsetAsync(deg, 0, NN * sizeof(int), stream);
    hist_kernel<<<(EE + 255) / 256, 256, 0, stream>>>(dst, deg, EE);
    const int NBLK = (NN + 511) / 512;
    scan_block_kernel<<<NBLK, 256, 0, stream>>>(deg, rowptr, bsum, NN);
    scan_bsum_kernel<<<1, 256, 0, stream>>>(bsum, NBLK);
    add_off_kernel<<<(NN + 255) / 256, 256, 0, stream>>>(rowptr, bsum, NN);
    hipMemsetAsync(deg, 0, NN * sizeof(int), stream);  // reuse as cursor
    fill_kernel<<<(EE + 255) / 256, 256, 0, stream>>>(src, dst, ew, rowptr, deg, csr, EE);

    // label counts (constant across layers)
    hipMemsetAsync(cnt, 0, CC * sizeof(float), stream);
    count_kernel<<<256, 256, 0, stream>>>(label, cnt, NN);

    // input linear + relu
    lin0_kernel<<<1024, 256, 0, stream>>>(x_in, lin0_w, lin0_b, x, x0, NN);

    const float betas[4] = {logf(0.5f / 1.0f + 1.0f), logf(0.5f / 2.0f + 1.0f),
                            logf(0.5f / 3.0f + 1.0f), logf(0.5f / 4.0f + 1.0f)};

    for (int i = 0; i < 4; i++) {
        hipMemsetAsync(sums, 0, CC * HH * sizeof(float), stream);
        sums_kernel<<<512, 256, 0, stream>>>(x, x0, label, sums, NN);
        rcm_kernel<<<CC, 128, 0, stream>>>(sums, cnt, cm, rcm);
        gather_combine_kernel<<<2048, 256, 0, stream>>>(x, x0, p, rcm, rowptr, csr, agg, NN);
        conv_kernel<<<1024, 256, 0, stream>>>(agg, conv_w + (size_t)i * HH * HH, x, betas[i], NN);
    }

    final_kernel<<<4096, 256, 0, stream>>>(x, lin1_w, lin1_b, out, NN);
}

// Round 3
// 1501.070 us; speedup vs baseline: 2.0898x; 1.4839x over previous
//
#include <hip/hip_runtime.h>
#include <math.h>

#define NN 100000
#define EE 800000
#define CC 47
#define HH 128

typedef __attribute__((ext_vector_type(8))) short short8v;
typedef __attribute__((ext_vector_type(4))) float float4v;

__device__ inline ushort f2bf(float f) {
    unsigned u = __float_as_uint(f);
    unsigned r = (u + 0x7fffu + ((u >> 16) & 1u)) >> 16;  // RNE
    return (ushort)r;
}

// ---------------- count labels (once) ----------------
__global__ __launch_bounds__(256) void count_kernel(const int* __restrict__ label,
                                                    float* __restrict__ cnt, int n) {
    __shared__ float lc[CC];
    if (threadIdx.x < CC) lc[threadIdx.x] = 0.0f;
    __syncthreads();
    for (int i = blockIdx.x * blockDim.x + threadIdx.x; i < n; i += gridDim.x * blockDim.x)
        atomicAdd(&lc[label[i]], 1.0f);
    __syncthreads();
    if (threadIdx.x < CC) atomicAdd(&cnt[threadIdx.x], lc[threadIdx.x]);
}

// ---------------- CSR build ----------------
__global__ __launch_bounds__(256) void hist_kernel(const int* __restrict__ dst,
                                                   int* __restrict__ deg, int e) {
    int i = blockIdx.x * 256 + threadIdx.x;
    if (i < e) atomicAdd(&deg[dst[i]], 1);
}

__global__ __launch_bounds__(256) void scan_block_kernel(const int* __restrict__ deg,
                                                         int* __restrict__ rowptr,
                                                         int* __restrict__ bsum, int n) {
    __shared__ int ls[256];
    int b = blockIdx.x, t = threadIdx.x;
    int i0 = b * 512 + 2 * t;
    int a0 = (i0 < n) ? deg[i0] : 0;
    int a1 = (i0 + 1 < n) ? deg[i0 + 1] : 0;
    int val = a0 + a1;
    ls[t] = val;
    __syncthreads();
    for (int off = 1; off < 256; off <<= 1) {
        int add = (t >= off) ? ls[t - off] : 0;
        __syncthreads();
        val += add;
        ls[t] = val;
        __syncthreads();
    }
    int incl1 = val;
    int incl0 = val - a1;
    if (i0 < n) rowptr[i0 + 1] = incl0;
    if (i0 + 1 < n) rowptr[i0 + 2] = incl1;
    if (t == 255) bsum[b] = val;
}

__global__ __launch_bounds__(256) void scan_bsum_kernel(int* __restrict__ bsum, int nb) {
    __shared__ int ls[256];
    int t = threadIdx.x;
    int v = (t < nb) ? bsum[t] : 0;
    int orig = v;
    ls[t] = v;
    __syncthreads();
    for (int off = 1; off < 256; off <<= 1) {
        int add = (t >= off) ? ls[t - off] : 0;
        __syncthreads();
        v += add;
        ls[t] = v;
        __syncthreads();
    }
    if (t < nb) bsum[t] = v - orig;
}

__global__ __launch_bounds__(256) void add_off_kernel(int* __restrict__ rowptr,
                                                      const int* __restrict__ bsum, int n) {
    int i = blockIdx.x * 256 + threadIdx.x;
    if (i < n) rowptr[i + 1] += bsum[i >> 9];
    if (i == 0) rowptr[0] = 0;
}

__global__ __launch_bounds__(256) void fill_kernel(const int* __restrict__ src,
                                                   const int* __restrict__ dst,
                                                   const float* __restrict__ ew,
                                                   const int* __restrict__ rowptr,
                                                   int* __restrict__ cur,
                                                   int2* __restrict__ csr, int e) {
    int i = blockIdx.x * 256 + threadIdx.x;
    if (i < e) {
        int d = dst[i];
        int pos = rowptr[d] + atomicAdd(&cur[d], 1);
        csr[pos] = make_int2(src[i], __float_as_int(ew[i]));
    }
}

// ---------------- pack weight [128][128] f32 -> MFMA B-fragment order bf16 ----------------
// Wp[(k>>3)*1024 + c*8 + (k&7)] = bf16(W[k][c])
__global__ __launch_bounds__(256) void pack_w_kernel(const float* __restrict__ W,
                                                     ushort* __restrict__ Wp) {
    int idx = blockIdx.x * 256 + threadIdx.x;  // 0..16383
    int k = idx >> 7, c = idx & 127;
    Wp[(k >> 3) * 1024 + c * 8 + (k & 7)] = f2bf(W[idx]);
}

// ---------------- MFMA GEMM core (shared by lin0/conv) ----------------
// Tile: 32 rows x 128 cols, K=128. 4 waves, wave w owns cols [32w,32w+32).
// A staged in LDS bf16 with XOR swizzle; B (packed) staged linear in LDS.
#define GEMM_PROLOGUE(SRC)                                                        \
    __shared__ ushort ts[32 * 128];                                               \
    __shared__ ushort wl[128 * 128];                                              \
    {                                                                             \
        const uint4* g4 = (const uint4*)Wp;                                       \
        uint4* l4 = (uint4*)wl;                                                   \
        for (int j = threadIdx.x; j < 2048; j += 256) l4[j] = g4[j];              \
    }                                                                             \
    const int lane = threadIdx.x & 63, wv = threadIdx.x >> 6;                     \
    const int sub = lane >> 4, r16 = lane & 15;                                   \
    const int wbase = wv * 32;                                                    \
    const int rowbase = blockIdx.x * 32;                                          \
    const float* tp = (SRC) + (size_t)rowbase * HH;                               \
    _Pragma("unroll")                                                             \
    for (int j = 0; j < 4; j++) {                                                 \
        int e = 4 * threadIdx.x + j * 1024;                                       \
        float4 f = *(const float4*)(tp + e);                                      \
        int r = e >> 7, c = e & 127;                                              \
        ushort4 b4 = make_ushort4(f2bf(f.x), f2bf(f.y), f2bf(f.z), f2bf(f.w));    \
        int off = (r * 256 + c * 2) ^ ((r & 7) << 4);                             \
        *(ushort4*)((char*)ts + off) = b4;                                        \
    }                                                                             \
    __syncthreads();                                                              \
    float4v acc[2][2] = {};                                                       \
    {                                                                             \
        const char* tsc = (const char*)ts;                                        \
        const int sw = (r16 & 7) << 4;                                            \
        _Pragma("unroll")                                                         \
        for (int ks = 0; ks < 4; ks++) {                                          \
            short8v a0 = *(const short8v*)(tsc + ((r16 * 256 + ks * 64 + sub * 16) ^ sw));        \
            short8v a1 = *(const short8v*)(tsc + (((16 + r16) * 256 + ks * 64 + sub * 16) ^ sw)); \
            int kb = (ks * 4 + sub) * 1024;                                       \
            short8v b0 = *(const short8v*)(wl + kb + (wbase + r16) * 8);          \
            short8v b1 = *(const short8v*)(wl + kb + (wbase + 16 + r16) * 8);     \
            acc[0][0] = __builtin_amdgcn_mfma_f32_16x16x32_bf16(a0, b0, acc[0][0], 0, 0, 0); \
            acc[0][1] = __builtin_amdgcn_mfma_f32_16x16x32_bf16(a0, b1, acc[0][1], 0, 0, 0); \
            acc[1][0] = __builtin_amdgcn_mfma_f32_16x16x32_bf16(a1, b0, acc[1][0], 0, 0, 0); \
            acc[1][1] = __builtin_amdgcn_mfma_f32_16x16x32_bf16(a1, b1, acc[1][1], 0, 0, 0); \
        }                                                                         \
    }

// lin0: x = x0 = relu(xin @ W + b)
__global__ __launch_bounds__(256) void lin0_mfma_kernel(const float* __restrict__ xin,
                                                        const ushort* __restrict__ Wp,
                                                        const float* __restrict__ bias,
                                                        float* __restrict__ x,
                                                        float* __restrict__ x0) {
    GEMM_PROLOGUE(xin)
    float bv[2] = {bias[wbase + r16], bias[wbase + 16 + r16]};
    #pragma unroll
    for (int mi = 0; mi < 2; mi++)
        #pragma unroll
        for (int ni = 0; ni < 2; ni++) {
            int col = wbase + ni * 16 + r16;
            #pragma unroll
            for (int r = 0; r < 4; r++) {
                int row = rowbase + mi * 16 + sub * 4 + r;
                float v = fmaxf(acc[mi][ni][r] + bv[ni], 0.0f);
                x[(size_t)row * HH + col] = v;
                x0[(size_t)row * HH + col] = v;
            }
        }
}

// conv: x = relu((1-beta)*t + beta*(t @ W))
__global__ __launch_bounds__(256) void conv_mfma_kernel(const float* __restrict__ t,
                                                        const ushort* __restrict__ Wp,
                                                        float* __restrict__ x, float beta) {
    GEMM_PROLOGUE(t)
    const float omb = 1.0f - beta;
    #pragma unroll
    for (int mi = 0; mi < 2; mi++)
        #pragma unroll
        for (int ni = 0; ni < 2; ni++) {
            int col = wbase + ni * 16 + r16;
            #pragma unroll
            for (int r = 0; r < 4; r++) {
                int row = rowbase + mi * 16 + sub * 4 + r;
                float tv = t[(size_t)row * HH + col];
                float v = omb * tv + beta * acc[mi][ni][r];
                x[(size_t)row * HH + col] = fmaxf(v, 0.0f);
            }
        }
}

// ---------------- per-layer: segment sums of (x + 0.1*x0) by label ----------------
__global__ __launch_bounds__(256) void sums_kernel(const float* __restrict__ x,
                                                   const float* __restrict__ x0,
                                                   const int* __restrict__ label,
                                                   float* __restrict__ sums, int n) {
    __shared__ float ls[CC * HH];
    for (int i = threadIdx.x; i < CC * HH; i += 256) ls[i] = 0.0f;
    __syncthreads();
    int local = threadIdx.x >> 7, h = threadIdx.x & 127;
    for (int nn = blockIdx.x * 2 + local; nn < n; nn += gridDim.x * 2) {
        int c = label[nn];
        float v = x[nn * HH + h] + 0.1f * x0[nn * HH + h];
        atomicAdd(&ls[c * HH + h], v);
    }
    __syncthreads();
    for (int i = threadIdx.x; i < CC * HH; i += 256) atomicAdd(&sums[i], ls[i]);
}

// ---------------- centers -> normalized diffs -> cm contraction -> rcm [C,H] ----------------
__global__ __launch_bounds__(128) void rcm_kernel(const float* __restrict__ sums,
                                                  const float* __restrict__ cnt,
                                                  const float* __restrict__ cm,
                                                  float* __restrict__ rcm) {
    __shared__ float cs[CC * HH];
    __shared__ float red[HH];
    int h = threadIdx.x;
    int i = blockIdx.x;
    for (int idx = h; idx < CC * HH; idx += 128) {
        int c = idx >> 7;
        cs[idx] = sums[idx] / fmaxf(cnt[c], 1.0f);
    }
    __syncthreads();
    float ci = cs[i * HH + h];
    float acc = 0.0f;
    for (int j = 0; j < CC; j++) {
        float d = ci - cs[j * HH + h];
        red[h] = d * d;
        __syncthreads();
        for (int s = 64; s > 0; s >>= 1) {
            if (h < s) red[h] += red[h + s];
            __syncthreads();
        }
        float nrm = sqrtf(red[0]);
        if (nrm == 0.0f) nrm = 1.0f;
        acc = fmaf(cm[i * CC + j], d / nrm, acc);
        __syncthreads();
    }
    rcm[i * HH + h] = acc;
}

// ---------------- fused: CSR gather (agg) + combine -> t ----------------
__global__ __launch_bounds__(256) void gather_combine_kernel(
    const float* __restrict__ x, const float* __restrict__ x0,
    const float* __restrict__ p, const float* __restrict__ rcm,
    const int* __restrict__ rowptr, const int2* __restrict__ csr,
    float* __restrict__ t, int n) {
    __shared__ float rs[CC * HH];
    for (int i = threadIdx.x; i < CC * HH; i += 256) rs[i] = rcm[i];
    __syncthreads();
    int wid = threadIdx.x >> 6, lane = threadIdx.x & 63;
    for (int nn = blockIdx.x * 4 + wid; nn < n; nn += gridDim.x * 4) {
        int beg = rowptr[nn], end = rowptr[nn + 1];
        float accx = 0.0f, accy = 0.0f;
        for (int chunk = beg; chunk < end; chunk += 64) {
            int cnt = min(64, end - chunk);
            int2 pr = make_int2(0, 0);
            if (lane < cnt) pr = csr[chunk + lane];
            for (int e2 = 0; e2 < cnt; e2++) {
                int s = __shfl(pr.x, e2);
                float w = __int_as_float(__shfl(pr.y, e2));
                const float2 xv = *(const float2*)(x + (size_t)s * HH + 2 * lane);
                accx = fmaf(w, xv.x, accx);
                accy = fmaf(w, xv.y, accy);
            }
        }
        float pv = (lane < CC) ? p[(size_t)nn * CC + lane] : 0.0f;
        float prx = 0.0f, pry = 0.0f;
        #pragma unroll
        for (int c = 0; c < CC; c++) {
            float pc = __shfl(pv, c);
            const float2 rv = *(const float2*)(rs + c * HH + 2 * lane);
            prx = fmaf(pc, rv.x, prx);
            pry = fmaf(pc, rv.y, pry);
        }
        const float2 xc = *(const float2*)(x + (size_t)nn * HH + 2 * lane);
        const float2 xo = *(const float2*)(x0 + (size_t)nn * HH + 2 * lane);
        float2 outv;
        outv.x = 0.45f * xc.x + 0.45f * prx + 0.45f * accx + 0.1f * xo.x;
        outv.y = 0.45f * xc.y + 0.45f * pry + 0.45f * accy + 0.1f * xo.y;
        *(float2*)(t + (size_t)nn * HH + 2 * lane) = outv;
    }
}

// ---------------- final: out = x @ W1 + b1  [N,47] ----------------
__global__ __launch_bounds__(256) void final_kernel(const float* __restrict__ x,
                                                    const float* __restrict__ W,
                                                    const float* __restrict__ b,
                                                    float* __restrict__ out, int n) {
    __shared__ float Ws[HH * CC];
    for (int i = threadIdx.x; i < HH * CC; i += 256) Ws[i] = W[i];
    __syncthreads();
    int grp = threadIdx.x >> 6;
    int lane = threadIdx.x & 63;
    for (int nn = blockIdx.x * 4 + grp; nn < n; nn += gridDim.x * 4) {
        if (lane < CC) {
            const float* xr = x + nn * HH;
            float acc = b[lane];
            #pragma unroll
            for (int k = 0; k < HH; k++) acc = fmaf(xr[k], Ws[k * CC + lane], acc);
            out[nn * CC + lane] = acc;
        }
    }
}

extern "C" void kernel_launch(void* const* d_in, const int* in_sizes, int n_in,
                              void* d_out, int out_size, void* d_ws, size_t ws_size,
                              hipStream_t stream) {
    const float* x_in   = (const float*)d_in[0];
    const int*   ei     = (const int*)d_in[1];
    const float* ew     = (const float*)d_in[2];
    const int*   label  = (const int*)d_in[3];
    const float* p      = (const float*)d_in[4];
    const float* cm     = (const float*)d_in[5];
    const float* lin0_w = (const float*)d_in[6];
    const float* lin0_b = (const float*)d_in[7];
    const float* lin1_w = (const float*)d_in[8];
    const float* lin1_b = (const float*)d_in[9];
    const float* conv_w = (const float*)d_in[10];
    float* out = (float*)d_out;

    const int* src = ei;
    const int* dst = ei + EE;

    const size_t NH = (size_t)NN * HH;
    float* ws = (float*)d_ws;
    float* x    = ws;
    float* x0   = x + NH;
    float* agg  = x0 + NH;
    float* sums = agg + NH;
    float* cnt  = sums + CC * HH;
    float* rcm  = cnt + 64;
    int*   deg    = (int*)(rcm + CC * HH);   // N ints; reused for Wp after CSR build
    int*   rowptr = deg + NN;
    int*   bsum   = rowptr + NN + 64;
    int2*  csr    = (int2*)(bsum + 256);

    // ---- CSR build (once per call) ----
    hipMemsetAsync(deg, 0, NN * sizeof(int), stream);
    hist_kernel<<<(EE + 255) / 256, 256, 0, stream>>>(dst, deg, EE);
    const int NBLK = (NN + 511) / 512;
    scan_block_kernel<<<NBLK, 256, 0, stream>>>(deg, rowptr, bsum, NN);
    scan_bsum_kernel<<<1, 256, 0, stream>>>(bsum, NBLK);
    add_off_kernel<<<(NN + 255) / 256, 256, 0, stream>>>(rowptr, bsum, NN);
    hipMemsetAsync(deg, 0, NN * sizeof(int), stream);  // reuse as cursor
    fill_kernel<<<(EE + 255) / 256, 256, 0, stream>>>(src, dst, ew, rowptr, deg, csr, EE);

    // ---- pack weights bf16 (deg region is free now) ----
    ushort* wp0 = (ushort*)deg;                // lin0: 16384 ushorts
    ushort* wpc = wp0 + 16384;                 // conv: 4 x 16384
    pack_w_kernel<<<64, 256, 0, stream>>>(lin0_w, wp0);
    for (int i = 0; i < 4; i++)
        pack_w_kernel<<<64, 256, 0, stream>>>(conv_w + (size_t)i * HH * HH, wpc + (size_t)i * 16384);

    // label counts (constant across layers)
    hipMemsetAsync(cnt, 0, CC * sizeof(float), stream);
    count_kernel<<<256, 256, 0, stream>>>(label, cnt, NN);

    // input linear + relu (N = 3125 * 32 exactly)
    lin0_mfma_kernel<<<NN / 32, 256, 0, stream>>>(x_in, wp0, lin0_b, x, x0);

    const float betas[4] = {logf(0.5f / 1.0f + 1.0f), logf(0.5f / 2.0f + 1.0f),
                            logf(0.5f / 3.0f + 1.0f), logf(0.5f / 4.0f + 1.0f)};

    for (int i = 0; i < 4; i++) {
        hipMemsetAsync(sums, 0, CC * HH * sizeof(float), stream);
        sums_kernel<<<512, 256, 0, stream>>>(x, x0, label, sums, NN);
        rcm_kernel<<<CC, 128, 0, stream>>>(sums, cnt, cm, rcm);
        gather_combine_kernel<<<2048, 256, 0, stream>>>(x, x0, p, rcm, rowptr, csr, agg, NN);
        conv_mfma_kernel<<<NN / 32, 256, 0, stream>>>(agg, wpc + (size_t)i * 16384, x, betas[i]);
    }

    final_kernel<<<4096, 256, 0, stream>>>(x, lin1_w, lin1_b, out, NN);
}

// Round 4
// 1459.760 us; speedup vs baseline: 2.1489x; 1.0283x over previous
//
#include <hip/hip_runtime.h>
#include <math.h>

#define NN 100000
#define EE 800000
#define CC 47
#define HH 128

typedef __attribute__((ext_vector_type(8))) short short8v;
typedef __attribute__((ext_vector_type(4))) float float4v;

__device__ inline ushort f2bf(float f) {
    unsigned u = __float_as_uint(f);
    unsigned r = (u + 0x7fffu + ((u >> 16) & 1u)) >> 16;  // RNE
    return (ushort)r;
}
__device__ inline float b2f(ushort u) { return __uint_as_float(((unsigned)u) << 16); }

// ---------------- count labels (once) ----------------
__global__ __launch_bounds__(256) void count_kernel(const int* __restrict__ label,
                                                    float* __restrict__ cnt, int n) {
    __shared__ float lc[CC];
    if (threadIdx.x < CC) lc[threadIdx.x] = 0.0f;
    __syncthreads();
    for (int i = blockIdx.x * blockDim.x + threadIdx.x; i < n; i += gridDim.x * blockDim.x)
        atomicAdd(&lc[label[i]], 1.0f);
    __syncthreads();
    if (threadIdx.x < CC) atomicAdd(&cnt[threadIdx.x], lc[threadIdx.x]);
}

// ---------------- CSR build ----------------
__global__ __launch_bounds__(256) void hist_kernel(const int* __restrict__ dst,
                                                   int* __restrict__ deg, int e) {
    int i = blockIdx.x * 256 + threadIdx.x;
    if (i < e) atomicAdd(&deg[dst[i]], 1);
}

__global__ __launch_bounds__(256) void scan_block_kernel(const int* __restrict__ deg,
                                                         int* __restrict__ rowptr,
                                                         int* __restrict__ bsum, int n) {
    __shared__ int ls[256];
    int b = blockIdx.x, t = threadIdx.x;
    int i0 = b * 512 + 2 * t;
    int a0 = (i0 < n) ? deg[i0] : 0;
    int a1 = (i0 + 1 < n) ? deg[i0 + 1] : 0;
    int val = a0 + a1;
    ls[t] = val;
    __syncthreads();
    for (int off = 1; off < 256; off <<= 1) {
        int add = (t >= off) ? ls[t - off] : 0;
        __syncthreads();
        val += add;
        ls[t] = val;
        __syncthreads();
    }
    int incl1 = val;
    int incl0 = val - a1;
    if (i0 < n) rowptr[i0 + 1] = incl0;
    if (i0 + 1 < n) rowptr[i0 + 2] = incl1;
    if (t == 255) bsum[b] = val;
}

__global__ __launch_bounds__(256) void scan_bsum_kernel(int* __restrict__ bsum, int nb) {
    __shared__ int ls[256];
    int t = threadIdx.x;
    int v = (t < nb) ? bsum[t] : 0;
    int orig = v;
    ls[t] = v;
    __syncthreads();
    for (int off = 1; off < 256; off <<= 1) {
        int add = (t >= off) ? ls[t - off] : 0;
        __syncthreads();
        v += add;
        ls[t] = v;
        __syncthreads();
    }
    if (t < nb) bsum[t] = v - orig;
}

__global__ __launch_bounds__(256) void add_off_kernel(int* __restrict__ rowptr,
                                                      const int* __restrict__ bsum, int n) {
    int i = blockIdx.x * 256 + threadIdx.x;
    if (i < n) rowptr[i + 1] += bsum[i >> 9];
    if (i == 0) rowptr[0] = 0;
}

__global__ __launch_bounds__(256) void fill_kernel(const int* __restrict__ src,
                                                   const int* __restrict__ dst,
                                                   const float* __restrict__ ew,
                                                   const int* __restrict__ rowptr,
                                                   int* __restrict__ cur,
                                                   int2* __restrict__ csr, int e) {
    int i = blockIdx.x * 256 + threadIdx.x;
    if (i < e) {
        int d = dst[i];
        int pos = rowptr[d] + atomicAdd(&cur[d], 1);
        csr[pos] = make_int2(src[i], __float_as_int(ew[i]));
    }
}

// ---------------- pack weight [128][128] f32 -> MFMA B-fragment order bf16 ----------------
__global__ __launch_bounds__(256) void pack_w_kernel(const float* __restrict__ W,
                                                     ushort* __restrict__ Wp) {
    int idx = blockIdx.x * 256 + threadIdx.x;  // 0..16383
    int k = idx >> 7, c = idx & 127;
    Wp[(k >> 3) * 1024 + c * 8 + (k & 7)] = f2bf(W[idx]);
}

// ---------------- lin0: x0 = xb = relu(xin @ W + b) ----------------
__global__ __launch_bounds__(256) void lin0_mfma_kernel(const float* __restrict__ xin,
                                                        const ushort* __restrict__ Wp,
                                                        const float* __restrict__ bias,
                                                        float* __restrict__ x0,
                                                        ushort* __restrict__ xb) {
    __shared__ ushort ts[32 * 128];
    __shared__ ushort wl[128 * 128];
    {
        const uint4* g4 = (const uint4*)Wp;
        uint4* l4 = (uint4*)wl;
        for (int j = threadIdx.x; j < 2048; j += 256) l4[j] = g4[j];
    }
    const int lane = threadIdx.x & 63, wv = threadIdx.x >> 6;
    const int sub = lane >> 4, r16 = lane & 15;
    const int wbase = wv * 32;
    const int rowbase = blockIdx.x * 32;
    const float* tp = xin + (size_t)rowbase * HH;
    #pragma unroll
    for (int j = 0; j < 4; j++) {
        int e = 4 * threadIdx.x + j * 1024;
        float4 f = *(const float4*)(tp + e);
        int r = e >> 7, c = e & 127;
        ushort4 b4 = make_ushort4(f2bf(f.x), f2bf(f.y), f2bf(f.z), f2bf(f.w));
        int off = (r * 256 + c * 2) ^ ((r & 7) << 4);
        *(ushort4*)((char*)ts + off) = b4;
    }
    __syncthreads();
    float4v acc[2][2] = {};
    {
        const char* tsc = (const char*)ts;
        const int sw = (r16 & 7) << 4;
        #pragma unroll
        for (int ks = 0; ks < 4; ks++) {
            short8v a0 = *(const short8v*)(tsc + ((r16 * 256 + ks * 64 + sub * 16) ^ sw));
            short8v a1 = *(const short8v*)(tsc + (((16 + r16) * 256 + ks * 64 + sub * 16) ^ sw));
            int kb = (ks * 4 + sub) * 1024;
            short8v b0 = *(const short8v*)(wl + kb + (wbase + r16) * 8);
            short8v b1 = *(const short8v*)(wl + kb + (wbase + 16 + r16) * 8);
            acc[0][0] = __builtin_amdgcn_mfma_f32_16x16x32_bf16(a0, b0, acc[0][0], 0, 0, 0);
            acc[0][1] = __builtin_amdgcn_mfma_f32_16x16x32_bf16(a0, b1, acc[0][1], 0, 0, 0);
            acc[1][0] = __builtin_amdgcn_mfma_f32_16x16x32_bf16(a1, b0, acc[1][0], 0, 0, 0);
            acc[1][1] = __builtin_amdgcn_mfma_f32_16x16x32_bf16(a1, b1, acc[1][1], 0, 0, 0);
        }
    }
    float bv[2] = {bias[wbase + r16], bias[wbase + 16 + r16]};
    #pragma unroll
    for (int mi = 0; mi < 2; mi++)
        #pragma unroll
        for (int ni = 0; ni < 2; ni++) {
            int col = wbase + ni * 16 + r16;
            #pragma unroll
            for (int r = 0; r < 4; r++) {
                int row = rowbase + mi * 16 + sub * 4 + r;
                float v = fmaxf(acc[mi][ni][r] + bv[ni], 0.0f);
                x0[(size_t)row * HH + col] = v;
                xb[(size_t)row * HH + col] = f2bf(v);
            }
        }
}

// ---------------- conv: xb = relu((1-beta)*t + beta*(t @ W)), t = tb (bf16) ----------------
__global__ __launch_bounds__(256) void conv_mfma_kernel(const ushort* __restrict__ tb,
                                                        const ushort* __restrict__ Wp,
                                                        ushort* __restrict__ xb, float beta) {
    __shared__ ushort ts[32 * 128];
    __shared__ ushort wl[128 * 128];
    {
        const uint4* g4 = (const uint4*)Wp;
        uint4* l4 = (uint4*)wl;
        for (int j = threadIdx.x; j < 2048; j += 256) l4[j] = g4[j];
    }
    const int lane = threadIdx.x & 63, wv = threadIdx.x >> 6;
    const int sub = lane >> 4, r16 = lane & 15;
    const int wbase = wv * 32;
    const int rowbase = blockIdx.x * 32;
    const ushort* tp = tb + (size_t)rowbase * HH;
    #pragma unroll
    for (int j = 0; j < 2; j++) {
        int cid = threadIdx.x + j * 256;   // 16B chunk id, 512 total
        int e = cid * 8;
        int r = e >> 7;
        int off = (e * 2) ^ ((r & 7) << 4);
        *(short8v*)((char*)ts + off) = *(const short8v*)(tp + e);
    }
    __syncthreads();
    float4v acc[2][2] = {};
    {
        const char* tsc = (const char*)ts;
        const int sw = (r16 & 7) << 4;
        #pragma unroll
        for (int ks = 0; ks < 4; ks++) {
            short8v a0 = *(const short8v*)(tsc + ((r16 * 256 + ks * 64 + sub * 16) ^ sw));
            short8v a1 = *(const short8v*)(tsc + (((16 + r16) * 256 + ks * 64 + sub * 16) ^ sw));
            int kb = (ks * 4 + sub) * 1024;
            short8v b0 = *(const short8v*)(wl + kb + (wbase + r16) * 8);
            short8v b1 = *(const short8v*)(wl + kb + (wbase + 16 + r16) * 8);
            acc[0][0] = __builtin_amdgcn_mfma_f32_16x16x32_bf16(a0, b0, acc[0][0], 0, 0, 0);
            acc[0][1] = __builtin_amdgcn_mfma_f32_16x16x32_bf16(a0, b1, acc[0][1], 0, 0, 0);
            acc[1][0] = __builtin_amdgcn_mfma_f32_16x16x32_bf16(a1, b0, acc[1][0], 0, 0, 0);
            acc[1][1] = __builtin_amdgcn_mfma_f32_16x16x32_bf16(a1, b1, acc[1][1], 0, 0, 0);
        }
    }
    const float omb = 1.0f - beta;
    #pragma unroll
    for (int mi = 0; mi < 2; mi++)
        #pragma unroll
        for (int ni = 0; ni < 2; ni++) {
            int col = wbase + ni * 16 + r16;
            #pragma unroll
            for (int r = 0; r < 4; r++) {
                int rl = mi * 16 + sub * 4 + r;
                int off = (rl * 256 + col * 2) ^ ((rl & 7) << 4);
                float tv = b2f(*(const ushort*)((const char*)ts + off));
                float v = fmaxf(omb * tv + beta * acc[mi][ni][r], 0.0f);
                xb[(size_t)(rowbase + rl) * HH + col] = f2bf(v);
            }
        }
}

// ---------------- segment sums of xb by label ----------------
__global__ __launch_bounds__(256) void sums_kernel(const ushort* __restrict__ xb,
                                                   const int* __restrict__ label,
                                                   float* __restrict__ sums, int n) {
    __shared__ float ls[CC * HH];
    for (int i = threadIdx.x; i < CC * HH; i += 256) ls[i] = 0.0f;
    __syncthreads();
    int local = threadIdx.x >> 7, h = threadIdx.x & 127;
    for (int nn = blockIdx.x * 2 + local; nn < n; nn += gridDim.x * 2) {
        int c = label[nn];
        float v = b2f(xb[(size_t)nn * HH + h]);
        atomicAdd(&ls[c * HH + h], v);
    }
    __syncthreads();
    for (int i = threadIdx.x; i < CC * HH; i += 256) atomicAdd(&sums[i], ls[i]);
}

// ---------------- centers -> normalized diffs -> cm contraction -> rcm [C,H] ----------------
// centers = (sums_x + 0.1*sums0) / cnt
__global__ __launch_bounds__(128) void rcm_kernel(const float* __restrict__ sumsx,
                                                  const float* __restrict__ sums0,
                                                  const float* __restrict__ cnt,
                                                  const float* __restrict__ cm,
                                                  float* __restrict__ rcm) {
    __shared__ float cs[CC * HH];
    __shared__ float red[HH];
    int h = threadIdx.x;
    int i = blockIdx.x;
    for (int idx = h; idx < CC * HH; idx += 128) {
        int c = idx >> 7;
        cs[idx] = (sumsx[idx] + 0.1f * sums0[idx]) / fmaxf(cnt[c], 1.0f);
    }
    __syncthreads();
    float ci = cs[i * HH + h];
    float acc = 0.0f;
    for (int j = 0; j < CC; j++) {
        float d = ci - cs[j * HH + h];
        red[h] = d * d;
        __syncthreads();
        for (int s = 64; s > 0; s >>= 1) {
            if (h < s) red[h] += red[h + s];
            __syncthreads();
        }
        float nrm = sqrtf(red[0]);
        if (nrm == 0.0f) nrm = 1.0f;
        acc = fmaf(cm[i * CC + j], d / nrm, acc);
        __syncthreads();
    }
    rcm[i * HH + h] = acc;
}

// ---------------- fused: CSR gather + combine -> tb (bf16) ----------------
// t = 0.45*x + 0.45*(p@rcm) + 0.45*agg + 0.1*x0
__global__ __launch_bounds__(256) void gather_combine_kernel(
    const ushort* __restrict__ xb, const float* __restrict__ x0,
    const float* __restrict__ p, const float* __restrict__ rcm,
    const int* __restrict__ rowptr, const int2* __restrict__ csr,
    ushort* __restrict__ tb, int n) {
    __shared__ float rs[CC * HH];
    for (int i = threadIdx.x; i < CC * HH; i += 256) rs[i] = rcm[i];
    __syncthreads();
    int wid = threadIdx.x >> 6, lane = threadIdx.x & 63;
    for (int nn = blockIdx.x * 4 + wid; nn < n; nn += gridDim.x * 4) {
        int beg = rowptr[nn], end = rowptr[nn + 1];
        float accx = 0.0f, accy = 0.0f;
        for (int chunk = beg; chunk < end; chunk += 64) {
            int cnt = min(64, end - chunk);
            int2 pr = make_int2(0, 0);
            if (lane < cnt) pr = csr[chunk + lane];
            for (int e2 = 0; e2 < cnt; e2++) {
                int s = __shfl(pr.x, e2);
                float w = __int_as_float(__shfl(pr.y, e2));
                const ushort2 xv = *(const ushort2*)(xb + (size_t)s * HH + 2 * lane);
                accx = fmaf(w, b2f(xv.x), accx);
                accy = fmaf(w, b2f(xv.y), accy);
            }
        }
        float pv = (lane < CC) ? p[(size_t)nn * CC + lane] : 0.0f;
        float prx = 0.0f, pry = 0.0f;
        #pragma unroll
        for (int c = 0; c < CC; c++) {
            float pc = __shfl(pv, c);
            const float2 rv = *(const float2*)(rs + c * HH + 2 * lane);
            prx = fmaf(pc, rv.x, prx);
            pry = fmaf(pc, rv.y, pry);
        }
        const ushort2 xc = *(const ushort2*)(xb + (size_t)nn * HH + 2 * lane);
        const float2 xo = *(const float2*)(x0 + (size_t)nn * HH + 2 * lane);
        float vx = 0.45f * b2f(xc.x) + 0.45f * prx + 0.45f * accx + 0.1f * xo.x;
        float vy = 0.45f * b2f(xc.y) + 0.45f * pry + 0.45f * accy + 0.1f * xo.y;
        ushort2 o;
        o.x = f2bf(vx);
        o.y = f2bf(vy);
        *(ushort2*)(tb + (size_t)nn * HH + 2 * lane) = o;
    }
}

// ---------------- final: out = xb @ W1 + b1  [N,47] ----------------
__global__ __launch_bounds__(256) void final_kernel(const ushort* __restrict__ xb,
                                                    const float* __restrict__ W,
                                                    const float* __restrict__ b,
                                                    float* __restrict__ out, int n) {
    __shared__ float Ws[HH * CC];
    for (int i = threadIdx.x; i < HH * CC; i += 256) Ws[i] = W[i];
    __syncthreads();
    int grp = threadIdx.x >> 6;
    int lane = threadIdx.x & 63;
    for (int nn = blockIdx.x * 4 + grp; nn < n; nn += gridDim.x * 4) {
        if (lane < CC) {
            const ushort* xr = xb + (size_t)nn * HH;
            float acc = b[lane];
            #pragma unroll
            for (int k = 0; k < HH; k++) acc = fmaf(b2f(xr[k]), Ws[k * CC + lane], acc);
            out[nn * CC + lane] = acc;
        }
    }
}

extern "C" void kernel_launch(void* const* d_in, const int* in_sizes, int n_in,
                              void* d_out, int out_size, void* d_ws, size_t ws_size,
                              hipStream_t stream) {
    const float* x_in   = (const float*)d_in[0];
    const int*   ei     = (const int*)d_in[1];
    const float* ew     = (const float*)d_in[2];
    const int*   label  = (const int*)d_in[3];
    const float* p      = (const float*)d_in[4];
    const float* cm     = (const float*)d_in[5];
    const float* lin0_w = (const float*)d_in[6];
    const float* lin0_b = (const float*)d_in[7];
    const float* lin1_w = (const float*)d_in[8];
    const float* lin1_b = (const float*)d_in[9];
    const float* conv_w = (const float*)d_in[10];
    float* out = (float*)d_out;

    const int* src = ei;
    const int* dst = ei + EE;

    const size_t NH = (size_t)NN * HH;
    float* ws = (float*)d_ws;
    float* x0    = ws;                       // NH f32
    float* cnt   = x0 + NH;                  // 64
    float* sums0 = cnt + 64;                 // CC*HH
    float* sumsx = sums0 + CC * HH;          // CC*HH
    float* rcm   = sumsx + CC * HH;          // CC*HH
    int*   deg    = (int*)(rcm + CC * HH);   // NN (also cursor)
    int*   rowptr = deg + NN;                // NN+1 (+pad)
    int*   bsum   = rowptr + NN + 64;        // 256
    int2*  csr    = (int2*)(bsum + 256);     // EE
    ushort* xb    = (ushort*)(csr + EE);     // NH bf16
    ushort* tb    = xb + NH;                 // NH bf16
    ushort* wp0   = tb + NH;                 // 16384
    ushort* wpc   = wp0 + 16384;             // 4*16384

    // ---- CSR build (once per call) ----
    hipMemsetAsync(deg, 0, NN * sizeof(int), stream);
    hist_kernel<<<(EE + 255) / 256, 256, 0, stream>>>(dst, deg, EE);
    const int NBLK = (NN + 511) / 512;
    scan_block_kernel<<<NBLK, 256, 0, stream>>>(deg, rowptr, bsum, NN);
    scan_bsum_kernel<<<1, 256, 0, stream>>>(bsum, NBLK);
    add_off_kernel<<<(NN + 255) / 256, 256, 0, stream>>>(rowptr, bsum, NN);
    hipMemsetAsync(deg, 0, NN * sizeof(int), stream);  // reuse as cursor
    fill_kernel<<<(EE + 255) / 256, 256, 0, stream>>>(src, dst, ew, rowptr, deg, csr, EE);

    // ---- pack weights bf16 ----
    pack_w_kernel<<<64, 256, 0, stream>>>(lin0_w, wp0);
    for (int i = 0; i < 4; i++)
        pack_w_kernel<<<64, 256, 0, stream>>>(conv_w + (size_t)i * HH * HH, wpc + (size_t)i * 16384);

    // label counts
    hipMemsetAsync(cnt, 0, CC * sizeof(float), stream);
    count_kernel<<<256, 256, 0, stream>>>(label, cnt, NN);

    // input linear + relu (N = 3125 * 32 exactly)
    lin0_mfma_kernel<<<NN / 32, 256, 0, stream>>>(x_in, wp0, lin0_b, x0, xb);

    // sums0 = sum_label x0 (bf16 rep)
    hipMemsetAsync(sums0, 0, CC * HH * sizeof(float), stream);
    sums_kernel<<<512, 256, 0, stream>>>(xb, label, sums0, NN);

    const float betas[4] = {logf(0.5f / 1.0f + 1.0f), logf(0.5f / 2.0f + 1.0f),
                            logf(0.5f / 3.0f + 1.0f), logf(0.5f / 4.0f + 1.0f)};

    for (int i = 0; i < 4; i++) {
        if (i == 0) {
            rcm_kernel<<<CC, 128, 0, stream>>>(sums0, sums0, cnt, cm, rcm);
        } else {
            hipMemsetAsync(sumsx, 0, CC * HH * sizeof(float), stream);
            sums_kernel<<<512, 256, 0, stream>>>(xb, label, sumsx, NN);
            rcm_kernel<<<CC, 128, 0, stream>>>(sumsx, sums0, cnt, cm, rcm);
        }
        gather_combine_kernel<<<2048, 256, 0, stream>>>(xb, x0, p, rcm, rowptr, csr, tb, NN);
        conv_mfma_kernel<<<NN / 32, 256, 0, stream>>>(tb, wpc + (size_t)i * 16384, xb, betas[i]);
    }

    final_kernel<<<4096, 256, 0, stream>>>(xb, lin1_w, lin1_b, out, NN);
}

// Round 5
// 1011.599 us; speedup vs baseline: 3.1009x; 1.4430x over previous
//
#include <hip/hip_runtime.h>
#include <math.h>

#define NN 100000
#define EE 800000
#define CC 47
#define HH 128

typedef __attribute__((ext_vector_type(8))) short short8v;
typedef __attribute__((ext_vector_type(4))) float float4v;

__device__ inline ushort f2bf(float f) {
    unsigned u = __float_as_uint(f);
    unsigned r = (u + 0x7fffu + ((u >> 16) & 1u)) >> 16;  // RNE
    return (ushort)r;
}
__device__ inline float b2f(ushort u) { return __uint_as_float(((unsigned)u) << 16); }

// ---------------- count labels (once) ----------------
__global__ __launch_bounds__(256) void count_kernel(const int* __restrict__ label,
                                                    float* __restrict__ cnt, int n) {
    __shared__ float lc[CC];
    if (threadIdx.x < CC) lc[threadIdx.x] = 0.0f;
    __syncthreads();
    for (int i = blockIdx.x * blockDim.x + threadIdx.x; i < n; i += gridDim.x * blockDim.x)
        atomicAdd(&lc[label[i]], 1.0f);
    __syncthreads();
    if (threadIdx.x < CC) atomicAdd(&cnt[threadIdx.x], lc[threadIdx.x]);
}

// ---------------- CSR build ----------------
__global__ __launch_bounds__(256) void hist_kernel(const int* __restrict__ dst,
                                                   int* __restrict__ deg, int e) {
    int i = blockIdx.x * 256 + threadIdx.x;
    if (i < e) atomicAdd(&deg[dst[i]], 1);
}

__global__ __launch_bounds__(256) void scan_block_kernel(const int* __restrict__ deg,
                                                         int* __restrict__ rowptr,
                                                         int* __restrict__ bsum, int n) {
    __shared__ int ls[256];
    int b = blockIdx.x, t = threadIdx.x;
    int i0 = b * 512 + 2 * t;
    int a0 = (i0 < n) ? deg[i0] : 0;
    int a1 = (i0 + 1 < n) ? deg[i0 + 1] : 0;
    int val = a0 + a1;
    ls[t] = val;
    __syncthreads();
    for (int off = 1; off < 256; off <<= 1) {
        int add = (t >= off) ? ls[t - off] : 0;
        __syncthreads();
        val += add;
        ls[t] = val;
        __syncthreads();
    }
    int incl1 = val;
    int incl0 = val - a1;
    if (i0 < n) rowptr[i0 + 1] = incl0;
    if (i0 + 1 < n) rowptr[i0 + 2] = incl1;
    if (t == 255) bsum[b] = val;
}

__global__ __launch_bounds__(256) void scan_bsum_kernel(int* __restrict__ bsum, int nb) {
    __shared__ int ls[256];
    int t = threadIdx.x;
    int v = (t < nb) ? bsum[t] : 0;
    int orig = v;
    ls[t] = v;
    __syncthreads();
    for (int off = 1; off < 256; off <<= 1) {
        int add = (t >= off) ? ls[t - off] : 0;
        __syncthreads();
        v += add;
        ls[t] = v;
        __syncthreads();
    }
    if (t < nb) bsum[t] = v - orig;
}

__global__ __launch_bounds__(256) void add_off_kernel(int* __restrict__ rowptr,
                                                      const int* __restrict__ bsum, int n) {
    int i = blockIdx.x * 256 + threadIdx.x;
    if (i < n) rowptr[i + 1] += bsum[i >> 9];
    if (i == 0) rowptr[0] = 0;
}

__global__ __launch_bounds__(256) void fill_kernel(const int* __restrict__ src,
                                                   const int* __restrict__ dst,
                                                   const float* __restrict__ ew,
                                                   const int* __restrict__ rowptr,
                                                   int* __restrict__ cur,
                                                   int2* __restrict__ csr, int e) {
    int i = blockIdx.x * 256 + threadIdx.x;
    if (i < e) {
        int d = dst[i];
        int pos = rowptr[d] + atomicAdd(&cur[d], 1);
        csr[pos] = make_int2(src[i], __float_as_int(ew[i]));
    }
}

// ---------------- pack weight [128][128] f32 -> MFMA B-fragment order bf16 ----------------
__global__ __launch_bounds__(256) void pack_w_kernel(const float* __restrict__ W,
                                                     ushort* __restrict__ Wp) {
    int idx = blockIdx.x * 256 + threadIdx.x;  // 0..16383
    int k = idx >> 7, c = idx & 127;
    Wp[(k >> 3) * 1024 + c * 8 + (k & 7)] = f2bf(W[idx]);
}

// ---------------- lin0: x0b = xb = relu(xin @ W + b) (bf16) ----------------
__global__ __launch_bounds__(256) void lin0_mfma_kernel(const float* __restrict__ xin,
                                                        const ushort* __restrict__ Wp,
                                                        const float* __restrict__ bias,
                                                        ushort* __restrict__ x0b,
                                                        ushort* __restrict__ xb) {
    __shared__ ushort ts[32 * 128];
    __shared__ ushort wl[128 * 128];
    {
        const uint4* g4 = (const uint4*)Wp;
        uint4* l4 = (uint4*)wl;
        for (int j = threadIdx.x; j < 2048; j += 256) l4[j] = g4[j];
    }
    const int lane = threadIdx.x & 63, wv = threadIdx.x >> 6;
    const int sub = lane >> 4, r16 = lane & 15;
    const int wbase = wv * 32;
    const int rowbase = blockIdx.x * 32;
    const float* tp = xin + (size_t)rowbase * HH;
    #pragma unroll
    for (int j = 0; j < 4; j++) {
        int e = 4 * threadIdx.x + j * 1024;
        float4 f = *(const float4*)(tp + e);
        int r = e >> 7, c = e & 127;
        ushort4 b4 = make_ushort4(f2bf(f.x), f2bf(f.y), f2bf(f.z), f2bf(f.w));
        int off = (r * 256 + c * 2) ^ ((r & 7) << 4);
        *(ushort4*)((char*)ts + off) = b4;
    }
    __syncthreads();
    float4v acc[2][2] = {};
    {
        const char* tsc = (const char*)ts;
        const int sw = (r16 & 7) << 4;
        #pragma unroll
        for (int ks = 0; ks < 4; ks++) {
            short8v a0 = *(const short8v*)(tsc + ((r16 * 256 + ks * 64 + sub * 16) ^ sw));
            short8v a1 = *(const short8v*)(tsc + (((16 + r16) * 256 + ks * 64 + sub * 16) ^ sw));
            int kb = (ks * 4 + sub) * 1024;
            short8v b0 = *(const short8v*)(wl + kb + (wbase + r16) * 8);
            short8v b1 = *(const short8v*)(wl + kb + (wbase + 16 + r16) * 8);
            acc[0][0] = __builtin_amdgcn_mfma_f32_16x16x32_bf16(a0, b0, acc[0][0], 0, 0, 0);
            acc[0][1] = __builtin_amdgcn_mfma_f32_16x16x32_bf16(a0, b1, acc[0][1], 0, 0, 0);
            acc[1][0] = __builtin_amdgcn_mfma_f32_16x16x32_bf16(a1, b0, acc[1][0], 0, 0, 0);
            acc[1][1] = __builtin_amdgcn_mfma_f32_16x16x32_bf16(a1, b1, acc[1][1], 0, 0, 0);
        }
    }
    float bv[2] = {bias[wbase + r16], bias[wbase + 16 + r16]};
    #pragma unroll
    for (int mi = 0; mi < 2; mi++)
        #pragma unroll
        for (int ni = 0; ni < 2; ni++) {
            int col = wbase + ni * 16 + r16;
            #pragma unroll
            for (int r = 0; r < 4; r++) {
                int row = rowbase + mi * 16 + sub * 4 + r;
                float v = fmaxf(acc[mi][ni][r] + bv[ni], 0.0f);
                ushort bv16 = f2bf(v);
                x0b[(size_t)row * HH + col] = bv16;
                xb[(size_t)row * HH + col] = bv16;
            }
        }
}

// ---------------- conv: xb = relu((1-beta)*t + beta*(t @ W)), t = tb (bf16) ----------------
__global__ __launch_bounds__(256) void conv_mfma_kernel(const ushort* __restrict__ tb,
                                                        const ushort* __restrict__ Wp,
                                                        ushort* __restrict__ xb, float beta) {
    __shared__ ushort ts[32 * 128];
    __shared__ ushort wl[128 * 128];
    {
        const uint4* g4 = (const uint4*)Wp;
        uint4* l4 = (uint4*)wl;
        for (int j = threadIdx.x; j < 2048; j += 256) l4[j] = g4[j];
    }
    const int lane = threadIdx.x & 63, wv = threadIdx.x >> 6;
    const int sub = lane >> 4, r16 = lane & 15;
    const int wbase = wv * 32;
    const int rowbase = blockIdx.x * 32;
    const ushort* tp = tb + (size_t)rowbase * HH;
    #pragma unroll
    for (int j = 0; j < 2; j++) {
        int cid = threadIdx.x + j * 256;   // 16B chunk id, 512 total
        int e = cid * 8;
        int r = e >> 7;
        int off = (e * 2) ^ ((r & 7) << 4);
        *(short8v*)((char*)ts + off) = *(const short8v*)(tp + e);
    }
    __syncthreads();
    float4v acc[2][2] = {};
    {
        const char* tsc = (const char*)ts;
        const int sw = (r16 & 7) << 4;
        #pragma unroll
        for (int ks = 0; ks < 4; ks++) {
            short8v a0 = *(const short8v*)(tsc + ((r16 * 256 + ks * 64 + sub * 16) ^ sw));
            short8v a1 = *(const short8v*)(tsc + (((16 + r16) * 256 + ks * 64 + sub * 16) ^ sw));
            int kb = (ks * 4 + sub) * 1024;
            short8v b0 = *(const short8v*)(wl + kb + (wbase + r16) * 8);
            short8v b1 = *(const short8v*)(wl + kb + (wbase + 16 + r16) * 8);
            acc[0][0] = __builtin_amdgcn_mfma_f32_16x16x32_bf16(a0, b0, acc[0][0], 0, 0, 0);
            acc[0][1] = __builtin_amdgcn_mfma_f32_16x16x32_bf16(a0, b1, acc[0][1], 0, 0, 0);
            acc[1][0] = __builtin_amdgcn_mfma_f32_16x16x32_bf16(a1, b0, acc[1][0], 0, 0, 0);
            acc[1][1] = __builtin_amdgcn_mfma_f32_16x16x32_bf16(a1, b1, acc[1][1], 0, 0, 0);
        }
    }
    const float omb = 1.0f - beta;
    #pragma unroll
    for (int mi = 0; mi < 2; mi++)
        #pragma unroll
        for (int ni = 0; ni < 2; ni++) {
            int col = wbase + ni * 16 + r16;
            #pragma unroll
            for (int r = 0; r < 4; r++) {
                int rl = mi * 16 + sub * 4 + r;
                int off = (rl * 256 + col * 2) ^ ((rl & 7) << 4);
                float tv = b2f(*(const ushort*)((const char*)ts + off));
                float v = fmaxf(omb * tv + beta * acc[mi][ni][r], 0.0f);
                xb[(size_t)(rowbase + rl) * HH + col] = f2bf(v);
            }
        }
}

// ---------------- segment sums of xb by label ----------------
__global__ __launch_bounds__(256) void sums_kernel(const ushort* __restrict__ xb,
                                                   const int* __restrict__ label,
                                                   float* __restrict__ sums, int n) {
    __shared__ float ls[CC * HH];
    for (int i = threadIdx.x; i < CC * HH; i += 256) ls[i] = 0.0f;
    __syncthreads();
    int local = threadIdx.x >> 7, h = threadIdx.x & 127;
    for (int nn = blockIdx.x * 2 + local; nn < n; nn += gridDim.x * 2) {
        int c = label[nn];
        float v = b2f(xb[(size_t)nn * HH + h]);
        atomicAdd(&ls[c * HH + h], v);
    }
    __syncthreads();
    for (int i = threadIdx.x; i < CC * HH; i += 256) atomicAdd(&sums[i], ls[i]);
}

// ---------------- centers -> normalized diffs -> cm contraction -> rcm [C,H] ----------------
__global__ __launch_bounds__(128) void rcm_kernel(const float* __restrict__ sumsx,
                                                  const float* __restrict__ sums0,
                                                  const float* __restrict__ cnt,
                                                  const float* __restrict__ cm,
                                                  float* __restrict__ rcm) {
    __shared__ float cs[CC * HH];
    __shared__ float red[HH];
    int h = threadIdx.x;
    int i = blockIdx.x;
    for (int idx = h; idx < CC * HH; idx += 128) {
        int c = idx >> 7;
        cs[idx] = (sumsx[idx] + 0.1f * sums0[idx]) / fmaxf(cnt[c], 1.0f);
    }
    __syncthreads();
    float ci = cs[i * HH + h];
    float acc = 0.0f;
    for (int j = 0; j < CC; j++) {
        float d = ci - cs[j * HH + h];
        red[h] = d * d;
        __syncthreads();
        for (int s = 64; s > 0; s >>= 1) {
            if (h < s) red[h] += red[h + s];
            __syncthreads();
        }
        float nrm = sqrtf(red[0]);
        if (nrm == 0.0f) nrm = 1.0f;
        acc = fmaf(cm[i * CC + j], d / nrm, acc);
        __syncthreads();
    }
    rcm[i * HH + h] = acc;
}

// ---------------- fused: CSR gather + combine -> tb (bf16), scalarized ----------------
// t = 0.45*x + 0.45*(p@rcm) + 0.45*agg + 0.1*x0
__global__ __launch_bounds__(256) void gather_combine_kernel(
    const ushort* __restrict__ xb, const ushort* __restrict__ x0b,
    const float* __restrict__ p, const float* __restrict__ rcm,
    const int* __restrict__ rowptr, const int2* __restrict__ csr,
    ushort* __restrict__ tb, int n) {
    __shared__ ushort rs[CC * HH];  // rcm in bf16 (12 KB)
    for (int i = threadIdx.x; i < CC * HH; i += 256) rs[i] = f2bf(rcm[i]);
    __syncthreads();
    const int lane = threadIdx.x & 63;
    const int wid = __builtin_amdgcn_readfirstlane(threadIdx.x >> 6);  // wave-uniform
    for (int nn = blockIdx.x * 4 + wid; nn < n; nn += gridDim.x * 4) {
        int beg = __builtin_amdgcn_readfirstlane(rowptr[nn]);
        int end = __builtin_amdgcn_readfirstlane(rowptr[nn + 1]);
        float accx = 0.0f, accy = 0.0f;
        int e2 = beg;
        for (; e2 + 4 <= end; e2 += 4) {
            int2 ed0 = csr[e2 + 0];
            int2 ed1 = csr[e2 + 1];
            int2 ed2 = csr[e2 + 2];
            int2 ed3 = csr[e2 + 3];
            ushort2 v0 = *(const ushort2*)(xb + (size_t)ed0.x * HH + 2 * lane);
            ushort2 v1 = *(const ushort2*)(xb + (size_t)ed1.x * HH + 2 * lane);
            ushort2 v2 = *(const ushort2*)(xb + (size_t)ed2.x * HH + 2 * lane);
            ushort2 v3 = *(const ushort2*)(xb + (size_t)ed3.x * HH + 2 * lane);
            float w0 = __int_as_float(ed0.y), w1 = __int_as_float(ed1.y);
            float w2 = __int_as_float(ed2.y), w3 = __int_as_float(ed3.y);
            accx = fmaf(w0, b2f(v0.x), accx);
            accy = fmaf(w0, b2f(v0.y), accy);
            accx = fmaf(w1, b2f(v1.x), accx);
            accy = fmaf(w1, b2f(v1.y), accy);
            accx = fmaf(w2, b2f(v2.x), accx);
            accy = fmaf(w2, b2f(v2.y), accy);
            accx = fmaf(w3, b2f(v3.x), accx);
            accy = fmaf(w3, b2f(v3.y), accy);
        }
        for (; e2 < end; e2++) {
            int2 ed = csr[e2];
            ushort2 v = *(const ushort2*)(xb + (size_t)ed.x * HH + 2 * lane);
            float w = __int_as_float(ed.y);
            accx = fmaf(w, b2f(v.x), accx);
            accy = fmaf(w, b2f(v.y), accy);
        }
        // p @ rcm — p loads are wave-uniform (scalar), rs from LDS
        float prx = 0.0f, pry = 0.0f;
        const float* prow = p + (size_t)nn * CC;
        #pragma unroll
        for (int c = 0; c < CC; c++) {
            float pc = prow[c];
            ushort2 rv = *(const ushort2*)(rs + c * HH + 2 * lane);
            prx = fmaf(pc, b2f(rv.x), prx);
            pry = fmaf(pc, b2f(rv.y), pry);
        }
        ushort2 xc = *(const ushort2*)(xb + (size_t)nn * HH + 2 * lane);
        ushort2 xo = *(const ushort2*)(x0b + (size_t)nn * HH + 2 * lane);
        float vx = 0.45f * b2f(xc.x) + 0.45f * prx + 0.45f * accx + 0.1f * b2f(xo.x);
        float vy = 0.45f * b2f(xc.y) + 0.45f * pry + 0.45f * accy + 0.1f * b2f(xo.y);
        ushort2 o;
        o.x = f2bf(vx);
        o.y = f2bf(vy);
        *(ushort2*)(tb + (size_t)nn * HH + 2 * lane) = o;
    }
}

// ---------------- final: out = xb @ W1 + b1  [N,47] ----------------
__global__ __launch_bounds__(256) void final_kernel(const ushort* __restrict__ xb,
                                                    const float* __restrict__ W,
                                                    const float* __restrict__ b,
                                                    float* __restrict__ out, int n) {
    __shared__ float Ws[HH * CC];
    for (int i = threadIdx.x; i < HH * CC; i += 256) Ws[i] = W[i];
    __syncthreads();
    int grp = threadIdx.x >> 6;
    int lane = threadIdx.x & 63;
    for (int nn = blockIdx.x * 4 + grp; nn < n; nn += gridDim.x * 4) {
        if (lane < CC) {
            const ushort* xr = xb + (size_t)nn * HH;
            float acc = b[lane];
            #pragma unroll
            for (int k = 0; k < HH; k++) acc = fmaf(b2f(xr[k]), Ws[k * CC + lane], acc);
            out[nn * CC + lane] = acc;
        }
    }
}

extern "C" void kernel_launch(void* const* d_in, const int* in_sizes, int n_in,
                              void* d_out, int out_size, void* d_ws, size_t ws_size,
                              hipStream_t stream) {
    const float* x_in   = (const float*)d_in[0];
    const int*   ei     = (const int*)d_in[1];
    const float* ew     = (const float*)d_in[2];
    const int*   label  = (const int*)d_in[3];
    const float* p      = (const float*)d_in[4];
    const float* cm     = (const float*)d_in[5];
    const float* lin0_w = (const float*)d_in[6];
    const float* lin0_b = (const float*)d_in[7];
    const float* lin1_w = (const float*)d_in[8];
    const float* lin1_b = (const float*)d_in[9];
    const float* conv_w = (const float*)d_in[10];
    float* out = (float*)d_out;

    const int* src = ei;
    const int* dst = ei + EE;

    const size_t NH = (size_t)NN * HH;
    float* ws = (float*)d_ws;
    float* cnt   = ws;                       // 64
    float* sums0 = cnt + 64;                 // CC*HH
    float* sumsx = sums0 + CC * HH;          // CC*HH
    float* rcm   = sumsx + CC * HH;          // CC*HH
    int*   deg    = (int*)(rcm + CC * HH);   // NN (also cursor)
    int*   rowptr = deg + NN;                // NN+1 (+pad)
    int*   bsum   = rowptr + NN + 64;        // 256
    int2*  csr    = (int2*)(bsum + 256);     // EE
    ushort* x0b   = (ushort*)(csr + EE);     // NH bf16
    ushort* xb    = x0b + NH;                // NH bf16
    ushort* tb    = xb + NH;                 // NH bf16
    ushort* wp0   = tb + NH;                 // 16384
    ushort* wpc   = wp0 + 16384;             // 4*16384

    // ---- CSR build (once per call) ----
    hipMemsetAsync(deg, 0, NN * sizeof(int), stream);
    hist_kernel<<<(EE + 255) / 256, 256, 0, stream>>>(dst, deg, EE);
    const int NBLK = (NN + 511) / 512;
    scan_block_kernel<<<NBLK, 256, 0, stream>>>(deg, rowptr, bsum, NN);
    scan_bsum_kernel<<<1, 256, 0, stream>>>(bsum, NBLK);
    add_off_kernel<<<(NN + 255) / 256, 256, 0, stream>>>(rowptr, bsum, NN);
    hipMemsetAsync(deg, 0, NN * sizeof(int), stream);  // reuse as cursor
    fill_kernel<<<(EE + 255) / 256, 256, 0, stream>>>(src, dst, ew, rowptr, deg, csr, EE);

    // ---- pack weights bf16 ----
    pack_w_kernel<<<64, 256, 0, stream>>>(lin0_w, wp0);
    for (int i = 0; i < 4; i++)
        pack_w_kernel<<<64, 256, 0, stream>>>(conv_w + (size_t)i * HH * HH, wpc + (size_t)i * 16384);

    // label counts
    hipMemsetAsync(cnt, 0, CC * sizeof(float), stream);
    count_kernel<<<256, 256, 0, stream>>>(label, cnt, NN);

    // input linear + relu (N = 3125 * 32 exactly)
    lin0_mfma_kernel<<<NN / 32, 256, 0, stream>>>(x_in, wp0, lin0_b, x0b, xb);

    // sums0 = sum_label x0 (bf16 rep)
    hipMemsetAsync(sums0, 0, CC * HH * sizeof(float), stream);
    sums_kernel<<<512, 256, 0, stream>>>(x0b, label, sums0, NN);

    const float betas[4] = {logf(0.5f / 1.0f + 1.0f), logf(0.5f / 2.0f + 1.0f),
                            logf(0.5f / 3.0f + 1.0f), logf(0.5f / 4.0f + 1.0f)};

    for (int i = 0; i < 4; i++) {
        if (i == 0) {
            rcm_kernel<<<CC, 128, 0, stream>>>(sums0, sums0, cnt, cm, rcm);
        } else {
            hipMemsetAsync(sumsx, 0, CC * HH * sizeof(float), stream);
            sums_kernel<<<512, 256, 0, stream>>>(xb, label, sumsx, NN);
            rcm_kernel<<<CC, 128, 0, stream>>>(sumsx, sums0, cnt, cm, rcm);
        }
        gather_combine_kernel<<<2048, 256, 0, stream>>>(xb, x0b, p, rcm, rowptr, csr, tb, NN);
        conv_mfma_kernel<<<NN / 32, 256, 0, stream>>>(tb, wpc + (size_t)i * 16384, xb, betas[i]);
    }

    final_kernel<<<4096, 256, 0, stream>>>(xb, lin1_w, lin1_b, out, NN);
}

// Round 6
// 955.400 us; speedup vs baseline: 3.2833x; 1.0588x over previous
//
#include <hip/hip_runtime.h>
#include <math.h>

#define NN 100000
#define EE 800000
#define CC 47
#define HH 128

typedef __attribute__((ext_vector_type(8))) short short8v;
typedef __attribute__((ext_vector_type(4))) float float4v;

__device__ inline ushort f2bf(float f) {
    unsigned u = __float_as_uint(f);
    unsigned r = (u + 0x7fffu + ((u >> 16) & 1u)) >> 16;  // RNE
    return (ushort)r;
}
__device__ inline float b2f(ushort u) { return __uint_as_float(((unsigned)u) << 16); }

// ---------------- count labels (once) ----------------
__global__ __launch_bounds__(256) void count_kernel(const int* __restrict__ label,
                                                    float* __restrict__ cnt, int n) {
    __shared__ float lc[CC];
    if (threadIdx.x < CC) lc[threadIdx.x] = 0.0f;
    __syncthreads();
    for (int i = blockIdx.x * blockDim.x + threadIdx.x; i < n; i += gridDim.x * blockDim.x)
        atomicAdd(&lc[label[i]], 1.0f);
    __syncthreads();
    if (threadIdx.x < CC) atomicAdd(&cnt[threadIdx.x], lc[threadIdx.x]);
}

// ---------------- CSR build ----------------
__global__ __launch_bounds__(256) void hist_kernel(const int* __restrict__ dst,
                                                   int* __restrict__ deg, int e) {
    int i = blockIdx.x * 256 + threadIdx.x;
    if (i < e) atomicAdd(&deg[dst[i]], 1);
}

__global__ __launch_bounds__(256) void scan_block_kernel(const int* __restrict__ deg,
                                                         int* __restrict__ rowptr,
                                                         int* __restrict__ bsum, int n) {
    __shared__ int ls[256];
    int b = blockIdx.x, t = threadIdx.x;
    int i0 = b * 512 + 2 * t;
    int a0 = (i0 < n) ? deg[i0] : 0;
    int a1 = (i0 + 1 < n) ? deg[i0 + 1] : 0;
    int val = a0 + a1;
    ls[t] = val;
    __syncthreads();
    for (int off = 1; off < 256; off <<= 1) {
        int add = (t >= off) ? ls[t - off] : 0;
        __syncthreads();
        val += add;
        ls[t] = val;
        __syncthreads();
    }
    int incl1 = val;
    int incl0 = val - a1;
    if (i0 < n) rowptr[i0 + 1] = incl0;
    if (i0 + 1 < n) rowptr[i0 + 2] = incl1;
    if (t == 255) bsum[b] = val;
}

__global__ __launch_bounds__(256) void scan_bsum_kernel(int* __restrict__ bsum, int nb) {
    __shared__ int ls[256];
    int t = threadIdx.x;
    int v = (t < nb) ? bsum[t] : 0;
    int orig = v;
    ls[t] = v;
    __syncthreads();
    for (int off = 1; off < 256; off <<= 1) {
        int add = (t >= off) ? ls[t - off] : 0;
        __syncthreads();
        v += add;
        ls[t] = v;
        __syncthreads();
    }
    if (t < nb) bsum[t] = v - orig;
}

__global__ __launch_bounds__(256) void add_off_kernel(int* __restrict__ rowptr,
                                                      const int* __restrict__ bsum, int n) {
    int i = blockIdx.x * 256 + threadIdx.x;
    if (i < n) rowptr[i + 1] += bsum[i >> 9];
    if (i == 0) rowptr[0] = 0;
}

__global__ __launch_bounds__(256) void fill_kernel(const int* __restrict__ src,
                                                   const int* __restrict__ dst,
                                                   const float* __restrict__ ew,
                                                   const int* __restrict__ rowptr,
                                                   int* __restrict__ cur,
                                                   int2* __restrict__ csr, int e) {
    int i = blockIdx.x * 256 + threadIdx.x;
    if (i < e) {
        int d = dst[i];
        int pos = rowptr[d] + atomicAdd(&cur[d], 1);
        csr[pos] = make_int2(src[i], __float_as_int(ew[i]));
    }
}

// ---------------- pack weight [128][128] f32 -> MFMA B-fragment order bf16 ----------------
__global__ __launch_bounds__(256) void pack_w_kernel(const float* __restrict__ W,
                                                     ushort* __restrict__ Wp) {
    int idx = blockIdx.x * 256 + threadIdx.x;  // 0..16383
    int k = idx >> 7, c = idx & 127;
    Wp[(k >> 3) * 1024 + c * 8 + (k & 7)] = f2bf(W[idx]);
}

// pack W1 [128][47] -> B-frag order, cols padded to 48. 6144 ushorts.
__global__ __launch_bounds__(256) void pack_w1_kernel(const float* __restrict__ W1,
                                                      ushort* __restrict__ Wp1) {
    int idx = blockIdx.x * 256 + threadIdx.x;  // 0..6143
    if (idx >= 6144) return;
    int ksub = idx / 384, rem = idx - ksub * 384;
    int c = rem >> 3, kk = ksub * 8 + (rem & 7);
    Wp1[idx] = (c < CC) ? f2bf(W1[kk * CC + c]) : (ushort)0;
}

// ---------------- lin0: x0b = xb = relu(xin @ W + b) (bf16) ----------------
__global__ __launch_bounds__(256) void lin0_mfma_kernel(const float* __restrict__ xin,
                                                        const ushort* __restrict__ Wp,
                                                        const float* __restrict__ bias,
                                                        ushort* __restrict__ x0b,
                                                        ushort* __restrict__ xb) {
    __shared__ ushort ts[32 * 128];
    __shared__ ushort wl[128 * 128];
    {
        const uint4* g4 = (const uint4*)Wp;
        uint4* l4 = (uint4*)wl;
        for (int j = threadIdx.x; j < 2048; j += 256) l4[j] = g4[j];
    }
    const int lane = threadIdx.x & 63, wv = threadIdx.x >> 6;
    const int sub = lane >> 4, r16 = lane & 15;
    const int wbase = wv * 32;
    const int rowbase = blockIdx.x * 32;
    const float* tp = xin + (size_t)rowbase * HH;
    #pragma unroll
    for (int j = 0; j < 4; j++) {
        int e = 4 * threadIdx.x + j * 1024;
        float4 f = *(const float4*)(tp + e);
        int r = e >> 7, c = e & 127;
        ushort4 b4 = make_ushort4(f2bf(f.x), f2bf(f.y), f2bf(f.z), f2bf(f.w));
        int off = (r * 256 + c * 2) ^ ((r & 7) << 4);
        *(ushort4*)((char*)ts + off) = b4;
    }
    __syncthreads();
    float4v acc[2][2] = {};
    {
        const char* tsc = (const char*)ts;
        const int sw = (r16 & 7) << 4;
        #pragma unroll
        for (int ks = 0; ks < 4; ks++) {
            short8v a0 = *(const short8v*)(tsc + ((r16 * 256 + ks * 64 + sub * 16) ^ sw));
            short8v a1 = *(const short8v*)(tsc + (((16 + r16) * 256 + ks * 64 + sub * 16) ^ sw));
            int kb = (ks * 4 + sub) * 1024;
            short8v b0 = *(const short8v*)(wl + kb + (wbase + r16) * 8);
            short8v b1 = *(const short8v*)(wl + kb + (wbase + 16 + r16) * 8);
            acc[0][0] = __builtin_amdgcn_mfma_f32_16x16x32_bf16(a0, b0, acc[0][0], 0, 0, 0);
            acc[0][1] = __builtin_amdgcn_mfma_f32_16x16x32_bf16(a0, b1, acc[0][1], 0, 0, 0);
            acc[1][0] = __builtin_amdgcn_mfma_f32_16x16x32_bf16(a1, b0, acc[1][0], 0, 0, 0);
            acc[1][1] = __builtin_amdgcn_mfma_f32_16x16x32_bf16(a1, b1, acc[1][1], 0, 0, 0);
        }
    }
    float bv[2] = {bias[wbase + r16], bias[wbase + 16 + r16]};
    #pragma unroll
    for (int mi = 0; mi < 2; mi++)
        #pragma unroll
        for (int ni = 0; ni < 2; ni++) {
            int col = wbase + ni * 16 + r16;
            #pragma unroll
            for (int r = 0; r < 4; r++) {
                int row = rowbase + mi * 16 + sub * 4 + r;
                float v = fmaxf(acc[mi][ni][r] + bv[ni], 0.0f);
                ushort bv16 = f2bf(v);
                x0b[(size_t)row * HH + col] = bv16;
                xb[(size_t)row * HH + col] = bv16;
            }
        }
}

// ---------------- conv (layers 0-2): xb = relu((1-beta)*t + beta*(t @ W)) ----------------
__global__ __launch_bounds__(256) void conv_mfma_kernel(const ushort* __restrict__ tb,
                                                        const ushort* __restrict__ Wp,
                                                        ushort* __restrict__ xb, float beta) {
    __shared__ ushort ts[32 * 128];
    __shared__ ushort wl[128 * 128];
    {
        const uint4* g4 = (const uint4*)Wp;
        uint4* l4 = (uint4*)wl;
        for (int j = threadIdx.x; j < 2048; j += 256) l4[j] = g4[j];
    }
    const int lane = threadIdx.x & 63, wv = threadIdx.x >> 6;
    const int sub = lane >> 4, r16 = lane & 15;
    const int wbase = wv * 32;
    const int rowbase = blockIdx.x * 32;
    const ushort* tp = tb + (size_t)rowbase * HH;
    #pragma unroll
    for (int j = 0; j < 2; j++) {
        int cid = threadIdx.x + j * 256;
        int e = cid * 8;
        int r = e >> 7;
        int off = (e * 2) ^ ((r & 7) << 4);
        *(short8v*)((char*)ts + off) = *(const short8v*)(tp + e);
    }
    __syncthreads();
    float4v acc[2][2] = {};
    {
        const char* tsc = (const char*)ts;
        const int sw = (r16 & 7) << 4;
        #pragma unroll
        for (int ks = 0; ks < 4; ks++) {
            short8v a0 = *(const short8v*)(tsc + ((r16 * 256 + ks * 64 + sub * 16) ^ sw));
            short8v a1 = *(const short8v*)(tsc + (((16 + r16) * 256 + ks * 64 + sub * 16) ^ sw));
            int kb = (ks * 4 + sub) * 1024;
            short8v b0 = *(const short8v*)(wl + kb + (wbase + r16) * 8);
            short8v b1 = *(const short8v*)(wl + kb + (wbase + 16 + r16) * 8);
            acc[0][0] = __builtin_amdgcn_mfma_f32_16x16x32_bf16(a0, b0, acc[0][0], 0, 0, 0);
            acc[0][1] = __builtin_amdgcn_mfma_f32_16x16x32_bf16(a0, b1, acc[0][1], 0, 0, 0);
            acc[1][0] = __builtin_amdgcn_mfma_f32_16x16x32_bf16(a1, b0, acc[1][0], 0, 0, 0);
            acc[1][1] = __builtin_amdgcn_mfma_f32_16x16x32_bf16(a1, b1, acc[1][1], 0, 0, 0);
        }
    }
    const float omb = 1.0f - beta;
    #pragma unroll
    for (int mi = 0; mi < 2; mi++)
        #pragma unroll
        for (int ni = 0; ni < 2; ni++) {
            int col = wbase + ni * 16 + r16;
            #pragma unroll
            for (int r = 0; r < 4; r++) {
                int rl = mi * 16 + sub * 4 + r;
                int off = (rl * 256 + col * 2) ^ ((rl & 7) << 4);
                float tv = b2f(*(const ushort*)((const char*)ts + off));
                float v = fmaxf(omb * tv + beta * acc[mi][ni][r], 0.0f);
                xb[(size_t)(rowbase + rl) * HH + col] = f2bf(v);
            }
        }
}

// ---------------- conv_final (layer 3): x = relu(conv(t)); out = x @ W1 + b1 ----------------
__global__ __launch_bounds__(256) void conv_final_kernel(const ushort* __restrict__ tb,
                                                         const ushort* __restrict__ Wp,
                                                         const ushort* __restrict__ Wp1,
                                                         const float* __restrict__ b1,
                                                         float* __restrict__ out, float beta) {
    __shared__ ushort ts[32 * 128];
    __shared__ ushort wl[128 * 128];
    __shared__ ushort w1l[6144];
    {
        const uint4* g4 = (const uint4*)Wp;
        uint4* l4 = (uint4*)wl;
        for (int j = threadIdx.x; j < 2048; j += 256) l4[j] = g4[j];
        const uint4* g1 = (const uint4*)Wp1;
        uint4* l1 = (uint4*)w1l;
        for (int j = threadIdx.x; j < 768; j += 256) l1[j] = g1[j];
    }
    const int lane = threadIdx.x & 63, wv = threadIdx.x >> 6;
    const int sub = lane >> 4, r16 = lane & 15;
    const int wbase = wv * 32;
    const int rowbase = blockIdx.x * 32;
    const ushort* tp = tb + (size_t)rowbase * HH;
    #pragma unroll
    for (int j = 0; j < 2; j++) {
        int cid = threadIdx.x + j * 256;
        int e = cid * 8;
        int r = e >> 7;
        int off = (e * 2) ^ ((r & 7) << 4);
        *(short8v*)((char*)ts + off) = *(const short8v*)(tp + e);
    }
    __syncthreads();
    float4v acc[2][2] = {};
    {
        const char* tsc = (const char*)ts;
        const int sw = (r16 & 7) << 4;
        #pragma unroll
        for (int ks = 0; ks < 4; ks++) {
            short8v a0 = *(const short8v*)(tsc + ((r16 * 256 + ks * 64 + sub * 16) ^ sw));
            short8v a1 = *(const short8v*)(tsc + (((16 + r16) * 256 + ks * 64 + sub * 16) ^ sw));
            int kb = (ks * 4 + sub) * 1024;
            short8v b0 = *(const short8v*)(wl + kb + (wbase + r16) * 8);
            short8v b1v = *(const short8v*)(wl + kb + (wbase + 16 + r16) * 8);
            acc[0][0] = __builtin_amdgcn_mfma_f32_16x16x32_bf16(a0, b0, acc[0][0], 0, 0, 0);
            acc[0][1] = __builtin_amdgcn_mfma_f32_16x16x32_bf16(a0, b1v, acc[0][1], 0, 0, 0);
            acc[1][0] = __builtin_amdgcn_mfma_f32_16x16x32_bf16(a1, b0, acc[1][0], 0, 0, 0);
            acc[1][1] = __builtin_amdgcn_mfma_f32_16x16x32_bf16(a1, b1v, acc[1][1], 0, 0, 0);
        }
    }
    __syncthreads();  // all waves done reading ts for GEMM1
    const float omb = 1.0f - beta;
    #pragma unroll
    for (int mi = 0; mi < 2; mi++)
        #pragma unroll
        for (int ni = 0; ni < 2; ni++) {
            int col = wbase + ni * 16 + r16;
            #pragma unroll
            for (int r = 0; r < 4; r++) {
                int rl = mi * 16 + sub * 4 + r;
                int off = (rl * 256 + col * 2) ^ ((rl & 7) << 4);
                ushort* slot = (ushort*)((char*)ts + off);
                float tv = b2f(*slot);
                float v = fmaxf(omb * tv + beta * acc[mi][ni][r], 0.0f);
                *slot = f2bf(v);  // x tile back into LDS (same swizzled layout)
            }
        }
    __syncthreads();
    // GEMM2: out(32x47) = x(32x128) @ W1(128x47) + b1 ; waves 0..2 take col-frags
    if (wv < 3) {
        float4v a2[2] = {};
        const char* tsc = (const char*)ts;
        const int sw = (r16 & 7) << 4;
        #pragma unroll
        for (int ks = 0; ks < 4; ks++) {
            short8v a0 = *(const short8v*)(tsc + ((r16 * 256 + ks * 64 + sub * 16) ^ sw));
            short8v a1 = *(const short8v*)(tsc + (((16 + r16) * 256 + ks * 64 + sub * 16) ^ sw));
            short8v bb = *(const short8v*)(w1l + (ks * 4 + sub) * 384 + (wv * 16 + r16) * 8);
            a2[0] = __builtin_amdgcn_mfma_f32_16x16x32_bf16(a0, bb, a2[0], 0, 0, 0);
            a2[1] = __builtin_amdgcn_mfma_f32_16x16x32_bf16(a1, bb, a2[1], 0, 0, 0);
        }
        int col = wv * 16 + r16;
        if (col < CC) {
            float bias = b1[col];
            #pragma unroll
            for (int mi = 0; mi < 2; mi++)
                #pragma unroll
                for (int r = 0; r < 4; r++) {
                    int row = rowbase + mi * 16 + sub * 4 + r;
                    out[(size_t)row * CC + col] = a2[mi][r] + bias;
                }
        }
    }
}

// ---------------- segment sums of xb by label ----------------
__global__ __launch_bounds__(256) void sums_kernel(const ushort* __restrict__ xb,
                                                   const int* __restrict__ label,
                                                   float* __restrict__ sums, int n) {
    __shared__ float ls[CC * HH];
    for (int i = threadIdx.x; i < CC * HH; i += 256) ls[i] = 0.0f;
    __syncthreads();
    int local = threadIdx.x >> 7, h = threadIdx.x & 127;
    for (int nn = blockIdx.x * 2 + local; nn < n; nn += gridDim.x * 2) {
        int c = label[nn];
        float v = b2f(xb[(size_t)nn * HH + h]);
        atomicAdd(&ls[c * HH + h], v);
    }
    __syncthreads();
    for (int i = threadIdx.x; i < CC * HH; i += 256) atomicAdd(&sums[i], ls[i]);
}

// ---------------- centers -> normalized diffs -> cm contraction -> rcm [C,H] ----------------
__global__ __launch_bounds__(128) void rcm_kernel(const float* __restrict__ sumsx,
                                                  const float* __restrict__ sums0,
                                                  const float* __restrict__ cnt,
                                                  const float* __restrict__ cm,
                                                  float* __restrict__ rcm) {
    __shared__ float cs[CC * HH];
    __shared__ float red[HH];
    int h = threadIdx.x;
    int i = blockIdx.x;
    for (int idx = h; idx < CC * HH; idx += 128) {
        int c = idx >> 7;
        cs[idx] = (sumsx[idx] + 0.1f * sums0[idx]) / fmaxf(cnt[c], 1.0f);
    }
    __syncthreads();
    float ci = cs[i * HH + h];
    float acc = 0.0f;
    for (int j = 0; j < CC; j++) {
        float d = ci - cs[j * HH + h];
        red[h] = d * d;
        __syncthreads();
        for (int s = 64; s > 0; s >>= 1) {
            if (h < s) red[h] += red[h + s];
            __syncthreads();
        }
        float nrm = sqrtf(red[0]);
        if (nrm == 0.0f) nrm = 1.0f;
        acc = fmaf(cm[i * CC + j], d / nrm, acc);
        __syncthreads();
    }
    rcm[i * HH + h] = acc;
}

// ---------------- pr = p @ rcm  (N x 47 @ 47 x 128 -> N x 128, bf16 out) ----------------
__global__ __launch_bounds__(256) void pr_mfma_kernel(const float* __restrict__ p,
                                                      const float* __restrict__ rcm,
                                                      ushort* __restrict__ prb) {
    __shared__ ushort ps[32 * 64];   // A tile (K padded to 64), swizzled
    __shared__ ushort rl[8 * 1024];  // B frags: 8 ksub x 128 cols x 8
    const int rowbase = blockIdx.x * 32;
    for (int idx = threadIdx.x; idx < 8192; idx += 256) {
        int ksub = idx >> 10, rem = idx & 1023;
        int c = rem >> 3, kk = ksub * 8 + (rem & 7);
        rl[idx] = (kk < CC) ? f2bf(rcm[kk * HH + c]) : (ushort)0;
    }
    {
        int t = threadIdx.x;
        int r = t >> 3, kc = (t & 7) * 8;
        const float* prow = p + (size_t)(rowbase + r) * CC;
        short8v v;
        #pragma unroll
        for (int j = 0; j < 8; j++) {
            int k = kc + j;
            v[j] = (short)((k < CC) ? f2bf(prow[k]) : (ushort)0);
        }
        int off = (r * 128 + kc * 2) ^ ((r & 7) << 4);
        *(short8v*)((char*)ps + off) = v;
    }
    __syncthreads();
    const int lane = threadIdx.x & 63, wv = threadIdx.x >> 6;
    const int sub = lane >> 4, r16 = lane & 15;
    const int wbase = wv * 32;
    float4v acc[2][2] = {};
    {
        const char* psc = (const char*)ps;
        const int sw = (r16 & 7) << 4;
        #pragma unroll
        for (int ks = 0; ks < 2; ks++) {
            short8v a0 = *(const short8v*)(psc + ((r16 * 128 + ks * 64 + sub * 16) ^ sw));
            short8v a1 = *(const short8v*)(psc + (((16 + r16) * 128 + ks * 64 + sub * 16) ^ sw));
            int kb = (ks * 4 + sub) * 1024;
            short8v b0 = *(const short8v*)(rl + kb + (wbase + r16) * 8);
            short8v b1 = *(const short8v*)(rl + kb + (wbase + 16 + r16) * 8);
            acc[0][0] = __builtin_amdgcn_mfma_f32_16x16x32_bf16(a0, b0, acc[0][0], 0, 0, 0);
            acc[0][1] = __builtin_amdgcn_mfma_f32_16x16x32_bf16(a0, b1, acc[0][1], 0, 0, 0);
            acc[1][0] = __builtin_amdgcn_mfma_f32_16x16x32_bf16(a1, b0, acc[1][0], 0, 0, 0);
            acc[1][1] = __builtin_amdgcn_mfma_f32_16x16x32_bf16(a1, b1, acc[1][1], 0, 0, 0);
        }
    }
    #pragma unroll
    for (int mi = 0; mi < 2; mi++)
        #pragma unroll
        for (int ni = 0; ni < 2; ni++) {
            int col = wbase + ni * 16 + r16;
            #pragma unroll
            for (int r = 0; r < 4; r++) {
                int row = rowbase + mi * 16 + sub * 4 + r;
                prb[(size_t)row * HH + col] = f2bf(acc[mi][ni][r]);
            }
        }
}

// ---------------- fused: CSR gather + combine -> tb (bf16) ----------------
// t = 0.45*x + 0.45*pr + 0.45*agg + 0.1*x0
__global__ __launch_bounds__(256) void gather_combine_kernel(
    const ushort* __restrict__ xb, const ushort* __restrict__ x0b,
    const ushort* __restrict__ prb,
    const int* __restrict__ rowptr, const int2* __restrict__ csr,
    ushort* __restrict__ tb, int n) {
    const int lane = threadIdx.x & 63;
    const int wid = __builtin_amdgcn_readfirstlane(threadIdx.x >> 6);  // wave-uniform
    for (int nn = blockIdx.x * 4 + wid; nn < n; nn += gridDim.x * 4) {
        int beg = __builtin_amdgcn_readfirstlane(rowptr[nn]);
        int end = __builtin_amdgcn_readfirstlane(rowptr[nn + 1]);
        float accx = 0.0f, accy = 0.0f;
        int e2 = beg;
        for (; e2 + 4 <= end; e2 += 4) {
            int2 ed0 = csr[e2 + 0];
            int2 ed1 = csr[e2 + 1];
            int2 ed2 = csr[e2 + 2];
            int2 ed3 = csr[e2 + 3];
            ushort2 v0 = *(const ushort2*)(xb + (size_t)ed0.x * HH + 2 * lane);
            ushort2 v1 = *(const ushort2*)(xb + (size_t)ed1.x * HH + 2 * lane);
            ushort2 v2 = *(const ushort2*)(xb + (size_t)ed2.x * HH + 2 * lane);
            ushort2 v3 = *(const ushort2*)(xb + (size_t)ed3.x * HH + 2 * lane);
            float w0 = __int_as_float(ed0.y), w1 = __int_as_float(ed1.y);
            float w2 = __int_as_float(ed2.y), w3 = __int_as_float(ed3.y);
            accx = fmaf(w0, b2f(v0.x), accx);
            accy = fmaf(w0, b2f(v0.y), accy);
            accx = fmaf(w1, b2f(v1.x), accx);
            accy = fmaf(w1, b2f(v1.y), accy);
            accx = fmaf(w2, b2f(v2.x), accx);
            accy = fmaf(w2, b2f(v2.y), accy);
            accx = fmaf(w3, b2f(v3.x), accx);
            accy = fmaf(w3, b2f(v3.y), accy);
        }
        for (; e2 < end; e2++) {
            int2 ed = csr[e2];
            ushort2 v = *(const ushort2*)(xb + (size_t)ed.x * HH + 2 * lane);
            float w = __int_as_float(ed.y);
            accx = fmaf(w, b2f(v.x), accx);
            accy = fmaf(w, b2f(v.y), accy);
        }
        ushort2 pv = *(const ushort2*)(prb + (size_t)nn * HH + 2 * lane);
        ushort2 xc = *(const ushort2*)(xb + (size_t)nn * HH + 2 * lane);
        ushort2 xo = *(const ushort2*)(x0b + (size_t)nn * HH + 2 * lane);
        float vx = 0.45f * b2f(xc.x) + 0.45f * b2f(pv.x) + 0.45f * accx + 0.1f * b2f(xo.x);
        float vy = 0.45f * b2f(xc.y) + 0.45f * b2f(pv.y) + 0.45f * accy + 0.1f * b2f(xo.y);
        ushort2 o;
        o.x = f2bf(vx);
        o.y = f2bf(vy);
        *(ushort2*)(tb + (size_t)nn * HH + 2 * lane) = o;
    }
}

extern "C" void kernel_launch(void* const* d_in, const int* in_sizes, int n_in,
                              void* d_out, int out_size, void* d_ws, size_t ws_size,
                              hipStream_t stream) {
    const float* x_in   = (const float*)d_in[0];
    const int*   ei     = (const int*)d_in[1];
    const float* ew     = (const float*)d_in[2];
    const int*   label  = (const int*)d_in[3];
    const float* p      = (const float*)d_in[4];
    const float* cm     = (const float*)d_in[5];
    const float* lin0_w = (const float*)d_in[6];
    const float* lin0_b = (const float*)d_in[7];
    const float* lin1_w = (const float*)d_in[8];
    const float* lin1_b = (const float*)d_in[9];
    const float* conv_w = (const float*)d_in[10];
    float* out = (float*)d_out;

    const int* src = ei;
    const int* dst = ei + EE;

    const size_t NH = (size_t)NN * HH;
    float* ws = (float*)d_ws;
    float* cnt   = ws;                       // 64
    float* sums0 = cnt + 64;                 // CC*HH
    float* sumsx = sums0 + CC * HH;          // CC*HH
    float* rcm   = sumsx + CC * HH;          // CC*HH
    int*   deg    = (int*)(rcm + CC * HH);   // NN (also cursor)
    int*   rowptr = deg + NN;                // NN+1 (+pad)
    int*   bsum   = rowptr + NN + 64;        // 256
    int2*  csr    = (int2*)(bsum + 256);     // EE
    ushort* x0b   = (ushort*)(csr + EE);     // NH bf16
    ushort* xb    = x0b + NH;                // NH bf16
    ushort* tb    = xb + NH;                 // NH bf16
    ushort* wp0   = tb + NH;                 // 16384
    ushort* wpc   = wp0 + 16384;             // 4*16384
    ushort* wp1   = wpc + 4 * 16384;         // 6144 (pad to 8192)
    ushort* prb   = wp1 + 8192;              // NH bf16

    // ---- CSR build (once per call) ----
    hipMemsetAsync(deg, 0, NN * sizeof(int), stream);
    hist_kernel<<<(EE + 255) / 256, 256, 0, stream>>>(dst, deg, EE);
    const int NBLK = (NN + 511) / 512;
    scan_block_kernel<<<NBLK, 256, 0, stream>>>(deg, rowptr, bsum, NN);
    scan_bsum_kernel<<<1, 256, 0, stream>>>(bsum, NBLK);
    add_off_kernel<<<(NN + 255) / 256, 256, 0, stream>>>(rowptr, bsum, NN);
    hipMemsetAsync(deg, 0, NN * sizeof(int), stream);  // reuse as cursor
    fill_kernel<<<(EE + 255) / 256, 256, 0, stream>>>(src, dst, ew, rowptr, deg, csr, EE);

    // ---- pack weights bf16 ----
    pack_w_kernel<<<64, 256, 0, stream>>>(lin0_w, wp0);
    for (int i = 0; i < 4; i++)
        pack_w_kernel<<<64, 256, 0, stream>>>(conv_w + (size_t)i * HH * HH, wpc + (size_t)i * 16384);
    pack_w1_kernel<<<24, 256, 0, stream>>>(lin1_w, wp1);

    // label counts
    hipMemsetAsync(cnt, 0, CC * sizeof(float), stream);
    count_kernel<<<256, 256, 0, stream>>>(label, cnt, NN);

    // input linear + relu (N = 3125 * 32 exactly)
    lin0_mfma_kernel<<<NN / 32, 256, 0, stream>>>(x_in, wp0, lin0_b, x0b, xb);

    // sums0 = sum_label x0 (bf16 rep)
    hipMemsetAsync(sums0, 0, CC * HH * sizeof(float), stream);
    sums_kernel<<<512, 256, 0, stream>>>(x0b, label, sums0, NN);

    const float betas[4] = {logf(0.5f / 1.0f + 1.0f), logf(0.5f / 2.0f + 1.0f),
                            logf(0.5f / 3.0f + 1.0f), logf(0.5f / 4.0f + 1.0f)};

    for (int i = 0; i < 4; i++) {
        if (i == 0) {
            rcm_kernel<<<CC, 128, 0, stream>>>(sums0, sums0, cnt, cm, rcm);
        } else {
            hipMemsetAsync(sumsx, 0, CC * HH * sizeof(float), stream);
            sums_kernel<<<512, 256, 0, stream>>>(xb, label, sumsx, NN);
            rcm_kernel<<<CC, 128, 0, stream>>>(sumsx, sums0, cnt, cm, rcm);
        }
        pr_mfma_kernel<<<NN / 32, 256, 0, stream>>>(p, rcm, prb);
        gather_combine_kernel<<<2048, 256, 0, stream>>>(xb, x0b, prb, rowptr, csr, tb, NN);
        if (i < 3)
            conv_mfma_kernel<<<NN / 32, 256, 0, stream>>>(tb, wpc + (size_t)i * 16384, xb, betas[i]);
        else
            conv_final_kernel<<<NN / 32, 256, 0, stream>>>(tb, wpc + 3 * 16384, wp1, lin1_b, out, betas[3]);
    }
}

// Round 7
// 723.012 us; speedup vs baseline: 4.3386x; 1.3214x over previous
//
#include <hip/hip_runtime.h>
#include <math.h>

#define NN 100000
#define EE 800000
#define CC 47
#define HH 128

typedef __attribute__((ext_vector_type(8))) short short8v;
typedef __attribute__((ext_vector_type(4))) float float4v;

__device__ inline ushort f2bf(float f) {
    unsigned u = __float_as_uint(f);
    unsigned r = (u + 0x7fffu + ((u >> 16) & 1u)) >> 16;  // RNE
    return (ushort)r;
}
__device__ inline float b2f(ushort u) { return __uint_as_float(((unsigned)u) << 16); }

// ---------------- CSR build (edges) ----------------
__global__ __launch_bounds__(256) void hist_kernel(const int* __restrict__ dst,
                                                   int* __restrict__ deg, int e) {
    int i = blockIdx.x * 256 + threadIdx.x;
    if (i < e) atomicAdd(&deg[dst[i]], 1);
}

__global__ __launch_bounds__(256) void scan_block_kernel(const int* __restrict__ deg,
                                                         int* __restrict__ rowptr,
                                                         int* __restrict__ bsum, int n) {
    __shared__ int ls[256];
    int b = blockIdx.x, t = threadIdx.x;
    int i0 = b * 512 + 2 * t;
    int a0 = (i0 < n) ? deg[i0] : 0;
    int a1 = (i0 + 1 < n) ? deg[i0 + 1] : 0;
    int val = a0 + a1;
    ls[t] = val;
    __syncthreads();
    for (int off = 1; off < 256; off <<= 1) {
        int add = (t >= off) ? ls[t - off] : 0;
        __syncthreads();
        val += add;
        ls[t] = val;
        __syncthreads();
    }
    int incl1 = val;
    int incl0 = val - a1;
    if (i0 < n) rowptr[i0 + 1] = incl0;
    if (i0 + 1 < n) rowptr[i0 + 2] = incl1;
    if (t == 255) bsum[b] = val;
}

__global__ __launch_bounds__(256) void scan_bsum_kernel(int* __restrict__ bsum, int nb) {
    __shared__ int ls[256];
    int t = threadIdx.x;
    int v = (t < nb) ? bsum[t] : 0;
    int orig = v;
    ls[t] = v;
    __syncthreads();
    for (int off = 1; off < 256; off <<= 1) {
        int add = (t >= off) ? ls[t - off] : 0;
        __syncthreads();
        v += add;
        ls[t] = v;
        __syncthreads();
    }
    if (t < nb) bsum[t] = v - orig;
}

__global__ __launch_bounds__(256) void add_off_kernel(int* __restrict__ rowptr,
                                                      const int* __restrict__ bsum, int n) {
    int i = blockIdx.x * 256 + threadIdx.x;
    if (i < n) rowptr[i + 1] += bsum[i >> 9];
    if (i == 0) rowptr[0] = 0;
}

__global__ __launch_bounds__(256) void fill_kernel(const int* __restrict__ src,
                                                   const int* __restrict__ dst,
                                                   const float* __restrict__ ew,
                                                   const int* __restrict__ rowptr,
                                                   int* __restrict__ cur,
                                                   int2* __restrict__ csr, int e) {
    int i = blockIdx.x * 256 + threadIdx.x;
    if (i < e) {
        int d = dst[i];
        int pos = rowptr[d] + atomicAdd(&cur[d], 1);
        csr[pos] = make_int2(src[i], __float_as_int(ew[i]));
    }
}

// ---------------- label sort (once): histogram / scan / fill ----------------
__global__ __launch_bounds__(256) void lhist_kernel(const int* __restrict__ label,
                                                    int* __restrict__ lcnt, int n) {
    __shared__ int lh[CC];
    if (threadIdx.x < CC) lh[threadIdx.x] = 0;
    __syncthreads();
    for (int i = blockIdx.x * 256 + threadIdx.x; i < n; i += gridDim.x * 256)
        atomicAdd(&lh[label[i]], 1);
    __syncthreads();
    if (threadIdx.x < CC) atomicAdd(&lcnt[threadIdx.x], lh[threadIdx.x]);
}

__global__ __launch_bounds__(64) void lscan_kernel(const int* __restrict__ lcnt,
                                                   int* __restrict__ lbase,
                                                   int* __restrict__ gcur,
                                                   float* __restrict__ cntf) {
    __shared__ int ls[CC];
    int t = threadIdx.x;
    if (t < CC) {
        int v = lcnt[t];
        cntf[t] = (float)v;
        gcur[t] = 0;
        ls[t] = v;
    }
    __syncthreads();
    if (t == 0) {
        int run = 0;
        for (int c = 0; c < CC; c++) { int x = ls[c]; ls[c] = run; run += x; }
    }
    __syncthreads();
    if (t < CC) lbase[t] = ls[t];
}

__global__ __launch_bounds__(256) void lfill_kernel(const int* __restrict__ label,
                                                    const int* __restrict__ lbase,
                                                    int* __restrict__ gcur,
                                                    int* __restrict__ perm, int n) {
    __shared__ int lh[CC], lbs[CC], lc[CC];
    int t = threadIdx.x;
    if (t < CC) lh[t] = 0;
    __syncthreads();
    int chunk = (n + gridDim.x - 1) / gridDim.x;
    int beg = blockIdx.x * chunk, end = min(n, beg + chunk);
    for (int i = beg + t; i < end; i += 256) atomicAdd(&lh[label[i]], 1);
    __syncthreads();
    if (t < CC) {
        lbs[t] = (lh[t] > 0) ? atomicAdd(&gcur[t], lh[t]) : 0;
        lc[t] = 0;
    }
    __syncthreads();
    for (int i = beg + t; i < end; i += 256) {
        int c = label[i];
        int pos = atomicAdd(&lc[c], 1);
        perm[lbase[c] + lbs[c] + pos] = (c << 24) | i;
    }
}

// ---------------- segment sums via sorted perm: register accumulate ----------------
__global__ __launch_bounds__(256) void psum_kernel(const ushort* __restrict__ xb,
                                                   const int* __restrict__ perm,
                                                   float* __restrict__ sums, int n) {
    const int lane = threadIdx.x & 63;
    const int wid = threadIdx.x >> 6;
    int gw = blockIdx.x * 4 + wid;
    int nw = gridDim.x * 4;
    int per = (n + nw - 1) / nw;
    int beg = gw * per, end = min(n, beg + per);
    if (beg >= end) return;
    float ax = 0.0f, ay = 0.0f;
    int ccur = __builtin_amdgcn_readfirstlane(perm[beg]) >> 24;
    int i = beg;
    while (i < end) {
        if (i + 4 <= end) {
            int p0 = __builtin_amdgcn_readfirstlane(perm[i]);
            int p1 = __builtin_amdgcn_readfirstlane(perm[i + 1]);
            int p2 = __builtin_amdgcn_readfirstlane(perm[i + 2]);
            int p3 = __builtin_amdgcn_readfirstlane(perm[i + 3]);
            if ((p0 >> 24) == (p3 >> 24)) {
                int c = p0 >> 24;
                if (c != ccur) {
                    atomicAdd(&sums[ccur * HH + 2 * lane], ax);
                    atomicAdd(&sums[ccur * HH + 2 * lane + 1], ay);
                    ax = ay = 0.0f;
                    ccur = c;
                }
                ushort2 v0 = *(const ushort2*)(xb + (size_t)(p0 & 0xFFFFFF) * HH + 2 * lane);
                ushort2 v1 = *(const ushort2*)(xb + (size_t)(p1 & 0xFFFFFF) * HH + 2 * lane);
                ushort2 v2 = *(const ushort2*)(xb + (size_t)(p2 & 0xFFFFFF) * HH + 2 * lane);
                ushort2 v3 = *(const ushort2*)(xb + (size_t)(p3 & 0xFFFFFF) * HH + 2 * lane);
                ax += b2f(v0.x) + b2f(v1.x) + b2f(v2.x) + b2f(v3.x);
                ay += b2f(v0.y) + b2f(v1.y) + b2f(v2.y) + b2f(v3.y);
                i += 4;
                continue;
            }
        }
        int pe = __builtin_amdgcn_readfirstlane(perm[i]);
        int c = pe >> 24;
        if (c != ccur) {
            atomicAdd(&sums[ccur * HH + 2 * lane], ax);
            atomicAdd(&sums[ccur * HH + 2 * lane + 1], ay);
            ax = ay = 0.0f;
            ccur = c;
        }
        ushort2 v = *(const ushort2*)(xb + (size_t)(pe & 0xFFFFFF) * HH + 2 * lane);
        ax += b2f(v.x);
        ay += b2f(v.y);
        i += 1;
    }
    atomicAdd(&sums[ccur * HH + 2 * lane], ax);
    atomicAdd(&sums[ccur * HH + 2 * lane + 1], ay);
}

// ---------------- pack weight [128][128] f32 -> MFMA B-fragment order bf16 ----------------
__global__ __launch_bounds__(256) void pack_w_kernel(const float* __restrict__ W,
                                                     ushort* __restrict__ Wp) {
    int idx = blockIdx.x * 256 + threadIdx.x;  // 0..16383
    int k = idx >> 7, c = idx & 127;
    Wp[(k >> 3) * 1024 + c * 8 + (k & 7)] = f2bf(W[idx]);
}

// pack W1 [128][47] -> B-frag order, cols padded to 48. 6144 ushorts.
__global__ __launch_bounds__(256) void pack_w1_kernel(const float* __restrict__ W1,
                                                      ushort* __restrict__ Wp1) {
    int idx = blockIdx.x * 256 + threadIdx.x;  // 0..6143
    if (idx >= 6144) return;
    int ksub = idx / 384, rem = idx - ksub * 384;
    int c = rem >> 3, kk = ksub * 8 + (rem & 7);
    Wp1[idx] = (c < CC) ? f2bf(W1[kk * CC + c]) : (ushort)0;
}

// ---------------- lin0: x0b = xb = relu(xin @ W + b) (bf16) ----------------
__global__ __launch_bounds__(256) void lin0_mfma_kernel(const float* __restrict__ xin,
                                                        const ushort* __restrict__ Wp,
                                                        const float* __restrict__ bias,
                                                        ushort* __restrict__ x0b,
                                                        ushort* __restrict__ xb) {
    __shared__ ushort ts[32 * 128];
    __shared__ ushort wl[128 * 128];
    {
        const uint4* g4 = (const uint4*)Wp;
        uint4* l4 = (uint4*)wl;
        for (int j = threadIdx.x; j < 2048; j += 256) l4[j] = g4[j];
    }
    const int lane = threadIdx.x & 63, wv = threadIdx.x >> 6;
    const int sub = lane >> 4, r16 = lane & 15;
    const int wbase = wv * 32;
    const int rowbase = blockIdx.x * 32;
    const float* tp = xin + (size_t)rowbase * HH;
    #pragma unroll
    for (int j = 0; j < 4; j++) {
        int e = 4 * threadIdx.x + j * 1024;
        float4 f = *(const float4*)(tp + e);
        int r = e >> 7, c = e & 127;
        ushort4 b4 = make_ushort4(f2bf(f.x), f2bf(f.y), f2bf(f.z), f2bf(f.w));
        int off = (r * 256 + c * 2) ^ ((r & 7) << 4);
        *(ushort4*)((char*)ts + off) = b4;
    }
    __syncthreads();
    float4v acc[2][2] = {};
    {
        const char* tsc = (const char*)ts;
        const int sw = (r16 & 7) << 4;
        #pragma unroll
        for (int ks = 0; ks < 4; ks++) {
            short8v a0 = *(const short8v*)(tsc + ((r16 * 256 + ks * 64 + sub * 16) ^ sw));
            short8v a1 = *(const short8v*)(tsc + (((16 + r16) * 256 + ks * 64 + sub * 16) ^ sw));
            int kb = (ks * 4 + sub) * 1024;
            short8v b0 = *(const short8v*)(wl + kb + (wbase + r16) * 8);
            short8v b1 = *(const short8v*)(wl + kb + (wbase + 16 + r16) * 8);
            acc[0][0] = __builtin_amdgcn_mfma_f32_16x16x32_bf16(a0, b0, acc[0][0], 0, 0, 0);
            acc[0][1] = __builtin_amdgcn_mfma_f32_16x16x32_bf16(a0, b1, acc[0][1], 0, 0, 0);
            acc[1][0] = __builtin_amdgcn_mfma_f32_16x16x32_bf16(a1, b0, acc[1][0], 0, 0, 0);
            acc[1][1] = __builtin_amdgcn_mfma_f32_16x16x32_bf16(a1, b1, acc[1][1], 0, 0, 0);
        }
    }
    float bv[2] = {bias[wbase + r16], bias[wbase + 16 + r16]};
    #pragma unroll
    for (int mi = 0; mi < 2; mi++)
        #pragma unroll
        for (int ni = 0; ni < 2; ni++) {
            int col = wbase + ni * 16 + r16;
            #pragma unroll
            for (int r = 0; r < 4; r++) {
                int row = rowbase + mi * 16 + sub * 4 + r;
                float v = fmaxf(acc[mi][ni][r] + bv[ni], 0.0f);
                ushort bv16 = f2bf(v);
                x0b[(size_t)row * HH + col] = bv16;
                xb[(size_t)row * HH + col] = bv16;
            }
        }
}

// ---------------- conv (layers 0-2): xb = relu((1-beta)*t + beta*(t @ W)) ----------------
__global__ __launch_bounds__(256) void conv_mfma_kernel(const ushort* __restrict__ tb,
                                                        const ushort* __restrict__ Wp,
                                                        ushort* __restrict__ xb, float beta) {
    __shared__ ushort ts[32 * 128];
    __shared__ ushort wl[128 * 128];
    {
        const uint4* g4 = (const uint4*)Wp;
        uint4* l4 = (uint4*)wl;
        for (int j = threadIdx.x; j < 2048; j += 256) l4[j] = g4[j];
    }
    const int lane = threadIdx.x & 63, wv = threadIdx.x >> 6;
    const int sub = lane >> 4, r16 = lane & 15;
    const int wbase = wv * 32;
    const int rowbase = blockIdx.x * 32;
    const ushort* tp = tb + (size_t)rowbase * HH;
    #pragma unroll
    for (int j = 0; j < 2; j++) {
        int cid = threadIdx.x + j * 256;
        int e = cid * 8;
        int r = e >> 7;
        int off = (e * 2) ^ ((r & 7) << 4);
        *(short8v*)((char*)ts + off) = *(const short8v*)(tp + e);
    }
    __syncthreads();
    float4v acc[2][2] = {};
    {
        const char* tsc = (const char*)ts;
        const int sw = (r16 & 7) << 4;
        #pragma unroll
        for (int ks = 0; ks < 4; ks++) {
            short8v a0 = *(const short8v*)(tsc + ((r16 * 256 + ks * 64 + sub * 16) ^ sw));
            short8v a1 = *(const short8v*)(tsc + (((16 + r16) * 256 + ks * 64 + sub * 16) ^ sw));
            int kb = (ks * 4 + sub) * 1024;
            short8v b0 = *(const short8v*)(wl + kb + (wbase + r16) * 8);
            short8v b1 = *(const short8v*)(wl + kb + (wbase + 16 + r16) * 8);
            acc[0][0] = __builtin_amdgcn_mfma_f32_16x16x32_bf16(a0, b0, acc[0][0], 0, 0, 0);
            acc[0][1] = __builtin_amdgcn_mfma_f32_16x16x32_bf16(a0, b1, acc[0][1], 0, 0, 0);
            acc[1][0] = __builtin_amdgcn_mfma_f32_16x16x32_bf16(a1, b0, acc[1][0], 0, 0, 0);
            acc[1][1] = __builtin_amdgcn_mfma_f32_16x16x32_bf16(a1, b1, acc[1][1], 0, 0, 0);
        }
    }
    const float omb = 1.0f - beta;
    #pragma unroll
    for (int mi = 0; mi < 2; mi++)
        #pragma unroll
        for (int ni = 0; ni < 2; ni++) {
            int col = wbase + ni * 16 + r16;
            #pragma unroll
            for (int r = 0; r < 4; r++) {
                int rl = mi * 16 + sub * 4 + r;
                int off = (rl * 256 + col * 2) ^ ((rl & 7) << 4);
                float tv = b2f(*(const ushort*)((const char*)ts + off));
                float v = fmaxf(omb * tv + beta * acc[mi][ni][r], 0.0f);
                xb[(size_t)(rowbase + rl) * HH + col] = f2bf(v);
            }
        }
}

// ---------------- conv_final (layer 3): x = relu(conv(t)); out = x @ W1 + b1 ----------------
__global__ __launch_bounds__(256) void conv_final_kernel(const ushort* __restrict__ tb,
                                                         const ushort* __restrict__ Wp,
                                                         const ushort* __restrict__ Wp1,
                                                         const float* __restrict__ b1,
                                                         float* __restrict__ out, float beta) {
    __shared__ ushort ts[32 * 128];
    __shared__ ushort wl[128 * 128];
    __shared__ ushort w1l[6144];
    {
        const uint4* g4 = (const uint4*)Wp;
        uint4* l4 = (uint4*)wl;
        for (int j = threadIdx.x; j < 2048; j += 256) l4[j] = g4[j];
        const uint4* g1 = (const uint4*)Wp1;
        uint4* l1 = (uint4*)w1l;
        for (int j = threadIdx.x; j < 768; j += 256) l1[j] = g1[j];
    }
    const int lane = threadIdx.x & 63, wv = threadIdx.x >> 6;
    const int sub = lane >> 4, r16 = lane & 15;
    const int wbase = wv * 32;
    const int rowbase = blockIdx.x * 32;
    const ushort* tp = tb + (size_t)rowbase * HH;
    #pragma unroll
    for (int j = 0; j < 2; j++) {
        int cid = threadIdx.x + j * 256;
        int e = cid * 8;
        int r = e >> 7;
        int off = (e * 2) ^ ((r & 7) << 4);
        *(short8v*)((char*)ts + off) = *(const short8v*)(tp + e);
    }
    __syncthreads();
    float4v acc[2][2] = {};
    {
        const char* tsc = (const char*)ts;
        const int sw = (r16 & 7) << 4;
        #pragma unroll
        for (int ks = 0; ks < 4; ks++) {
            short8v a0 = *(const short8v*)(tsc + ((r16 * 256 + ks * 64 + sub * 16) ^ sw));
            short8v a1 = *(const short8v*)(tsc + (((16 + r16) * 256 + ks * 64 + sub * 16) ^ sw));
            int kb = (ks * 4 + sub) * 1024;
            short8v b0 = *(const short8v*)(wl + kb + (wbase + r16) * 8);
            short8v b1v = *(const short8v*)(wl + kb + (wbase + 16 + r16) * 8);
            acc[0][0] = __builtin_amdgcn_mfma_f32_16x16x32_bf16(a0, b0, acc[0][0], 0, 0, 0);
            acc[0][1] = __builtin_amdgcn_mfma_f32_16x16x32_bf16(a0, b1v, acc[0][1], 0, 0, 0);
            acc[1][0] = __builtin_amdgcn_mfma_f32_16x16x32_bf16(a1, b0, acc[1][0], 0, 0, 0);
            acc[1][1] = __builtin_amdgcn_mfma_f32_16x16x32_bf16(a1, b1v, acc[1][1], 0, 0, 0);
        }
    }
    __syncthreads();
    const float omb = 1.0f - beta;
    #pragma unroll
    for (int mi = 0; mi < 2; mi++)
        #pragma unroll
        for (int ni = 0; ni < 2; ni++) {
            int col = wbase + ni * 16 + r16;
            #pragma unroll
            for (int r = 0; r < 4; r++) {
                int rl = mi * 16 + sub * 4 + r;
                int off = (rl * 256 + col * 2) ^ ((rl & 7) << 4);
                ushort* slot = (ushort*)((char*)ts + off);
                float tv = b2f(*slot);
                float v = fmaxf(omb * tv + beta * acc[mi][ni][r], 0.0f);
                *slot = f2bf(v);
            }
        }
    __syncthreads();
    if (wv < 3) {
        float4v a2[2] = {};
        const char* tsc = (const char*)ts;
        const int sw = (r16 & 7) << 4;
        #pragma unroll
        for (int ks = 0; ks < 4; ks++) {
            short8v a0 = *(const short8v*)(tsc + ((r16 * 256 + ks * 64 + sub * 16) ^ sw));
            short8v a1 = *(const short8v*)(tsc + (((16 + r16) * 256 + ks * 64 + sub * 16) ^ sw));
            short8v bb = *(const short8v*)(w1l + (ks * 4 + sub) * 384 + (wv * 16 + r16) * 8);
            a2[0] = __builtin_amdgcn_mfma_f32_16x16x32_bf16(a0, bb, a2[0], 0, 0, 0);
            a2[1] = __builtin_amdgcn_mfma_f32_16x16x32_bf16(a1, bb, a2[1], 0, 0, 0);
        }
        int col = wv * 16 + r16;
        if (col < CC) {
            float bias = b1[col];
            #pragma unroll
            for (int mi = 0; mi < 2; mi++)
                #pragma unroll
                for (int r = 0; r < 4; r++) {
                    int row = rowbase + mi * 16 + sub * 4 + r;
                    out[(size_t)row * CC + col] = a2[mi][r] + bias;
                }
        }
    }
}

// ---------------- centers -> normalized diffs -> cm contraction -> rcm [C,H] ----------------
__global__ __launch_bounds__(128) void rcm_kernel(const float* __restrict__ sumsx,
                                                  const float* __restrict__ sums0,
                                                  const float* __restrict__ cnt,
                                                  const float* __restrict__ cm,
                                                  float* __restrict__ rcm) {
    __shared__ float cs[CC * HH];
    __shared__ float red[HH];
    int h = threadIdx.x;
    int i = blockIdx.x;
    for (int idx = h; idx < CC * HH; idx += 128) {
        int c = idx >> 7;
        cs[idx] = (sumsx[idx] + 0.1f * sums0[idx]) / fmaxf(cnt[c], 1.0f);
    }
    __syncthreads();
    float ci = cs[i * HH + h];
    float acc = 0.0f;
    for (int j = 0; j < CC; j++) {
        float d = ci - cs[j * HH + h];
        red[h] = d * d;
        __syncthreads();
        for (int s = 64; s > 0; s >>= 1) {
            if (h < s) red[h] += red[h + s];
            __syncthreads();
        }
        float nrm = sqrtf(red[0]);
        if (nrm == 0.0f) nrm = 1.0f;
        acc = fmaf(cm[i * CC + j], d / nrm, acc);
        __syncthreads();
    }
    rcm[i * HH + h] = acc;
}

// ---------------- pr = p @ rcm  (N x 47 @ 47 x 128 -> N x 128, bf16 out) ----------------
__global__ __launch_bounds__(256) void pr_mfma_kernel(const float* __restrict__ p,
                                                      const float* __restrict__ rcm,
                                                      ushort* __restrict__ prb) {
    __shared__ ushort ps[32 * 64];
    __shared__ ushort rl[8 * 1024];
    const int rowbase = blockIdx.x * 32;
    for (int idx = threadIdx.x; idx < 8192; idx += 256) {
        int ksub = idx >> 10, rem = idx & 1023;
        int c = rem >> 3, kk = ksub * 8 + (rem & 7);
        rl[idx] = (kk < CC) ? f2bf(rcm[kk * HH + c]) : (ushort)0;
    }
    {
        int t = threadIdx.x;
        int r = t >> 3, kc = (t & 7) * 8;
        const float* prow = p + (size_t)(rowbase + r) * CC;
        short8v v;
        #pragma unroll
        for (int j = 0; j < 8; j++) {
            int k = kc + j;
            v[j] = (short)((k < CC) ? f2bf(prow[k]) : (ushort)0);
        }
        int off = (r * 128 + kc * 2) ^ ((r & 7) << 4);
        *(short8v*)((char*)ps + off) = v;
    }
    __syncthreads();
    const int lane = threadIdx.x & 63, wv = threadIdx.x >> 6;
    const int sub = lane >> 4, r16 = lane & 15;
    const int wbase = wv * 32;
    float4v acc[2][2] = {};
    {
        const char* psc = (const char*)ps;
        const int sw = (r16 & 7) << 4;
        #pragma unroll
        for (int ks = 0; ks < 2; ks++) {
            short8v a0 = *(const short8v*)(psc + ((r16 * 128 + ks * 64 + sub * 16) ^ sw));
            short8v a1 = *(const short8v*)(psc + (((16 + r16) * 128 + ks * 64 + sub * 16) ^ sw));
            int kb = (ks * 4 + sub) * 1024;
            short8v b0 = *(const short8v*)(rl + kb + (wbase + r16) * 8);
            short8v b1 = *(const short8v*)(rl + kb + (wbase + 16 + r16) * 8);
            acc[0][0] = __builtin_amdgcn_mfma_f32_16x16x32_bf16(a0, b0, acc[0][0], 0, 0, 0);
            acc[0][1] = __builtin_amdgcn_mfma_f32_16x16x32_bf16(a0, b1, acc[0][1], 0, 0, 0);
            acc[1][0] = __builtin_amdgcn_mfma_f32_16x16x32_bf16(a1, b0, acc[1][0], 0, 0, 0);
            acc[1][1] = __builtin_amdgcn_mfma_f32_16x16x32_bf16(a1, b1, acc[1][1], 0, 0, 0);
        }
    }
    #pragma unroll
    for (int mi = 0; mi < 2; mi++)
        #pragma unroll
        for (int ni = 0; ni < 2; ni++) {
            int col = wbase + ni * 16 + r16;
            #pragma unroll
            for (int r = 0; r < 4; r++) {
                int row = rowbase + mi * 16 + sub * 4 + r;
                prb[(size_t)row * HH + col] = f2bf(acc[mi][ni][r]);
            }
        }
}

// ---------------- fused: CSR gather + combine -> tb (bf16) ----------------
__global__ __launch_bounds__(256) void gather_combine_kernel(
    const ushort* __restrict__ xb, const ushort* __restrict__ x0b,
    const ushort* __restrict__ prb,
    const int* __restrict__ rowptr, const int2* __restrict__ csr,
    ushort* __restrict__ tb, int n) {
    const int lane = threadIdx.x & 63;
    const int wid = __builtin_amdgcn_readfirstlane(threadIdx.x >> 6);
    for (int nn = blockIdx.x * 4 + wid; nn < n; nn += gridDim.x * 4) {
        int beg = __builtin_amdgcn_readfirstlane(rowptr[nn]);
        int end = __builtin_amdgcn_readfirstlane(rowptr[nn + 1]);
        float accx = 0.0f, accy = 0.0f;
        int e2 = beg;
        for (; e2 + 4 <= end; e2 += 4) {
            int2 ed0 = csr[e2 + 0];
            int2 ed1 = csr[e2 + 1];
            int2 ed2 = csr[e2 + 2];
            int2 ed3 = csr[e2 + 3];
            ushort2 v0 = *(const ushort2*)(xb + (size_t)ed0.x * HH + 2 * lane);
            ushort2 v1 = *(const ushort2*)(xb + (size_t)ed1.x * HH + 2 * lane);
            ushort2 v2 = *(const ushort2*)(xb + (size_t)ed2.x * HH + 2 * lane);
            ushort2 v3 = *(const ushort2*)(xb + (size_t)ed3.x * HH + 2 * lane);
            float w0 = __int_as_float(ed0.y), w1 = __int_as_float(ed1.y);
            float w2 = __int_as_float(ed2.y), w3 = __int_as_float(ed3.y);
            accx = fmaf(w0, b2f(v0.x), accx);
            accy = fmaf(w0, b2f(v0.y), accy);
            accx = fmaf(w1, b2f(v1.x), accx);
            accy = fmaf(w1, b2f(v1.y), accy);
            accx = fmaf(w2, b2f(v2.x), accx);
            accy = fmaf(w2, b2f(v2.y), accy);
            accx = fmaf(w3, b2f(v3.x), accx);
            accy = fmaf(w3, b2f(v3.y), accy);
        }
        for (; e2 < end; e2++) {
            int2 ed = csr[e2];
            ushort2 v = *(const ushort2*)(xb + (size_t)ed.x * HH + 2 * lane);
            float w = __int_as_float(ed.y);
            accx = fmaf(w, b2f(v.x), accx);
            accy = fmaf(w, b2f(v.y), accy);
        }
        ushort2 pv = *(const ushort2*)(prb + (size_t)nn * HH + 2 * lane);
        ushort2 xc = *(const ushort2*)(xb + (size_t)nn * HH + 2 * lane);
        ushort2 xo = *(const ushort2*)(x0b + (size_t)nn * HH + 2 * lane);
        float vx = 0.45f * b2f(xc.x) + 0.45f * b2f(pv.x) + 0.45f * accx + 0.1f * b2f(xo.x);
        float vy = 0.45f * b2f(xc.y) + 0.45f * b2f(pv.y) + 0.45f * accy + 0.1f * b2f(xo.y);
        ushort2 o;
        o.x = f2bf(vx);
        o.y = f2bf(vy);
        *(ushort2*)(tb + (size_t)nn * HH + 2 * lane) = o;
    }
}

extern "C" void kernel_launch(void* const* d_in, const int* in_sizes, int n_in,
                              void* d_out, int out_size, void* d_ws, size_t ws_size,
                              hipStream_t stream) {
    const float* x_in   = (const float*)d_in[0];
    const int*   ei     = (const int*)d_in[1];
    const float* ew     = (const float*)d_in[2];
    const int*   label  = (const int*)d_in[3];
    const float* p      = (const float*)d_in[4];
    const float* cm     = (const float*)d_in[5];
    const float* lin0_w = (const float*)d_in[6];
    const float* lin0_b = (const float*)d_in[7];
    const float* lin1_w = (const float*)d_in[8];
    const float* lin1_b = (const float*)d_in[9];
    const float* conv_w = (const float*)d_in[10];
    float* out = (float*)d_out;

    const int* src = ei;
    const int* dst = ei + EE;

    const size_t NH = (size_t)NN * HH;
    float* ws = (float*)d_ws;
    float* cnt   = ws;                       // 64
    float* sums0 = cnt + 64;                 // CC*HH
    float* sumsx = sums0 + CC * HH;          // CC*HH
    float* rcm   = sumsx + CC * HH;          // CC*HH
    int*   deg    = (int*)(rcm + CC * HH);   // NN (also cursor)
    int*   rowptr = deg + NN;                // NN+1 (+pad)
    int*   bsum   = rowptr + NN + 64;        // 256
    int2*  csr    = (int2*)(bsum + 256);     // EE
    ushort* x0b   = (ushort*)(csr + EE);     // NH bf16
    ushort* xb    = x0b + NH;                // NH bf16
    ushort* tb    = xb + NH;                 // NH bf16
    ushort* wp0   = tb + NH;                 // 16384
    ushort* wpc   = wp0 + 16384;             // 4*16384
    ushort* wp1   = wpc + 4 * 16384;         // 6144 (pad to 8192)
    ushort* prb   = wp1 + 8192;              // NH bf16
    int*   lcnt  = (int*)(prb + NH);         // 64
    int*   lbase = lcnt + 64;                // 64
    int*   gcur  = lbase + 64;               // 64
    int*   perm  = gcur + 64;                // NN

    // ---- edge CSR build (once per call) ----
    hipMemsetAsync(deg, 0, NN * sizeof(int), stream);
    hist_kernel<<<(EE + 255) / 256, 256, 0, stream>>>(dst, deg, EE);
    const int NBLK = (NN + 511) / 512;
    scan_block_kernel<<<NBLK, 256, 0, stream>>>(deg, rowptr, bsum, NN);
    scan_bsum_kernel<<<1, 256, 0, stream>>>(bsum, NBLK);
    add_off_kernel<<<(NN + 255) / 256, 256, 0, stream>>>(rowptr, bsum, NN);
    hipMemsetAsync(deg, 0, NN * sizeof(int), stream);  // reuse as cursor
    fill_kernel<<<(EE + 255) / 256, 256, 0, stream>>>(src, dst, ew, rowptr, deg, csr, EE);

    // ---- label sort (once per call): hist / scan / fill ----
    hipMemsetAsync(lcnt, 0, CC * sizeof(int), stream);
    lhist_kernel<<<256, 256, 0, stream>>>(label, lcnt, NN);
    lscan_kernel<<<1, 64, 0, stream>>>(lcnt, lbase, gcur, cnt);
    lfill_kernel<<<256, 256, 0, stream>>>(label, lbase, gcur, perm, NN);

    // ---- pack weights bf16 ----
    pack_w_kernel<<<64, 256, 0, stream>>>(lin0_w, wp0);
    for (int i = 0; i < 4; i++)
        pack_w_kernel<<<64, 256, 0, stream>>>(conv_w + (size_t)i * HH * HH, wpc + (size_t)i * 16384);
    pack_w1_kernel<<<24, 256, 0, stream>>>(lin1_w, wp1);

    // input linear + relu (N = 3125 * 32 exactly)
    lin0_mfma_kernel<<<NN / 32, 256, 0, stream>>>(x_in, wp0, lin0_b, x0b, xb);

    // sums0 = sum_label x0 (bf16 rep)
    hipMemsetAsync(sums0, 0, CC * HH * sizeof(float), stream);
    psum_kernel<<<1024, 256, 0, stream>>>(x0b, perm, sums0, NN);

    const float betas[4] = {logf(0.5f / 1.0f + 1.0f), logf(0.5f / 2.0f + 1.0f),
                            logf(0.5f / 3.0f + 1.0f), logf(0.5f / 4.0f + 1.0f)};

    for (int i = 0; i < 4; i++) {
        if (i == 0) {
            rcm_kernel<<<CC, 128, 0, stream>>>(sums0, sums0, cnt, cm, rcm);
        } else {
            hipMemsetAsync(sumsx, 0, CC * HH * sizeof(float), stream);
            psum_kernel<<<1024, 256, 0, stream>>>(xb, perm, sumsx, NN);
            rcm_kernel<<<CC, 128, 0, stream>>>(sumsx, sums0, cnt, cm, rcm);
        }
        pr_mfma_kernel<<<NN / 32, 256, 0, stream>>>(p, rcm, prb);
        gather_combine_kernel<<<2048, 256, 0, stream>>>(xb, x0b, prb, rowptr, csr, tb, NN);
        if (i < 3)
            conv_mfma_kernel<<<NN / 32, 256, 0, stream>>>(tb, wpc + (size_t)i * 16384, xb, betas[i]);
        else
            conv_final_kernel<<<NN / 32, 256, 0, stream>>>(tb, wpc + 3 * 16384, wp1, lin1_b, out, betas[3]);
    }
}

// Round 8
// 718.757 us; speedup vs baseline: 4.3643x; 1.0059x over previous
//
#include <hip/hip_runtime.h>
#include <math.h>

#define NN 100000
#define EE 800000
#define CC 47
#define HH 128
#define NB 391      // node buckets of 256
#define CHUNK 2000  // edges per coarse block

typedef __attribute__((ext_vector_type(8))) short short8v;
typedef __attribute__((ext_vector_type(4))) float float4v;

__device__ inline ushort f2bf(float f) {
    unsigned u = __float_as_uint(f);
    unsigned r = (u + 0x7fffu + ((u >> 16) & 1u)) >> 16;  // RNE
    return (ushort)r;
}
__device__ inline float b2f(ushort u) { return __uint_as_float(((unsigned)u) << 16); }

// ---------------- node-degree histogram + rowptr scan ----------------
__global__ __launch_bounds__(256) void hist_kernel(const int* __restrict__ dst,
                                                   int* __restrict__ deg, int e) {
    int i = blockIdx.x * 256 + threadIdx.x;
    if (i < e) atomicAdd(&deg[dst[i]], 1);
}

__global__ __launch_bounds__(256) void scan_block_kernel(const int* __restrict__ deg,
                                                         int* __restrict__ rowptr,
                                                         int* __restrict__ bsum, int n) {
    __shared__ int ls[256];
    int b = blockIdx.x, t = threadIdx.x;
    int i0 = b * 512 + 2 * t;
    int a0 = (i0 < n) ? deg[i0] : 0;
    int a1 = (i0 + 1 < n) ? deg[i0 + 1] : 0;
    int val = a0 + a1;
    ls[t] = val;
    __syncthreads();
    for (int off = 1; off < 256; off <<= 1) {
        int add = (t >= off) ? ls[t - off] : 0;
        __syncthreads();
        val += add;
        ls[t] = val;
        __syncthreads();
    }
    int incl1 = val;
    int incl0 = val - a1;
    if (i0 < n) rowptr[i0 + 1] = incl0;
    if (i0 + 1 < n) rowptr[i0 + 2] = incl1;
    if (t == 255) bsum[b] = val;
}

__global__ __launch_bounds__(256) void scan_bsum_kernel(int* __restrict__ bsum, int nb) {
    __shared__ int ls[256];
    int t = threadIdx.x;
    int v = (t < nb) ? bsum[t] : 0;
    int orig = v;
    ls[t] = v;
    __syncthreads();
    for (int off = 1; off < 256; off <<= 1) {
        int add = (t >= off) ? ls[t - off] : 0;
        __syncthreads();
        v += add;
        ls[t] = v;
        __syncthreads();
    }
    if (t < nb) bsum[t] = v - orig;
}

__global__ __launch_bounds__(256) void add_off_kernel(int* __restrict__ rowptr,
                                                      const int* __restrict__ bsum, int n) {
    int i = blockIdx.x * 256 + threadIdx.x;
    if (i < n) rowptr[i + 1] += bsum[i >> 9];
    if (i == 0) rowptr[0] = 0;
}

// ---------------- binned CSR fill ----------------
__global__ __launch_bounds__(256) void init_bcur_kernel(const int* __restrict__ rowptr,
                                                        int* __restrict__ bcur) {
    int b = blockIdx.x * 256 + threadIdx.x;
    if (b < 512) bcur[b] = rowptr[min(b * 256, NN)];
}

// pass 1: counting-sort each 2000-edge chunk by bucket (dst>>8) in LDS, write
// bucket-contiguous runs into staging at final-CSR bucket regions.
__global__ __launch_bounds__(256) void coarse_fill_kernel(const int* __restrict__ src,
                                                          const int* __restrict__ dst,
                                                          const float* __restrict__ ew,
                                                          int* __restrict__ bcur,
                                                          int2* __restrict__ stage, int e) {
    __shared__ int hist[512];
    __shared__ int base_local[512];
    __shared__ int gbase[512];
    __shared__ int lc[512];
    __shared__ int ls[256];
    __shared__ int2 le[CHUNK];
    __shared__ ushort lb[CHUNK];
    int t = threadIdx.x;
    int beg = blockIdx.x * CHUNK, end = min(e, beg + CHUNK);
    int cnt = end - beg;
    for (int i = t; i < 512; i += 256) { hist[i] = 0; lc[i] = 0; }
    __syncthreads();
    for (int i = beg + t; i < end; i += 256) atomicAdd(&hist[((unsigned)dst[i]) >> 8], 1);
    __syncthreads();
    // exclusive scan of hist[0..511] (2 elems/thread, Hillis-Steele)
    int a0 = hist[2 * t], a1 = hist[2 * t + 1];
    int val = a0 + a1;
    ls[t] = val;
    __syncthreads();
    for (int off = 1; off < 256; off <<= 1) {
        int add = (t >= off) ? ls[t - off] : 0;
        __syncthreads();
        val += add;
        ls[t] = val;
        __syncthreads();
    }
    base_local[2 * t] = val - a0 - a1;
    base_local[2 * t + 1] = val - a1;
    __syncthreads();
    // reserve global ranges per bucket
    for (int b = t; b < 512; b += 256)
        if (hist[b] > 0) gbase[b] = atomicAdd(&bcur[b], hist[b]);
    __syncthreads();
    // place edges into LDS grouped by bucket
    for (int i = beg + t; i < end; i += 256) {
        int d = dst[i];
        int bk = ((unsigned)d) >> 8;
        int slot = base_local[bk] + atomicAdd(&lc[bk], 1);
        le[slot] = make_int2(((d & 255) << 24) | src[i], __float_as_int(ew[i]));
        lb[slot] = (ushort)bk;
    }
    __syncthreads();
    // coalesced write-out
    for (int s = t; s < cnt; s += 256) {
        int bk = lb[s];
        stage[gbase[bk] + (s - base_local[bk])] = le[s];
    }
}

// pass 2: exact placement within each bucket's 16KB window (L2-combined)
__global__ __launch_bounds__(256) void fine_fill_kernel(const int2* __restrict__ stage,
                                                        const int* __restrict__ rowptr,
                                                        int2* __restrict__ csr, int n) {
    __shared__ int cur[256];
    __shared__ int rp[257];
    int b = blockIdx.x, t = threadIdx.x;
    int node0 = b * 256;
    int nodes = min(256, n - node0);
    cur[t] = 0;
    rp[t] = rowptr[min(node0 + t, n)];
    if (t == 0) rp[256] = rowptr[min(node0 + 256, n)];
    __syncthreads();
    int S = rp[0], E = rp[nodes];
    for (int i = S + t; i < E; i += 256) {
        int2 en = stage[i];
        int dl = ((unsigned)en.x) >> 24;
        int pos = rp[dl] + atomicAdd(&cur[dl], 1);
        csr[pos] = make_int2(en.x & 0xFFFFFF, en.y);
    }
}

// ---------------- label sort (once): histogram / scan / fill ----------------
__global__ __launch_bounds__(256) void lhist_kernel(const int* __restrict__ label,
                                                    int* __restrict__ lcnt, int n) {
    __shared__ int lh[CC];
    if (threadIdx.x < CC) lh[threadIdx.x] = 0;
    __syncthreads();
    for (int i = blockIdx.x * 256 + threadIdx.x; i < n; i += gridDim.x * 256)
        atomicAdd(&lh[label[i]], 1);
    __syncthreads();
    if (threadIdx.x < CC) atomicAdd(&lcnt[threadIdx.x], lh[threadIdx.x]);
}

__global__ __launch_bounds__(64) void lscan_kernel(const int* __restrict__ lcnt,
                                                   int* __restrict__ lbase,
                                                   int* __restrict__ gcur,
                                                   float* __restrict__ cntf) {
    __shared__ int ls[CC];
    int t = threadIdx.x;
    if (t < CC) {
        int v = lcnt[t];
        cntf[t] = (float)v;
        gcur[t] = 0;
        ls[t] = v;
    }
    __syncthreads();
    if (t == 0) {
        int run = 0;
        for (int c = 0; c < CC; c++) { int x = ls[c]; ls[c] = run; run += x; }
    }
    __syncthreads();
    if (t < CC) lbase[t] = ls[t];
}

__global__ __launch_bounds__(256) void lfill_kernel(const int* __restrict__ label,
                                                    const int* __restrict__ lbase,
                                                    int* __restrict__ gcur,
                                                    int* __restrict__ perm, int n) {
    __shared__ int lh[CC], lbs[CC], lc[CC];
    int t = threadIdx.x;
    if (t < CC) lh[t] = 0;
    __syncthreads();
    int chunk = (n + gridDim.x - 1) / gridDim.x;
    int beg = blockIdx.x * chunk, end = min(n, beg + chunk);
    for (int i = beg + t; i < end; i += 256) atomicAdd(&lh[label[i]], 1);
    __syncthreads();
    if (t < CC) {
        lbs[t] = (lh[t] > 0) ? atomicAdd(&gcur[t], lh[t]) : 0;
        lc[t] = 0;
    }
    __syncthreads();
    for (int i = beg + t; i < end; i += 256) {
        int c = label[i];
        int pos = atomicAdd(&lc[c], 1);
        perm[lbase[c] + lbs[c] + pos] = (c << 24) | i;
    }
}

// ---------------- segment sums via sorted perm: register accumulate ----------------
__global__ __launch_bounds__(256) void psum_kernel(const ushort* __restrict__ xb,
                                                   const int* __restrict__ perm,
                                                   float* __restrict__ sums, int n) {
    const int lane = threadIdx.x & 63;
    const int wid = threadIdx.x >> 6;
    int gw = blockIdx.x * 4 + wid;
    int nw = gridDim.x * 4;
    int per = (n + nw - 1) / nw;
    int beg = gw * per, end = min(n, beg + per);
    if (beg >= end) return;
    float ax = 0.0f, ay = 0.0f;
    int ccur = __builtin_amdgcn_readfirstlane(perm[beg]) >> 24;
    int i = beg;
    while (i < end) {
        if (i + 4 <= end) {
            int p0 = __builtin_amdgcn_readfirstlane(perm[i]);
            int p1 = __builtin_amdgcn_readfirstlane(perm[i + 1]);
            int p2 = __builtin_amdgcn_readfirstlane(perm[i + 2]);
            int p3 = __builtin_amdgcn_readfirstlane(perm[i + 3]);
            if ((p0 >> 24) == (p3 >> 24)) {
                int c = p0 >> 24;
                if (c != ccur) {
                    atomicAdd(&sums[ccur * HH + 2 * lane], ax);
                    atomicAdd(&sums[ccur * HH + 2 * lane + 1], ay);
                    ax = ay = 0.0f;
                    ccur = c;
                }
                ushort2 v0 = *(const ushort2*)(xb + (size_t)(p0 & 0xFFFFFF) * HH + 2 * lane);
                ushort2 v1 = *(const ushort2*)(xb + (size_t)(p1 & 0xFFFFFF) * HH + 2 * lane);
                ushort2 v2 = *(const ushort2*)(xb + (size_t)(p2 & 0xFFFFFF) * HH + 2 * lane);
                ushort2 v3 = *(const ushort2*)(xb + (size_t)(p3 & 0xFFFFFF) * HH + 2 * lane);
                ax += b2f(v0.x) + b2f(v1.x) + b2f(v2.x) + b2f(v3.x);
                ay += b2f(v0.y) + b2f(v1.y) + b2f(v2.y) + b2f(v3.y);
                i += 4;
                continue;
            }
        }
        int pe = __builtin_amdgcn_readfirstlane(perm[i]);
        int c = pe >> 24;
        if (c != ccur) {
            atomicAdd(&sums[ccur * HH + 2 * lane], ax);
            atomicAdd(&sums[ccur * HH + 2 * lane + 1], ay);
            ax = ay = 0.0f;
            ccur = c;
        }
        ushort2 v = *(const ushort2*)(xb + (size_t)(pe & 0xFFFFFF) * HH + 2 * lane);
        ax += b2f(v.x);
        ay += b2f(v.y);
        i += 1;
    }
    atomicAdd(&sums[ccur * HH + 2 * lane], ax);
    atomicAdd(&sums[ccur * HH + 2 * lane + 1], ay);
}

// ---------------- pack weights ----------------
__global__ __launch_bounds__(256) void pack_w_kernel(const float* __restrict__ W,
                                                     ushort* __restrict__ Wp) {
    int idx = blockIdx.x * 256 + threadIdx.x;  // 0..16383
    int k = idx >> 7, c = idx & 127;
    Wp[(k >> 3) * 1024 + c * 8 + (k & 7)] = f2bf(W[idx]);
}

__global__ __launch_bounds__(256) void pack_w1_kernel(const float* __restrict__ W1,
                                                      ushort* __restrict__ Wp1) {
    int idx = blockIdx.x * 256 + threadIdx.x;  // 0..6143
    if (idx >= 6144) return;
    int ksub = idx / 384, rem = idx - ksub * 384;
    int c = rem >> 3, kk = ksub * 8 + (rem & 7);
    Wp1[idx] = (c < CC) ? f2bf(W1[kk * CC + c]) : (ushort)0;
}

// ---------------- lin0: x0b = xb = relu(xin @ W + b) (bf16) ----------------
__global__ __launch_bounds__(256) void lin0_mfma_kernel(const float* __restrict__ xin,
                                                        const ushort* __restrict__ Wp,
                                                        const float* __restrict__ bias,
                                                        ushort* __restrict__ x0b,
                                                        ushort* __restrict__ xb) {
    __shared__ ushort ts[32 * 128];
    __shared__ ushort wl[128 * 128];
    {
        const uint4* g4 = (const uint4*)Wp;
        uint4* l4 = (uint4*)wl;
        for (int j = threadIdx.x; j < 2048; j += 256) l4[j] = g4[j];
    }
    const int lane = threadIdx.x & 63, wv = threadIdx.x >> 6;
    const int sub = lane >> 4, r16 = lane & 15;
    const int wbase = wv * 32;
    const int rowbase = blockIdx.x * 32;
    const float* tp = xin + (size_t)rowbase * HH;
    #pragma unroll
    for (int j = 0; j < 4; j++) {
        int e = 4 * threadIdx.x + j * 1024;
        float4 f = *(const float4*)(tp + e);
        int r = e >> 7, c = e & 127;
        ushort4 b4 = make_ushort4(f2bf(f.x), f2bf(f.y), f2bf(f.z), f2bf(f.w));
        int off = (r * 256 + c * 2) ^ ((r & 7) << 4);
        *(ushort4*)((char*)ts + off) = b4;
    }
    __syncthreads();
    float4v acc[2][2] = {};
    {
        const char* tsc = (const char*)ts;
        const int sw = (r16 & 7) << 4;
        #pragma unroll
        for (int ks = 0; ks < 4; ks++) {
            short8v a0 = *(const short8v*)(tsc + ((r16 * 256 + ks * 64 + sub * 16) ^ sw));
            short8v a1 = *(const short8v*)(tsc + (((16 + r16) * 256 + ks * 64 + sub * 16) ^ sw));
            int kb = (ks * 4 + sub) * 1024;
            short8v b0 = *(const short8v*)(wl + kb + (wbase + r16) * 8);
            short8v b1 = *(const short8v*)(wl + kb + (wbase + 16 + r16) * 8);
            acc[0][0] = __builtin_amdgcn_mfma_f32_16x16x32_bf16(a0, b0, acc[0][0], 0, 0, 0);
            acc[0][1] = __builtin_amdgcn_mfma_f32_16x16x32_bf16(a0, b1, acc[0][1], 0, 0, 0);
            acc[1][0] = __builtin_amdgcn_mfma_f32_16x16x32_bf16(a1, b0, acc[1][0], 0, 0, 0);
            acc[1][1] = __builtin_amdgcn_mfma_f32_16x16x32_bf16(a1, b1, acc[1][1], 0, 0, 0);
        }
    }
    float bv[2] = {bias[wbase + r16], bias[wbase + 16 + r16]};
    #pragma unroll
    for (int mi = 0; mi < 2; mi++)
        #pragma unroll
        for (int ni = 0; ni < 2; ni++) {
            int col = wbase + ni * 16 + r16;
            #pragma unroll
            for (int r = 0; r < 4; r++) {
                int row = rowbase + mi * 16 + sub * 4 + r;
                float v = fmaxf(acc[mi][ni][r] + bv[ni], 0.0f);
                ushort bv16 = f2bf(v);
                x0b[(size_t)row * HH + col] = bv16;
                xb[(size_t)row * HH + col] = bv16;
            }
        }
}

// ---------------- centers -> normalized diffs -> cm contraction -> rcm [C,H] ----------------
__global__ __launch_bounds__(128) void rcm_kernel(const float* __restrict__ sumsx,
                                                  const float* __restrict__ sums0,
                                                  const float* __restrict__ cnt,
                                                  const float* __restrict__ cm,
                                                  float* __restrict__ rcm) {
    __shared__ float cs[CC * HH];
    __shared__ float red[HH];
    int h = threadIdx.x;
    int i = blockIdx.x;
    for (int idx = h; idx < CC * HH; idx += 128) {
        int c = idx >> 7;
        cs[idx] = (sumsx[idx] + 0.1f * sums0[idx]) / fmaxf(cnt[c], 1.0f);
    }
    __syncthreads();
    float ci = cs[i * HH + h];
    float acc = 0.0f;
    for (int j = 0; j < CC; j++) {
        float d = ci - cs[j * HH + h];
        red[h] = d * d;
        __syncthreads();
        for (int s = 64; s > 0; s >>= 1) {
            if (h < s) red[h] += red[h + s];
            __syncthreads();
        }
        float nrm = sqrtf(red[0]);
        if (nrm == 0.0f) nrm = 1.0f;
        acc = fmaf(cm[i * CC + j], d / nrm, acc);
        __syncthreads();
    }
    rcm[i * HH + h] = acc;
}

// ---------------- pr = p @ rcm  (N x 47 @ 47 x 128 -> N x 128, bf16 out) ----------------
__global__ __launch_bounds__(256) void pr_mfma_kernel(const float* __restrict__ p,
                                                      const float* __restrict__ rcm,
                                                      ushort* __restrict__ prb) {
    __shared__ ushort ps[32 * 64];
    __shared__ ushort rl[8 * 1024];
    const int rowbase = blockIdx.x * 32;
    for (int idx = threadIdx.x; idx < 8192; idx += 256) {
        int ksub = idx >> 10, rem = idx & 1023;
        int c = rem >> 3, kk = ksub * 8 + (rem & 7);
        rl[idx] = (kk < CC) ? f2bf(rcm[kk * HH + c]) : (ushort)0;
    }
    {
        int t = threadIdx.x;
        int r = t >> 3, kc = (t & 7) * 8;
        const float* prow = p + (size_t)(rowbase + r) * CC;
        short8v v;
        #pragma unroll
        for (int j = 0; j < 8; j++) {
            int k = kc + j;
            v[j] = (short)((k < CC) ? f2bf(prow[k]) : (ushort)0);
        }
        int off = (r * 128 + kc * 2) ^ ((r & 7) << 4);
        *(short8v*)((char*)ps + off) = v;
    }
    __syncthreads();
    const int lane = threadIdx.x & 63, wv = threadIdx.x >> 6;
    const int sub = lane >> 4, r16 = lane & 15;
    const int wbase = wv * 32;
    float4v acc[2][2] = {};
    {
        const char* psc = (const char*)ps;
        const int sw = (r16 & 7) << 4;
        #pragma unroll
        for (int ks = 0; ks < 2; ks++) {
            short8v a0 = *(const short8v*)(psc + ((r16 * 128 + ks * 64 + sub * 16) ^ sw));
            short8v a1 = *(const short8v*)(psc + (((16 + r16) * 128 + ks * 64 + sub * 16) ^ sw));
            int kb = (ks * 4 + sub) * 1024;
            short8v b0 = *(const short8v*)(rl + kb + (wbase + r16) * 8);
            short8v b1 = *(const short8v*)(rl + kb + (wbase + 16 + r16) * 8);
            acc[0][0] = __builtin_amdgcn_mfma_f32_16x16x32_bf16(a0, b0, acc[0][0], 0, 0, 0);
            acc[0][1] = __builtin_amdgcn_mfma_f32_16x16x32_bf16(a0, b1, acc[0][1], 0, 0, 0);
            acc[1][0] = __builtin_amdgcn_mfma_f32_16x16x32_bf16(a1, b0, acc[1][0], 0, 0, 0);
            acc[1][1] = __builtin_amdgcn_mfma_f32_16x16x32_bf16(a1, b1, acc[1][1], 0, 0, 0);
        }
    }
    #pragma unroll
    for (int mi = 0; mi < 2; mi++)
        #pragma unroll
        for (int ni = 0; ni < 2; ni++) {
            int col = wbase + ni * 16 + r16;
            #pragma unroll
            for (int r = 0; r < 4; r++) {
                int row = rowbase + mi * 16 + sub * 4 + r;
                prb[(size_t)row * HH + col] = f2bf(acc[mi][ni][r]);
            }
        }
}

// ---------------- fused layer: gather+combine -> LDS tile -> conv MFMA (-> final GEMM) ----------------
template <int FINAL>
__global__ __launch_bounds__(512) void layer_kernel(
    const ushort* __restrict__ xin, const ushort* __restrict__ x0b,
    const ushort* __restrict__ prb,
    const int* __restrict__ rowptr, const int2* __restrict__ csr,
    const ushort* __restrict__ Wp,
    const ushort* __restrict__ Wp1, const float* __restrict__ b1,
    ushort* __restrict__ xout, float* __restrict__ out, float beta) {
    __shared__ ushort wl[128 * 128];
    __shared__ ushort ts[32 * 128];
    __shared__ ushort w1l[FINAL ? 6144 : 64];
    {
        const uint4* g4 = (const uint4*)Wp;
        uint4* l4 = (uint4*)wl;
        for (int j = threadIdx.x; j < 2048; j += 512) l4[j] = g4[j];
        if constexpr (FINAL) {
            const uint4* g1 = (const uint4*)Wp1;
            uint4* l1 = (uint4*)w1l;
            for (int j = threadIdx.x; j < 768; j += 512) l1[j] = g1[j];
        }
    }
    const int lane = threadIdx.x & 63;
    const int wv = __builtin_amdgcn_readfirstlane(threadIdx.x >> 6);
    const int rowbase = blockIdx.x * 32;
    // ---- gather + combine -> ts (swizzled bf16 tile) ----
    #pragma unroll 1
    for (int k = 0; k < 4; k++) {
        int rloc = 4 * wv + k;
        int nn = rowbase + rloc;
        int beg = __builtin_amdgcn_readfirstlane(rowptr[nn]);
        int end = __builtin_amdgcn_readfirstlane(rowptr[nn + 1]);
        float accx = 0.0f, accy = 0.0f;
        int e2 = beg;
        for (; e2 + 4 <= end; e2 += 4) {
            int2 ed0 = csr[e2 + 0];
            int2 ed1 = csr[e2 + 1];
            int2 ed2 = csr[e2 + 2];
            int2 ed3 = csr[e2 + 3];
            ushort2 v0 = *(const ushort2*)(xin + (size_t)ed0.x * HH + 2 * lane);
            ushort2 v1 = *(const ushort2*)(xin + (size_t)ed1.x * HH + 2 * lane);
            ushort2 v2 = *(const ushort2*)(xin + (size_t)ed2.x * HH + 2 * lane);
            ushort2 v3 = *(const ushort2*)(xin + (size_t)ed3.x * HH + 2 * lane);
            float w0 = __int_as_float(ed0.y), w1 = __int_as_float(ed1.y);
            float w2 = __int_as_float(ed2.y), w3 = __int_as_float(ed3.y);
            accx = fmaf(w0, b2f(v0.x), accx);
            accy = fmaf(w0, b2f(v0.y), accy);
            accx = fmaf(w1, b2f(v1.x), accx);
            accy = fmaf(w1, b2f(v1.y), accy);
            accx = fmaf(w2, b2f(v2.x), accx);
            accy = fmaf(w2, b2f(v2.y), accy);
            accx = fmaf(w3, b2f(v3.x), accx);
            accy = fmaf(w3, b2f(v3.y), accy);
        }
        for (; e2 < end; e2++) {
            int2 ed = csr[e2];
            ushort2 v = *(const ushort2*)(xin + (size_t)ed.x * HH + 2 * lane);
            float w = __int_as_float(ed.y);
            accx = fmaf(w, b2f(v.x), accx);
            accy = fmaf(w, b2f(v.y), accy);
        }
        ushort2 pv = *(const ushort2*)(prb + (size_t)nn * HH + 2 * lane);
        ushort2 xc = *(const ushort2*)(xin + (size_t)nn * HH + 2 * lane);
        ushort2 xo = *(const ushort2*)(x0b + (size_t)nn * HH + 2 * lane);
        ushort2 o;
        o.x = f2bf(0.45f * b2f(xc.x) + 0.45f * b2f(pv.x) + 0.45f * accx + 0.1f * b2f(xo.x));
        o.y = f2bf(0.45f * b2f(xc.y) + 0.45f * b2f(pv.y) + 0.45f * accy + 0.1f * b2f(xo.y));
        *(ushort2*)((char*)ts + ((rloc * 256 + lane * 4) ^ ((rloc & 7) << 4))) = o;
    }
    __syncthreads();
    // ---- conv MFMA: wave wv owns cols [16wv, 16wv+16) ----
    const int sub = lane >> 4, r16 = lane & 15;
    const int sw = (r16 & 7) << 4;
    const char* tsc = (const char*)ts;
    float4v acc[2] = {};
    #pragma unroll
    for (int ks = 0; ks < 4; ks++) {
        short8v a0 = *(const short8v*)(tsc + ((r16 * 256 + ks * 64 + sub * 16) ^ sw));
        short8v a1 = *(const short8v*)(tsc + (((16 + r16) * 256 + ks * 64 + sub * 16) ^ sw));
        short8v bb = *(const short8v*)(wl + (ks * 4 + sub) * 1024 + (16 * wv + r16) * 8);
        acc[0] = __builtin_amdgcn_mfma_f32_16x16x32_bf16(a0, bb, acc[0], 0, 0, 0);
        acc[1] = __builtin_amdgcn_mfma_f32_16x16x32_bf16(a1, bb, acc[1], 0, 0, 0);
    }
    const float omb = 1.0f - beta;
    const int col = 16 * wv + r16;
    if constexpr (!FINAL) {
        #pragma unroll
        for (int mi = 0; mi < 2; mi++)
            #pragma unroll
            for (int r = 0; r < 4; r++) {
                int rl_ = mi * 16 + sub * 4 + r;
                int toff = (rl_ * 256 + col * 2) ^ ((rl_ & 7) << 4);
                float tv = b2f(*(const ushort*)(tsc + toff));
                float v = fmaxf(omb * tv + beta * acc[mi][r], 0.0f);
                xout[(size_t)(rowbase + rl_) * HH + col] = f2bf(v);
            }
    } else {
        __syncthreads();  // all frag reads of ts done
        #pragma unroll
        for (int mi = 0; mi < 2; mi++)
            #pragma unroll
            for (int r = 0; r < 4; r++) {
                int rl_ = mi * 16 + sub * 4 + r;
                int toff = (rl_ * 256 + col * 2) ^ ((rl_ & 7) << 4);
                ushort* slot = (ushort*)((char*)ts + toff);
                float tv = b2f(*slot);
                float v = fmaxf(omb * tv + beta * acc[mi][r], 0.0f);
                *slot = f2bf(v);
            }
        __syncthreads();
        if (wv < 3) {
            float4v a2[2] = {};
            #pragma unroll
            for (int ks = 0; ks < 4; ks++) {
                short8v a0 = *(const short8v*)(tsc + ((r16 * 256 + ks * 64 + sub * 16) ^ sw));
                short8v a1 = *(const short8v*)(tsc + (((16 + r16) * 256 + ks * 64 + sub * 16) ^ sw));
                short8v bb = *(const short8v*)(w1l + (ks * 4 + sub) * 384 + (wv * 16 + r16) * 8);
                a2[0] = __builtin_amdgcn_mfma_f32_16x16x32_bf16(a0, bb, a2[0], 0, 0, 0);
                a2[1] = __builtin_amdgcn_mfma_f32_16x16x32_bf16(a1, bb, a2[1], 0, 0, 0);
            }
            int col2 = wv * 16 + r16;
            if (col2 < CC) {
                float bias = b1[col2];
                #pragma unroll
                for (int mi = 0; mi < 2; mi++)
                    #pragma unroll
                    for (int r = 0; r < 4; r++) {
                        int row = rowbase + mi * 16 + sub * 4 + r;
                        out[(size_t)row * CC + col2] = a2[mi][r] + bias;
                    }
            }
        }
    }
}

extern "C" void kernel_launch(void* const* d_in, const int* in_sizes, int n_in,
                              void* d_out, int out_size, void* d_ws, size_t ws_size,
                              hipStream_t stream) {
    const float* x_in   = (const float*)d_in[0];
    const int*   ei     = (const int*)d_in[1];
    const float* ew     = (const float*)d_in[2];
    const int*   label  = (const int*)d_in[3];
    const float* p      = (const float*)d_in[4];
    const float* cm     = (const float*)d_in[5];
    const float* lin0_w = (const float*)d_in[6];
    const float* lin0_b = (const float*)d_in[7];
    const float* lin1_w = (const float*)d_in[8];
    const float* lin1_b = (const float*)d_in[9];
    const float* conv_w = (const float*)d_in[10];
    float* out = (float*)d_out;

    const int* src = ei;
    const int* dst = ei + EE;

    const size_t NH = (size_t)NN * HH;
    float* ws = (float*)d_ws;
    float* cnt   = ws;                       // 64
    float* sums0 = cnt + 64;                 // CC*HH
    float* sumsx = sums0 + CC * HH;          // CC*HH
    float* rcm   = sumsx + CC * HH;          // CC*HH
    int*   deg    = (int*)(rcm + CC * HH);   // NN
    int*   rowptr = deg + NN;                // NN+1 (+pad)
    int*   bsum   = rowptr + NN + 64;        // 256
    int*   bcur   = bsum + 256;              // 512
    int*   lcnt   = bcur + 512;              // 64
    int*   lbase  = lcnt + 64;               // 64
    int*   gcur   = lbase + 64;              // 64
    int*   perm   = gcur + 64;               // NN
    int2*  csr    = (int2*)(perm + NN);      // EE
    int2*  stage  = csr + EE;                // EE
    ushort* x0b   = (ushort*)(stage + EE);   // NH bf16
    ushort* xbA   = x0b + NH;                // NH bf16
    ushort* xbB   = xbA + NH;                // NH bf16
    ushort* prb   = xbB + NH;                // NH bf16
    ushort* wp0   = prb + NH;                // 16384
    ushort* wpc   = wp0 + 16384;             // 4*16384
    ushort* wp1   = wpc + 4 * 16384;         // 6144 (pad to 8192)

    // ---- edge CSR build: hist -> rowptr -> binned two-pass fill ----
    hipMemsetAsync(deg, 0, NN * sizeof(int), stream);
    hist_kernel<<<(EE + 255) / 256, 256, 0, stream>>>(dst, deg, EE);
    const int NBLK = (NN + 511) / 512;
    scan_block_kernel<<<NBLK, 256, 0, stream>>>(deg, rowptr, bsum, NN);
    scan_bsum_kernel<<<1, 256, 0, stream>>>(bsum, NBLK);
    add_off_kernel<<<(NN + 255) / 256, 256, 0, stream>>>(rowptr, bsum, NN);
    init_bcur_kernel<<<2, 256, 0, stream>>>(rowptr, bcur);
    coarse_fill_kernel<<<(EE + CHUNK - 1) / CHUNK, 256, 0, stream>>>(src, dst, ew, bcur, stage, EE);
    fine_fill_kernel<<<NB, 256, 0, stream>>>(stage, rowptr, csr, NN);

    // ---- label sort (once per call) ----
    hipMemsetAsync(lcnt, 0, CC * sizeof(int), stream);
    lhist_kernel<<<256, 256, 0, stream>>>(label, lcnt, NN);
    lscan_kernel<<<1, 64, 0, stream>>>(lcnt, lbase, gcur, cnt);
    lfill_kernel<<<256, 256, 0, stream>>>(label, lbase, gcur, perm, NN);

    // ---- pack weights bf16 ----
    pack_w_kernel<<<64, 256, 0, stream>>>(lin0_w, wp0);
    for (int i = 0; i < 4; i++)
        pack_w_kernel<<<64, 256, 0, stream>>>(conv_w + (size_t)i * HH * HH, wpc + (size_t)i * 16384);
    pack_w1_kernel<<<24, 256, 0, stream>>>(lin1_w, wp1);

    // input linear + relu (N = 3125 * 32 exactly)
    lin0_mfma_kernel<<<NN / 32, 256, 0, stream>>>(x_in, wp0, lin0_b, x0b, xbA);

    // sums0 = sum_label x0
    hipMemsetAsync(sums0, 0, CC * HH * sizeof(float), stream);
    psum_kernel<<<2048, 256, 0, stream>>>(x0b, perm, sums0, NN);

    const float betas[4] = {logf(0.5f / 1.0f + 1.0f), logf(0.5f / 2.0f + 1.0f),
                            logf(0.5f / 3.0f + 1.0f), logf(0.5f / 4.0f + 1.0f)};

    ushort* xin_b = xbA;
    ushort* xout_b = xbB;
    for (int i = 0; i < 4; i++) {
        if (i == 0) {
            rcm_kernel<<<CC, 128, 0, stream>>>(sums0, sums0, cnt, cm, rcm);
        } else {
            hipMemsetAsync(sumsx, 0, CC * HH * sizeof(float), stream);
            psum_kernel<<<2048, 256, 0, stream>>>(xin_b, perm, sumsx, NN);
            rcm_kernel<<<CC, 128, 0, stream>>>(sumsx, sums0, cnt, cm, rcm);
        }
        pr_mfma_kernel<<<NN / 32, 256, 0, stream>>>(p, rcm, prb);
        if (i < 3) {
            layer_kernel<0><<<NN / 32, 512, 0, stream>>>(xin_b, x0b, prb, rowptr, csr,
                                                         wpc + (size_t)i * 16384, wp1, lin1_b,
                                                         xout_b, out, betas[i]);
            ushort* tmp = xin_b; xin_b = xout_b; xout_b = tmp;
        } else {
            layer_kernel<1><<<NN / 32, 512, 0, stream>>>(xin_b, x0b, prb, rowptr, csr,
                                                         wpc + 3 * 16384, wp1, lin1_b,
                                                         xout_b, out, betas[3]);
        }
    }
}

// Round 9
// 609.270 us; speedup vs baseline: 5.1486x; 1.1797x over previous
//
#include <hip/hip_runtime.h>
#include <math.h>

#define NN 100000
#define EE 800000
#define CC 47
#define HH 128
#define NB 391      // node buckets of 256
#define CHUNK 2000  // edges per coarse block

typedef __attribute__((ext_vector_type(8))) short short8v;
typedef __attribute__((ext_vector_type(4))) float float4v;

__device__ inline ushort f2bf(float f) {
    unsigned u = __float_as_uint(f);
    unsigned r = (u + 0x7fffu + ((u >> 16) & 1u)) >> 16;  // RNE
    return (ushort)r;
}
__device__ inline float b2f(ushort u) { return __uint_as_float(((unsigned)u) << 16); }

// ---------------- node-degree histogram + rowptr scan ----------------
__global__ __launch_bounds__(256) void hist_kernel(const int* __restrict__ dst,
                                                   int* __restrict__ deg, int e) {
    int i = blockIdx.x * 256 + threadIdx.x;
    if (i < e) atomicAdd(&deg[dst[i]], 1);
}

__global__ __launch_bounds__(256) void scan_block_kernel(const int* __restrict__ deg,
                                                         int* __restrict__ rowptr,
                                                         int* __restrict__ bsum, int n) {
    __shared__ int ls[256];
    int b = blockIdx.x, t = threadIdx.x;
    int i0 = b * 512 + 2 * t;
    int a0 = (i0 < n) ? deg[i0] : 0;
    int a1 = (i0 + 1 < n) ? deg[i0 + 1] : 0;
    int val = a0 + a1;
    ls[t] = val;
    __syncthreads();
    for (int off = 1; off < 256; off <<= 1) {
        int add = (t >= off) ? ls[t - off] : 0;
        __syncthreads();
        val += add;
        ls[t] = val;
        __syncthreads();
    }
    int incl1 = val;
    int incl0 = val - a1;
    if (i0 < n) rowptr[i0 + 1] = incl0;
    if (i0 + 1 < n) rowptr[i0 + 2] = incl1;
    if (t == 255) bsum[b] = val;
}

__global__ __launch_bounds__(256) void scan_bsum_kernel(int* __restrict__ bsum, int nb) {
    __shared__ int ls[256];
    int t = threadIdx.x;
    int v = (t < nb) ? bsum[t] : 0;
    int orig = v;
    ls[t] = v;
    __syncthreads();
    for (int off = 1; off < 256; off <<= 1) {
        int add = (t >= off) ? ls[t - off] : 0;
        __syncthreads();
        v += add;
        ls[t] = v;
        __syncthreads();
    }
    if (t < nb) bsum[t] = v - orig;
}

__global__ __launch_bounds__(256) void add_off_kernel(int* __restrict__ rowptr,
                                                      const int* __restrict__ bsum, int n) {
    int i = blockIdx.x * 256 + threadIdx.x;
    if (i < n) rowptr[i + 1] += bsum[i >> 9];
    if (i == 0) rowptr[0] = 0;
}

// ---------------- binned CSR fill ----------------
__global__ __launch_bounds__(256) void init_bcur_kernel(const int* __restrict__ rowptr,
                                                        int* __restrict__ bcur) {
    int b = blockIdx.x * 256 + threadIdx.x;
    if (b < 512) bcur[b] = rowptr[min(b * 256, NN)];
}

__global__ __launch_bounds__(256) void coarse_fill_kernel(const int* __restrict__ src,
                                                          const int* __restrict__ dst,
                                                          const float* __restrict__ ew,
                                                          int* __restrict__ bcur,
                                                          int2* __restrict__ stage, int e) {
    __shared__ int hist[512];
    __shared__ int base_local[512];
    __shared__ int gbase[512];
    __shared__ int lc[512];
    __shared__ int ls[256];
    __shared__ int2 le[CHUNK];
    __shared__ ushort lb[CHUNK];
    int t = threadIdx.x;
    int beg = blockIdx.x * CHUNK, end = min(e, beg + CHUNK);
    int cnt = end - beg;
    for (int i = t; i < 512; i += 256) { hist[i] = 0; lc[i] = 0; }
    __syncthreads();
    for (int i = beg + t; i < end; i += 256) atomicAdd(&hist[((unsigned)dst[i]) >> 8], 1);
    __syncthreads();
    int a0 = hist[2 * t], a1 = hist[2 * t + 1];
    int val = a0 + a1;
    ls[t] = val;
    __syncthreads();
    for (int off = 1; off < 256; off <<= 1) {
        int add = (t >= off) ? ls[t - off] : 0;
        __syncthreads();
        val += add;
        ls[t] = val;
        __syncthreads();
    }
    base_local[2 * t] = val - a0 - a1;
    base_local[2 * t + 1] = val - a1;
    __syncthreads();
    for (int b = t; b < 512; b += 256)
        if (hist[b] > 0) gbase[b] = atomicAdd(&bcur[b], hist[b]);
    __syncthreads();
    for (int i = beg + t; i < end; i += 256) {
        int d = dst[i];
        int bk = ((unsigned)d) >> 8;
        int slot = base_local[bk] + atomicAdd(&lc[bk], 1);
        le[slot] = make_int2(((d & 255) << 24) | src[i], __float_as_int(ew[i]));
        lb[slot] = (ushort)bk;
    }
    __syncthreads();
    for (int s = t; s < cnt; s += 256) {
        int bk = lb[s];
        stage[gbase[bk] + (s - base_local[bk])] = le[s];
    }
}

__global__ __launch_bounds__(256) void fine_fill_kernel(const int2* __restrict__ stage,
                                                        const int* __restrict__ rowptr,
                                                        int2* __restrict__ csr, int n) {
    __shared__ int cur[256];
    __shared__ int rp[257];
    int b = blockIdx.x, t = threadIdx.x;
    int node0 = b * 256;
    int nodes = min(256, n - node0);
    cur[t] = 0;
    rp[t] = rowptr[min(node0 + t, n)];
    if (t == 0) rp[256] = rowptr[min(node0 + 256, n)];
    __syncthreads();
    int S = rp[0], E = rp[nodes];
    for (int i = S + t; i < E; i += 256) {
        int2 en = stage[i];
        int dl = ((unsigned)en.x) >> 24;
        int pos = rp[dl] + atomicAdd(&cur[dl], 1);
        csr[pos] = make_int2(en.x & 0xFFFFFF, en.y);
    }
}

// ---------------- label sort (once) ----------------
__global__ __launch_bounds__(256) void lhist_kernel(const int* __restrict__ label,
                                                    int* __restrict__ lcnt, int n) {
    __shared__ int lh[CC];
    if (threadIdx.x < CC) lh[threadIdx.x] = 0;
    __syncthreads();
    for (int i = blockIdx.x * 256 + threadIdx.x; i < n; i += gridDim.x * 256)
        atomicAdd(&lh[label[i]], 1);
    __syncthreads();
    if (threadIdx.x < CC) atomicAdd(&lcnt[threadIdx.x], lh[threadIdx.x]);
}

__global__ __launch_bounds__(64) void lscan_kernel(const int* __restrict__ lcnt,
                                                   int* __restrict__ lbase,
                                                   int* __restrict__ gcur,
                                                   float* __restrict__ cntf) {
    __shared__ int ls[CC];
    int t = threadIdx.x;
    if (t < CC) {
        int v = lcnt[t];
        cntf[t] = (float)v;
        gcur[t] = 0;
        ls[t] = v;
    }
    __syncthreads();
    if (t == 0) {
        int run = 0;
        for (int c = 0; c < CC; c++) { int x = ls[c]; ls[c] = run; run += x; }
    }
    __syncthreads();
    if (t < CC) lbase[t] = ls[t];
}

__global__ __launch_bounds__(256) void lfill_kernel(const int* __restrict__ label,
                                                    const int* __restrict__ lbase,
                                                    int* __restrict__ gcur,
                                                    int* __restrict__ perm, int n) {
    __shared__ int lh[CC], lbs[CC], lc[CC];
    int t = threadIdx.x;
    if (t < CC) lh[t] = 0;
    __syncthreads();
    int chunk = (n + gridDim.x - 1) / gridDim.x;
    int beg = blockIdx.x * chunk, end = min(n, beg + chunk);
    for (int i = beg + t; i < end; i += 256) atomicAdd(&lh[label[i]], 1);
    __syncthreads();
    if (t < CC) {
        lbs[t] = (lh[t] > 0) ? atomicAdd(&gcur[t], lh[t]) : 0;
        lc[t] = 0;
    }
    __syncthreads();
    for (int i = beg + t; i < end; i += 256) {
        int c = label[i];
        int pos = atomicAdd(&lc[c], 1);
        perm[lbase[c] + lbs[c] + pos] = (c << 24) | i;
    }
}

// ---------------- segment sums via sorted perm ----------------
__global__ __launch_bounds__(256) void psum_kernel(const ushort* __restrict__ xb,
                                                   const int* __restrict__ perm,
                                                   float* __restrict__ sums, int n) {
    const int lane = threadIdx.x & 63;
    const int wid = threadIdx.x >> 6;
    int gw = blockIdx.x * 4 + wid;
    int nw = gridDim.x * 4;
    int per = (n + nw - 1) / nw;
    int beg = gw * per, end = min(n, beg + per);
    if (beg >= end) return;
    float ax = 0.0f, ay = 0.0f;
    int ccur = __builtin_amdgcn_readfirstlane(perm[beg]) >> 24;
    int i = beg;
    while (i < end) {
        if (i + 4 <= end) {
            int p0 = __builtin_amdgcn_readfirstlane(perm[i]);
            int p1 = __builtin_amdgcn_readfirstlane(perm[i + 1]);
            int p2 = __builtin_amdgcn_readfirstlane(perm[i + 2]);
            int p3 = __builtin_amdgcn_readfirstlane(perm[i + 3]);
            if ((p0 >> 24) == (p3 >> 24)) {
                int c = p0 >> 24;
                if (c != ccur) {
                    atomicAdd(&sums[ccur * HH + 2 * lane], ax);
                    atomicAdd(&sums[ccur * HH + 2 * lane + 1], ay);
                    ax = ay = 0.0f;
                    ccur = c;
                }
                ushort2 v0 = *(const ushort2*)(xb + (size_t)(p0 & 0xFFFFFF) * HH + 2 * lane);
                ushort2 v1 = *(const ushort2*)(xb + (size_t)(p1 & 0xFFFFFF) * HH + 2 * lane);
                ushort2 v2 = *(const ushort2*)(xb + (size_t)(p2 & 0xFFFFFF) * HH + 2 * lane);
                ushort2 v3 = *(const ushort2*)(xb + (size_t)(p3 & 0xFFFFFF) * HH + 2 * lane);
                ax += b2f(v0.x) + b2f(v1.x) + b2f(v2.x) + b2f(v3.x);
                ay += b2f(v0.y) + b2f(v1.y) + b2f(v2.y) + b2f(v3.y);
                i += 4;
                continue;
            }
        }
        int pe = __builtin_amdgcn_readfirstlane(perm[i]);
        int c = pe >> 24;
        if (c != ccur) {
            atomicAdd(&sums[ccur * HH + 2 * lane], ax);
            atomicAdd(&sums[ccur * HH + 2 * lane + 1], ay);
            ax = ay = 0.0f;
            ccur = c;
        }
        ushort2 v = *(const ushort2*)(xb + (size_t)(pe & 0xFFFFFF) * HH + 2 * lane);
        ax += b2f(v.x);
        ay += b2f(v.y);
        i += 1;
    }
    atomicAdd(&sums[ccur * HH + 2 * lane], ax);
    atomicAdd(&sums[ccur * HH + 2 * lane + 1], ay);
}

// ---------------- pack weights ----------------
__global__ __launch_bounds__(256) void pack_w_kernel(const float* __restrict__ W,
                                                     ushort* __restrict__ Wp) {
    int idx = blockIdx.x * 256 + threadIdx.x;  // 0..16383
    int k = idx >> 7, c = idx & 127;
    Wp[(k >> 3) * 1024 + c * 8 + (k & 7)] = f2bf(W[idx]);
}

__global__ __launch_bounds__(256) void pack_w1_kernel(const float* __restrict__ W1,
                                                      ushort* __restrict__ Wp1) {
    int idx = blockIdx.x * 256 + threadIdx.x;  // 0..6143
    if (idx >= 6144) return;
    int ksub = idx / 384, rem = idx - ksub * 384;
    int c = rem >> 3, kk = ksub * 8 + (rem & 7);
    Wp1[idx] = (c < CC) ? f2bf(W1[kk * CC + c]) : (ushort)0;
}

// ---------------- lin0 ----------------
__global__ __launch_bounds__(256) void lin0_mfma_kernel(const float* __restrict__ xin,
                                                        const ushort* __restrict__ Wp,
                                                        const float* __restrict__ bias,
                                                        ushort* __restrict__ x0b,
                                                        ushort* __restrict__ xb) {
    __shared__ ushort ts[32 * 128];
    __shared__ ushort wl[128 * 128];
    {
        const uint4* g4 = (const uint4*)Wp;
        uint4* l4 = (uint4*)wl;
        for (int j = threadIdx.x; j < 2048; j += 256) l4[j] = g4[j];
    }
    const int lane = threadIdx.x & 63, wv = threadIdx.x >> 6;
    const int sub = lane >> 4, r16 = lane & 15;
    const int wbase = wv * 32;
    const int rowbase = blockIdx.x * 32;
    const float* tp = xin + (size_t)rowbase * HH;
    #pragma unroll
    for (int j = 0; j < 4; j++) {
        int e = 4 * threadIdx.x + j * 1024;
        float4 f = *(const float4*)(tp + e);
        int r = e >> 7, c = e & 127;
        ushort4 b4 = make_ushort4(f2bf(f.x), f2bf(f.y), f2bf(f.z), f2bf(f.w));
        int off = (r * 256 + c * 2) ^ ((r & 7) << 4);
        *(ushort4*)((char*)ts + off) = b4;
    }
    __syncthreads();
    float4v acc[2][2] = {};
    {
        const char* tsc = (const char*)ts;
        const int sw = (r16 & 7) << 4;
        #pragma unroll
        for (int ks = 0; ks < 4; ks++) {
            short8v a0 = *(const short8v*)(tsc + ((r16 * 256 + ks * 64 + sub * 16) ^ sw));
            short8v a1 = *(const short8v*)(tsc + (((16 + r16) * 256 + ks * 64 + sub * 16) ^ sw));
            int kb = (ks * 4 + sub) * 1024;
            short8v b0 = *(const short8v*)(wl + kb + (wbase + r16) * 8);
            short8v b1 = *(const short8v*)(wl + kb + (wbase + 16 + r16) * 8);
            acc[0][0] = __builtin_amdgcn_mfma_f32_16x16x32_bf16(a0, b0, acc[0][0], 0, 0, 0);
            acc[0][1] = __builtin_amdgcn_mfma_f32_16x16x32_bf16(a0, b1, acc[0][1], 0, 0, 0);
            acc[1][0] = __builtin_amdgcn_mfma_f32_16x16x32_bf16(a1, b0, acc[1][0], 0, 0, 0);
            acc[1][1] = __builtin_amdgcn_mfma_f32_16x16x32_bf16(a1, b1, acc[1][1], 0, 0, 0);
        }
    }
    float bv[2] = {bias[wbase + r16], bias[wbase + 16 + r16]};
    #pragma unroll
    for (int mi = 0; mi < 2; mi++)
        #pragma unroll
        for (int ni = 0; ni < 2; ni++) {
            int col = wbase + ni * 16 + r16;
            #pragma unroll
            for (int r = 0; r < 4; r++) {
                int row = rowbase + mi * 16 + sub * 4 + r;
                float v = fmaxf(acc[mi][ni][r] + bv[ni], 0.0f);
                ushort bv16 = f2bf(v);
                x0b[(size_t)row * HH + col] = bv16;
                xb[(size_t)row * HH + col] = bv16;
            }
        }
}

// ---------------- centers + barrier-free rcm ----------------
__global__ __launch_bounds__(128) void centers_kernel(const float* __restrict__ sumsx,
                                                      const float* __restrict__ sums0,
                                                      const float* __restrict__ cnt,
                                                      float* __restrict__ cs) {
    int i = blockIdx.x, h = threadIdx.x;
    cs[i * HH + h] = (sumsx[i * HH + h] + 0.1f * sums0[i * HH + h]) / fmaxf(cnt[i], 1.0f);
}

// one wave per class i; lane owns h=lane and h=lane+64; shfl-reduce per j.
__global__ __launch_bounds__(64) void rcm2_kernel(const float* __restrict__ cs,
                                                  const float* __restrict__ cm,
                                                  float* __restrict__ rcm) {
    int i = blockIdx.x, lane = threadIdx.x;
    float ci0 = cs[i * HH + lane];
    float ci1 = cs[i * HH + 64 + lane];
    float acc0 = 0.0f, acc1 = 0.0f;
    for (int j = 0; j < CC; j++) {
        float d0 = ci0 - cs[j * HH + lane];
        float d1 = ci1 - cs[j * HH + 64 + lane];
        float s = d0 * d0 + d1 * d1;
        #pragma unroll
        for (int off = 32; off >= 1; off >>= 1) s += __shfl_xor(s, off);
        float nrm = sqrtf(s);
        if (nrm == 0.0f) nrm = 1.0f;
        float w = cm[i * CC + j] / nrm;
        acc0 = fmaf(w, d0, acc0);
        acc1 = fmaf(w, d1, acc1);
    }
    rcm[i * HH + lane] = acc0;
    rcm[i * HH + 64 + lane] = acc1;
}

// pack rcm into B-fragment order bf16 once per layer (8192 entries)
__global__ __launch_bounds__(256) void pack_rcm_kernel(const float* __restrict__ rcm,
                                                       ushort* __restrict__ rlp) {
    int idx = blockIdx.x * 256 + threadIdx.x;  // 0..8191
    int ksub = idx >> 10, rem = idx & 1023;
    int c = rem >> 3, kk = ksub * 8 + (rem & 7);
    rlp[idx] = (kk < CC) ? f2bf(rcm[kk * HH + c]) : (ushort)0;
}

// ---------------- pr = p @ rcm ----------------
__global__ __launch_bounds__(256) void pr_mfma_kernel(const float* __restrict__ p,
                                                      const ushort* __restrict__ rlp,
                                                      ushort* __restrict__ prb) {
    __shared__ ushort ps[32 * 64];
    __shared__ ushort rl[8 * 1024];
    const int rowbase = blockIdx.x * 32;
    {
        const uint4* g4 = (const uint4*)rlp;
        uint4* l4 = (uint4*)rl;
        for (int j = threadIdx.x; j < 1024; j += 256) l4[j] = g4[j];
    }
    {
        int t = threadIdx.x;
        int r = t >> 3, kc = (t & 7) * 8;
        const float* prow = p + (size_t)(rowbase + r) * CC;
        short8v v;
        #pragma unroll
        for (int j = 0; j < 8; j++) {
            int k = kc + j;
            v[j] = (short)((k < CC) ? f2bf(prow[k]) : (ushort)0);
        }
        int off = (r * 128 + kc * 2) ^ ((r & 7) << 4);
        *(short8v*)((char*)ps + off) = v;
    }
    __syncthreads();
    const int lane = threadIdx.x & 63, wv = threadIdx.x >> 6;
    const int sub = lane >> 4, r16 = lane & 15;
    const int wbase = wv * 32;
    float4v acc[2][2] = {};
    {
        const char* psc = (const char*)ps;
        const int sw = (r16 & 7) << 4;
        #pragma unroll
        for (int ks = 0; ks < 2; ks++) {
            short8v a0 = *(const short8v*)(psc + ((r16 * 128 + ks * 64 + sub * 16) ^ sw));
            short8v a1 = *(const short8v*)(psc + (((16 + r16) * 128 + ks * 64 + sub * 16) ^ sw));
            int kb = (ks * 4 + sub) * 1024;
            short8v b0 = *(const short8v*)(rl + kb + (wbase + r16) * 8);
            short8v b1 = *(const short8v*)(rl + kb + (wbase + 16 + r16) * 8);
            acc[0][0] = __builtin_amdgcn_mfma_f32_16x16x32_bf16(a0, b0, acc[0][0], 0, 0, 0);
            acc[0][1] = __builtin_amdgcn_mfma_f32_16x16x32_bf16(a0, b1, acc[0][1], 0, 0, 0);
            acc[1][0] = __builtin_amdgcn_mfma_f32_16x16x32_bf16(a1, b0, acc[1][0], 0, 0, 0);
            acc[1][1] = __builtin_amdgcn_mfma_f32_16x16x32_bf16(a1, b1, acc[1][1], 0, 0, 0);
        }
    }
    #pragma unroll
    for (int mi = 0; mi < 2; mi++)
        #pragma unroll
        for (int ni = 0; ni < 2; ni++) {
            int col = wbase + ni * 16 + r16;
            #pragma unroll
            for (int r = 0; r < 4; r++) {
                int row = rowbase + mi * 16 + sub * 4 + r;
                prb[(size_t)row * HH + col] = f2bf(acc[mi][ni][r]);
            }
        }
}

// ---------------- fused layer ----------------
template <int FINAL>
__global__ __launch_bounds__(512) void layer_kernel(
    const ushort* __restrict__ xin, const ushort* __restrict__ x0b,
    const ushort* __restrict__ prb,
    const int* __restrict__ rowptr, const int2* __restrict__ csr,
    const ushort* __restrict__ Wp,
    const ushort* __restrict__ Wp1, const float* __restrict__ b1,
    ushort* __restrict__ xout, float* __restrict__ out, float beta) {
    __shared__ ushort wl[128 * 128];
    __shared__ ushort ts[32 * 128];
    __shared__ ushort w1l[FINAL ? 6144 : 64];
    {
        const uint4* g4 = (const uint4*)Wp;
        uint4* l4 = (uint4*)wl;
        for (int j = threadIdx.x; j < 2048; j += 512) l4[j] = g4[j];
        if constexpr (FINAL) {
            const uint4* g1 = (const uint4*)Wp1;
            uint4* l1 = (uint4*)w1l;
            for (int j = threadIdx.x; j < 768; j += 512) l1[j] = g1[j];
        }
    }
    const int lane = threadIdx.x & 63;
    const int wv = __builtin_amdgcn_readfirstlane(threadIdx.x >> 6);
    const int rowbase = blockIdx.x * 32;
    const int nn0 = rowbase + 4 * wv;
    // prefetch the wave's 5 rowptr values (wave-uniform s_loads, pipelined)
    int rp0 = __builtin_amdgcn_readfirstlane(rowptr[nn0]);
    int rp1 = __builtin_amdgcn_readfirstlane(rowptr[nn0 + 1]);
    int rp2 = __builtin_amdgcn_readfirstlane(rowptr[nn0 + 2]);
    int rp3 = __builtin_amdgcn_readfirstlane(rowptr[nn0 + 3]);
    int rp4 = __builtin_amdgcn_readfirstlane(rowptr[nn0 + 4]);
    int rps[5] = {rp0, rp1, rp2, rp3, rp4};
    // ---- gather + combine -> ts ----
    #pragma unroll 1
    for (int k = 0; k < 4; k++) {
        int rloc = 4 * wv + k;
        int nn = nn0 + k;
        int beg = rps[k], end = rps[k + 1];
        float accx = 0.0f, accy = 0.0f;
        int e2 = beg;
        for (; e2 + 8 <= end; e2 += 8) {
            int2 ed[8];
            #pragma unroll
            for (int u = 0; u < 8; u++) ed[u] = csr[e2 + u];
            ushort2 vv[8];
            #pragma unroll
            for (int u = 0; u < 8; u++)
                vv[u] = *(const ushort2*)(xin + (size_t)ed[u].x * HH + 2 * lane);
            #pragma unroll
            for (int u = 0; u < 8; u++) {
                float w = __int_as_float(ed[u].y);
                accx = fmaf(w, b2f(vv[u].x), accx);
                accy = fmaf(w, b2f(vv[u].y), accy);
            }
        }
        for (; e2 + 4 <= end; e2 += 4) {
            int2 ed[4];
            #pragma unroll
            for (int u = 0; u < 4; u++) ed[u] = csr[e2 + u];
            ushort2 vv[4];
            #pragma unroll
            for (int u = 0; u < 4; u++)
                vv[u] = *(const ushort2*)(xin + (size_t)ed[u].x * HH + 2 * lane);
            #pragma unroll
            for (int u = 0; u < 4; u++) {
                float w = __int_as_float(ed[u].y);
                accx = fmaf(w, b2f(vv[u].x), accx);
                accy = fmaf(w, b2f(vv[u].y), accy);
            }
        }
        for (; e2 < end; e2++) {
            int2 ed = csr[e2];
            ushort2 v = *(const ushort2*)(xin + (size_t)ed.x * HH + 2 * lane);
            float w = __int_as_float(ed.y);
            accx = fmaf(w, b2f(v.x), accx);
            accy = fmaf(w, b2f(v.y), accy);
        }
        ushort2 pv = *(const ushort2*)(prb + (size_t)nn * HH + 2 * lane);
        ushort2 xc = *(const ushort2*)(xin + (size_t)nn * HH + 2 * lane);
        ushort2 xo = *(const ushort2*)(x0b + (size_t)nn * HH + 2 * lane);
        ushort2 o;
        o.x = f2bf(0.45f * b2f(xc.x) + 0.45f * b2f(pv.x) + 0.45f * accx + 0.1f * b2f(xo.x));
        o.y = f2bf(0.45f * b2f(xc.y) + 0.45f * b2f(pv.y) + 0.45f * accy + 0.1f * b2f(xo.y));
        *(ushort2*)((char*)ts + ((rloc * 256 + lane * 4) ^ ((rloc & 7) << 4))) = o;
    }
    __syncthreads();
    // ---- conv MFMA: wave wv owns cols [16wv, 16wv+16) ----
    const int sub = lane >> 4, r16 = lane & 15;
    const int sw = (r16 & 7) << 4;
    const char* tsc = (const char*)ts;
    float4v acc[2] = {};
    #pragma unroll
    for (int ks = 0; ks < 4; ks++) {
        short8v a0 = *(const short8v*)(tsc + ((r16 * 256 + ks * 64 + sub * 16) ^ sw));
        short8v a1 = *(const short8v*)(tsc + (((16 + r16) * 256 + ks * 64 + sub * 16) ^ sw));
        short8v bb = *(const short8v*)(wl + (ks * 4 + sub) * 1024 + (16 * wv + r16) * 8);
        acc[0] = __builtin_amdgcn_mfma_f32_16x16x32_bf16(a0, bb, acc[0], 0, 0, 0);
        acc[1] = __builtin_amdgcn_mfma_f32_16x16x32_bf16(a1, bb, acc[1], 0, 0, 0);
    }
    const float omb = 1.0f - beta;
    const int col = 16 * wv + r16;
    if constexpr (!FINAL) {
        #pragma unroll
        for (int mi = 0; mi < 2; mi++)
            #pragma unroll
            for (int r = 0; r < 4; r++) {
                int rl_ = mi * 16 + sub * 4 + r;
                int toff = (rl_ * 256 + col * 2) ^ ((rl_ & 7) << 4);
                float tv = b2f(*(const ushort*)(tsc + toff));
                float v = fmaxf(omb * tv + beta * acc[mi][r], 0.0f);
                xout[(size_t)(rowbase + rl_) * HH + col] = f2bf(v);
            }
    } else {
        __syncthreads();
        #pragma unroll
        for (int mi = 0; mi < 2; mi++)
            #pragma unroll
            for (int r = 0; r < 4; r++) {
                int rl_ = mi * 16 + sub * 4 + r;
                int toff = (rl_ * 256 + col * 2) ^ ((rl_ & 7) << 4);
                ushort* slot = (ushort*)((char*)ts + toff);
                float tv = b2f(*slot);
                float v = fmaxf(omb * tv + beta * acc[mi][r], 0.0f);
                *slot = f2bf(v);
            }
        __syncthreads();
        if (wv < 3) {
            float4v a2[2] = {};
            #pragma unroll
            for (int ks = 0; ks < 4; ks++) {
                short8v a0 = *(const short8v*)(tsc + ((r16 * 256 + ks * 64 + sub * 16) ^ sw));
                short8v a1 = *(const short8v*)(tsc + (((16 + r16) * 256 + ks * 64 + sub * 16) ^ sw));
                short8v bb = *(const short8v*)(w1l + (ks * 4 + sub) * 384 + (wv * 16 + r16) * 8);
                a2[0] = __builtin_amdgcn_mfma_f32_16x16x32_bf16(a0, bb, a2[0], 0, 0, 0);
                a2[1] = __builtin_amdgcn_mfma_f32_16x16x32_bf16(a1, bb, a2[1], 0, 0, 0);
            }
            int col2 = wv * 16 + r16;
            if (col2 < CC) {
                float bias = b1[col2];
                #pragma unroll
                for (int mi = 0; mi < 2; mi++)
                    #pragma unroll
                    for (int r = 0; r < 4; r++) {
                        int row = rowbase + mi * 16 + sub * 4 + r;
                        out[(size_t)row * CC + col2] = a2[mi][r] + bias;
                    }
            }
        }
    }
}

extern "C" void kernel_launch(void* const* d_in, const int* in_sizes, int n_in,
                              void* d_out, int out_size, void* d_ws, size_t ws_size,
                              hipStream_t stream) {
    const float* x_in   = (const float*)d_in[0];
    const int*   ei     = (const int*)d_in[1];
    const float* ew     = (const float*)d_in[2];
    const int*   label  = (const int*)d_in[3];
    const float* p      = (const float*)d_in[4];
    const float* cm     = (const float*)d_in[5];
    const float* lin0_w = (const float*)d_in[6];
    const float* lin0_b = (const float*)d_in[7];
    const float* lin1_w = (const float*)d_in[8];
    const float* lin1_b = (const float*)d_in[9];
    const float* conv_w = (const float*)d_in[10];
    float* out = (float*)d_out;

    const int* src = ei;
    const int* dst = ei + EE;

    const size_t NH = (size_t)NN * HH;
    float* ws = (float*)d_ws;
    float* cnt   = ws;                       // 64
    float* sums0 = cnt + 64;                 // CC*HH
    float* sumsx = sums0 + CC * HH;          // CC*HH
    float* rcm   = sumsx + CC * HH;          // CC*HH
    float* cs    = rcm + CC * HH;            // CC*HH
    int*   deg    = (int*)(cs + CC * HH);    // NN
    int*   rowptr = deg + NN;                // NN+1 (+pad)
    int*   bsum   = rowptr + NN + 64;        // 256
    int*   bcur   = bsum + 256;              // 512
    int*   lcnt   = bcur + 512;              // 64
    int*   lbase  = lcnt + 64;               // 64
    int*   gcur   = lbase + 64;              // 64
    int*   perm   = gcur + 64;               // NN
    int2*  csr    = (int2*)(perm + NN);      // EE
    int2*  stage  = csr + EE;                // EE
    ushort* x0b   = (ushort*)(stage + EE);   // NH bf16
    ushort* xbA   = x0b + NH;                // NH bf16
    ushort* xbB   = xbA + NH;                // NH bf16
    ushort* prb   = xbB + NH;                // NH bf16
    ushort* wp0   = prb + NH;                // 16384
    ushort* wpc   = wp0 + 16384;             // 4*16384
    ushort* wp1   = wpc + 4 * 16384;         // 6144 (pad to 8192)
    ushort* rlp   = wp1 + 8192;              // 8192

    // ---- edge CSR build ----
    hipMemsetAsync(deg, 0, NN * sizeof(int), stream);
    hist_kernel<<<(EE + 255) / 256, 256, 0, stream>>>(dst, deg, EE);
    const int NBLK = (NN + 511) / 512;
    scan_block_kernel<<<NBLK, 256, 0, stream>>>(deg, rowptr, bsum, NN);
    scan_bsum_kernel<<<1, 256, 0, stream>>>(bsum, NBLK);
    add_off_kernel<<<(NN + 255) / 256, 256, 0, stream>>>(rowptr, bsum, NN);
    init_bcur_kernel<<<2, 256, 0, stream>>>(rowptr, bcur);
    coarse_fill_kernel<<<(EE + CHUNK - 1) / CHUNK, 256, 0, stream>>>(src, dst, ew, bcur, stage, EE);
    fine_fill_kernel<<<NB, 256, 0, stream>>>(stage, rowptr, csr, NN);

    // ---- label sort ----
    hipMemsetAsync(lcnt, 0, CC * sizeof(int), stream);
    lhist_kernel<<<256, 256, 0, stream>>>(label, lcnt, NN);
    lscan_kernel<<<1, 64, 0, stream>>>(lcnt, lbase, gcur, cnt);
    lfill_kernel<<<256, 256, 0, stream>>>(label, lbase, gcur, perm, NN);

    // ---- pack weights ----
    pack_w_kernel<<<64, 256, 0, stream>>>(lin0_w, wp0);
    for (int i = 0; i < 4; i++)
        pack_w_kernel<<<64, 256, 0, stream>>>(conv_w + (size_t)i * HH * HH, wpc + (size_t)i * 16384);
    pack_w1_kernel<<<24, 256, 0, stream>>>(lin1_w, wp1);

    // input linear + relu
    lin0_mfma_kernel<<<NN / 32, 256, 0, stream>>>(x_in, wp0, lin0_b, x0b, xbA);

    // sums0 = sum_label x0
    hipMemsetAsync(sums0, 0, CC * HH * sizeof(float), stream);
    psum_kernel<<<2048, 256, 0, stream>>>(x0b, perm, sums0, NN);

    const float betas[4] = {logf(0.5f / 1.0f + 1.0f), logf(0.5f / 2.0f + 1.0f),
                            logf(0.5f / 3.0f + 1.0f), logf(0.5f / 4.0f + 1.0f)};

    ushort* xin_b = xbA;
    ushort* xout_b = xbB;
    for (int i = 0; i < 4; i++) {
        if (i == 0) {
            centers_kernel<<<CC, 128, 0, stream>>>(sums0, sums0, cnt, cs);
        } else {
            hipMemsetAsync(sumsx, 0, CC * HH * sizeof(float), stream);
            psum_kernel<<<2048, 256, 0, stream>>>(xin_b, perm, sumsx, NN);
            centers_kernel<<<CC, 128, 0, stream>>>(sumsx, sums0, cnt, cs);
        }
        rcm2_kernel<<<CC, 64, 0, stream>>>(cs, cm, rcm);
        pack_rcm_kernel<<<32, 256, 0, stream>>>(rcm, rlp);
        pr_mfma_kernel<<<NN / 32, 256, 0, stream>>>(p, rlp, prb);
        if (i < 3) {
            layer_kernel<0><<<NN / 32, 512, 0, stream>>>(xin_b, x0b, prb, rowptr, csr,
                                                         wpc + (size_t)i * 16384, wp1, lin1_b,
                                                         xout_b, out, betas[i]);
            ushort* tmp = xin_b; xin_b = xout_b; xout_b = tmp;
        } else {
            layer_kernel<1><<<NN / 32, 512, 0, stream>>>(xin_b, x0b, prb, rowptr, csr,
                                                         wpc + 3 * 16384, wp1, lin1_b,
                                                         xout_b, out, betas[3]);
        }
    }
}

// Round 10
// 558.044 us; speedup vs baseline: 5.6212x; 1.0918x over previous
//
#include <hip/hip_runtime.h>
#include <math.h>

#define NN 100000
#define EE 800000
#define CC 47
#define HH 128
#define NB 391      // node buckets of 256
#define CHUNK 2000  // edges per coarse block

typedef __attribute__((ext_vector_type(8))) short short8v;
typedef __attribute__((ext_vector_type(4))) float float4v;

__device__ inline ushort f2bf(float f) {
    unsigned u = __float_as_uint(f);
    unsigned r = (u + 0x7fffu + ((u >> 16) & 1u)) >> 16;  // RNE
    return (ushort)r;
}
__device__ inline float b2f(ushort u) { return __uint_as_float(((unsigned)u) << 16); }

// ---------------- node-degree histogram + rowptr scan ----------------
__global__ __launch_bounds__(256) void hist_kernel(const int* __restrict__ dst,
                                                   int* __restrict__ deg, int e) {
    int i = blockIdx.x * 256 + threadIdx.x;
    if (i < e) atomicAdd(&deg[dst[i]], 1);
}

__global__ __launch_bounds__(256) void scan_block_kernel(const int* __restrict__ deg,
                                                         int* __restrict__ rowptr,
                                                         int* __restrict__ bsum, int n) {
    __shared__ int ls[256];
    int b = blockIdx.x, t = threadIdx.x;
    int i0 = b * 512 + 2 * t;
    int a0 = (i0 < n) ? deg[i0] : 0;
    int a1 = (i0 + 1 < n) ? deg[i0 + 1] : 0;
    int val = a0 + a1;
    ls[t] = val;
    __syncthreads();
    for (int off = 1; off < 256; off <<= 1) {
        int add = (t >= off) ? ls[t - off] : 0;
        __syncthreads();
        val += add;
        ls[t] = val;
        __syncthreads();
    }
    int incl1 = val;
    int incl0 = val - a1;
    if (i0 < n) rowptr[i0 + 1] = incl0;
    if (i0 + 1 < n) rowptr[i0 + 2] = incl1;
    if (t == 255) bsum[b] = val;
}

__global__ __launch_bounds__(256) void scan_bsum_kernel(int* __restrict__ bsum, int nb) {
    __shared__ int ls[256];
    int t = threadIdx.x;
    int v = (t < nb) ? bsum[t] : 0;
    int orig = v;
    ls[t] = v;
    __syncthreads();
    for (int off = 1; off < 256; off <<= 1) {
        int add = (t >= off) ? ls[t - off] : 0;
        __syncthreads();
        v += add;
        ls[t] = v;
        __syncthreads();
    }
    if (t < nb) bsum[t] = v - orig;
}

__global__ __launch_bounds__(256) void add_off_kernel(int* __restrict__ rowptr,
                                                      const int* __restrict__ bsum, int n) {
    int i = blockIdx.x * 256 + threadIdx.x;
    if (i < n) rowptr[i + 1] += bsum[i >> 9];
    if (i == 0) rowptr[0] = 0;
}

// ---------------- binned CSR fill ----------------
__global__ __launch_bounds__(256) void init_bcur_kernel(const int* __restrict__ rowptr,
                                                        int* __restrict__ bcur) {
    int b = blockIdx.x * 256 + threadIdx.x;
    if (b < 512) bcur[b] = rowptr[min(b * 256, NN)];
}

__global__ __launch_bounds__(256) void coarse_fill_kernel(const int* __restrict__ src,
                                                          const int* __restrict__ dst,
                                                          const float* __restrict__ ew,
                                                          int* __restrict__ bcur,
                                                          int2* __restrict__ stage, int e) {
    __shared__ int hist[512];
    __shared__ int base_local[512];
    __shared__ int gbase[512];
    __shared__ int lc[512];
    __shared__ int ls[256];
    __shared__ int2 le[CHUNK];
    __shared__ ushort lb[CHUNK];
    int t = threadIdx.x;
    int beg = blockIdx.x * CHUNK, end = min(e, beg + CHUNK);
    int cnt = end - beg;
    for (int i = t; i < 512; i += 256) { hist[i] = 0; lc[i] = 0; }
    __syncthreads();
    for (int i = beg + t; i < end; i += 256) atomicAdd(&hist[((unsigned)dst[i]) >> 8], 1);
    __syncthreads();
    int a0 = hist[2 * t], a1 = hist[2 * t + 1];
    int val = a0 + a1;
    ls[t] = val;
    __syncthreads();
    for (int off = 1; off < 256; off <<= 1) {
        int add = (t >= off) ? ls[t - off] : 0;
        __syncthreads();
        val += add;
        ls[t] = val;
        __syncthreads();
    }
    base_local[2 * t] = val - a0 - a1;
    base_local[2 * t + 1] = val - a1;
    __syncthreads();
    for (int b = t; b < 512; b += 256)
        if (hist[b] > 0) gbase[b] = atomicAdd(&bcur[b], hist[b]);
    __syncthreads();
    for (int i = beg + t; i < end; i += 256) {
        int d = dst[i];
        int bk = ((unsigned)d) >> 8;
        int slot = base_local[bk] + atomicAdd(&lc[bk], 1);
        le[slot] = make_int2(((d & 255) << 24) | src[i], __float_as_int(ew[i]));
        lb[slot] = (ushort)bk;
    }
    __syncthreads();
    for (int s = t; s < cnt; s += 256) {
        int bk = lb[s];
        stage[gbase[bk] + (s - base_local[bk])] = le[s];
    }
}

__global__ __launch_bounds__(256) void fine_fill_kernel(const int2* __restrict__ stage,
                                                        const int* __restrict__ rowptr,
                                                        int2* __restrict__ csr, int n) {
    __shared__ int cur[256];
    __shared__ int rp[257];
    int b = blockIdx.x, t = threadIdx.x;
    int node0 = b * 256;
    int nodes = min(256, n - node0);
    cur[t] = 0;
    rp[t] = rowptr[min(node0 + t, n)];
    if (t == 0) rp[256] = rowptr[min(node0 + 256, n)];
    __syncthreads();
    int S = rp[0], E = rp[nodes];
    for (int i = S + t; i < E; i += 256) {
        int2 en = stage[i];
        int dl = ((unsigned)en.x) >> 24;
        int pos = rp[dl] + atomicAdd(&cur[dl], 1);
        csr[pos] = make_int2(en.x & 0xFFFFFF, en.y);
    }
}

// ---------------- label sort (once) ----------------
__global__ __launch_bounds__(256) void lhist_kernel(const int* __restrict__ label,
                                                    int* __restrict__ lcnt, int n) {
    __shared__ int lh[CC];
    if (threadIdx.x < CC) lh[threadIdx.x] = 0;
    __syncthreads();
    for (int i = blockIdx.x * 256 + threadIdx.x; i < n; i += gridDim.x * 256)
        atomicAdd(&lh[label[i]], 1);
    __syncthreads();
    if (threadIdx.x < CC) atomicAdd(&lcnt[threadIdx.x], lh[threadIdx.x]);
}

__global__ __launch_bounds__(64) void lscan_kernel(const int* __restrict__ lcnt,
                                                   int* __restrict__ lbase,
                                                   int* __restrict__ gcur,
                                                   float* __restrict__ cntf) {
    __shared__ int ls[CC];
    int t = threadIdx.x;
    if (t < CC) {
        int v = lcnt[t];
        cntf[t] = (float)v;
        gcur[t] = 0;
        ls[t] = v;
    }
    __syncthreads();
    if (t == 0) {
        int run = 0;
        for (int c = 0; c < CC; c++) { int x = ls[c]; ls[c] = run; run += x; }
    }
    __syncthreads();
    if (t < CC) lbase[t] = ls[t];
}

__global__ __launch_bounds__(256) void lfill_kernel(const int* __restrict__ label,
                                                    const int* __restrict__ lbase,
                                                    int* __restrict__ gcur,
                                                    int* __restrict__ perm, int n) {
    __shared__ int lh[CC], lbs[CC], lc[CC];
    int t = threadIdx.x;
    if (t < CC) lh[t] = 0;
    __syncthreads();
    int chunk = (n + gridDim.x - 1) / gridDim.x;
    int beg = blockIdx.x * chunk, end = min(n, beg + chunk);
    for (int i = beg + t; i < end; i += 256) atomicAdd(&lh[label[i]], 1);
    __syncthreads();
    if (t < CC) {
        lbs[t] = (lh[t] > 0) ? atomicAdd(&gcur[t], lh[t]) : 0;
        lc[t] = 0;
    }
    __syncthreads();
    for (int i = beg + t; i < end; i += 256) {
        int c = label[i];
        int pos = atomicAdd(&lc[c], 1);
        perm[lbase[c] + lbs[c] + pos] = (c << 24) | i;
    }
}

// ---------------- segment sums via sorted perm ----------------
__global__ __launch_bounds__(256) void psum_kernel(const ushort* __restrict__ xb,
                                                   const int* __restrict__ perm,
                                                   float* __restrict__ sums, int n) {
    const int lane = threadIdx.x & 63;
    const int wid = threadIdx.x >> 6;
    int gw = blockIdx.x * 4 + wid;
    int nw = gridDim.x * 4;
    int per = (n + nw - 1) / nw;
    int beg = gw * per, end = min(n, beg + per);
    if (beg >= end) return;
    float ax = 0.0f, ay = 0.0f;
    int ccur = __builtin_amdgcn_readfirstlane(perm[beg]) >> 24;
    int i = beg;
    while (i < end) {
        if (i + 4 <= end) {
            int p0 = __builtin_amdgcn_readfirstlane(perm[i]);
            int p1 = __builtin_amdgcn_readfirstlane(perm[i + 1]);
            int p2 = __builtin_amdgcn_readfirstlane(perm[i + 2]);
            int p3 = __builtin_amdgcn_readfirstlane(perm[i + 3]);
            if ((p0 >> 24) == (p3 >> 24)) {
                int c = p0 >> 24;
                if (c != ccur) {
                    atomicAdd(&sums[ccur * HH + 2 * lane], ax);
                    atomicAdd(&sums[ccur * HH + 2 * lane + 1], ay);
                    ax = ay = 0.0f;
                    ccur = c;
                }
                ushort2 v0 = *(const ushort2*)(xb + (size_t)(p0 & 0xFFFFFF) * HH + 2 * lane);
                ushort2 v1 = *(const ushort2*)(xb + (size_t)(p1 & 0xFFFFFF) * HH + 2 * lane);
                ushort2 v2 = *(const ushort2*)(xb + (size_t)(p2 & 0xFFFFFF) * HH + 2 * lane);
                ushort2 v3 = *(const ushort2*)(xb + (size_t)(p3 & 0xFFFFFF) * HH + 2 * lane);
                ax += b2f(v0.x) + b2f(v1.x) + b2f(v2.x) + b2f(v3.x);
                ay += b2f(v0.y) + b2f(v1.y) + b2f(v2.y) + b2f(v3.y);
                i += 4;
                continue;
            }
        }
        int pe = __builtin_amdgcn_readfirstlane(perm[i]);
        int c = pe >> 24;
        if (c != ccur) {
            atomicAdd(&sums[ccur * HH + 2 * lane], ax);
            atomicAdd(&sums[ccur * HH + 2 * lane + 1], ay);
            ax = ay = 0.0f;
            ccur = c;
        }
        ushort2 v = *(const ushort2*)(xb + (size_t)(pe & 0xFFFFFF) * HH + 2 * lane);
        ax += b2f(v.x);
        ay += b2f(v.y);
        i += 1;
    }
    atomicAdd(&sums[ccur * HH + 2 * lane], ax);
    atomicAdd(&sums[ccur * HH + 2 * lane + 1], ay);
}

// ---------------- pack weights ----------------
__global__ __launch_bounds__(256) void pack_w_kernel(const float* __restrict__ W,
                                                     ushort* __restrict__ Wp) {
    int idx = blockIdx.x * 256 + threadIdx.x;  // 0..16383
    int k = idx >> 7, c = idx & 127;
    Wp[(k >> 3) * 1024 + c * 8 + (k & 7)] = f2bf(W[idx]);
}

__global__ __launch_bounds__(256) void pack_w1_kernel(const float* __restrict__ W1,
                                                      ushort* __restrict__ Wp1) {
    int idx = blockIdx.x * 256 + threadIdx.x;  // 0..6143
    if (idx >= 6144) return;
    int ksub = idx / 384, rem = idx - ksub * 384;
    int c = rem >> 3, kk = ksub * 8 + (rem & 7);
    Wp1[idx] = (c < CC) ? f2bf(W1[kk * CC + c]) : (ushort)0;
}

// ---------------- lin0 ----------------
__global__ __launch_bounds__(256) void lin0_mfma_kernel(const float* __restrict__ xin,
                                                        const ushort* __restrict__ Wp,
                                                        const float* __restrict__ bias,
                                                        ushort* __restrict__ x0b,
                                                        ushort* __restrict__ xb) {
    __shared__ ushort ts[32 * 128];
    __shared__ ushort wl[128 * 128];
    {
        const uint4* g4 = (const uint4*)Wp;
        uint4* l4 = (uint4*)wl;
        for (int j = threadIdx.x; j < 2048; j += 256) l4[j] = g4[j];
    }
    const int lane = threadIdx.x & 63, wv = threadIdx.x >> 6;
    const int sub = lane >> 4, r16 = lane & 15;
    const int wbase = wv * 32;
    const int rowbase = blockIdx.x * 32;
    const float* tp = xin + (size_t)rowbase * HH;
    #pragma unroll
    for (int j = 0; j < 4; j++) {
        int e = 4 * threadIdx.x + j * 1024;
        float4 f = *(const float4*)(tp + e);
        int r = e >> 7, c = e & 127;
        ushort4 b4 = make_ushort4(f2bf(f.x), f2bf(f.y), f2bf(f.z), f2bf(f.w));
        int off = (r * 256 + c * 2) ^ ((r & 7) << 4);
        *(ushort4*)((char*)ts + off) = b4;
    }
    __syncthreads();
    float4v acc[2][2] = {};
    {
        const char* tsc = (const char*)ts;
        const int sw = (r16 & 7) << 4;
        #pragma unroll
        for (int ks = 0; ks < 4; ks++) {
            short8v a0 = *(const short8v*)(tsc + ((r16 * 256 + ks * 64 + sub * 16) ^ sw));
            short8v a1 = *(const short8v*)(tsc + (((16 + r16) * 256 + ks * 64 + sub * 16) ^ sw));
            int kb = (ks * 4 + sub) * 1024;
            short8v b0 = *(const short8v*)(wl + kb + (wbase + r16) * 8);
            short8v b1 = *(const short8v*)(wl + kb + (wbase + 16 + r16) * 8);
            acc[0][0] = __builtin_amdgcn_mfma_f32_16x16x32_bf16(a0, b0, acc[0][0], 0, 0, 0);
            acc[0][1] = __builtin_amdgcn_mfma_f32_16x16x32_bf16(a0, b1, acc[0][1], 0, 0, 0);
            acc[1][0] = __builtin_amdgcn_mfma_f32_16x16x32_bf16(a1, b0, acc[1][0], 0, 0, 0);
            acc[1][1] = __builtin_amdgcn_mfma_f32_16x16x32_bf16(a1, b1, acc[1][1], 0, 0, 0);
        }
    }
    float bv[2] = {bias[wbase + r16], bias[wbase + 16 + r16]};
    #pragma unroll
    for (int mi = 0; mi < 2; mi++)
        #pragma unroll
        for (int ni = 0; ni < 2; ni++) {
            int col = wbase + ni * 16 + r16;
            #pragma unroll
            for (int r = 0; r < 4; r++) {
                int row = rowbase + mi * 16 + sub * 4 + r;
                float v = fmaxf(acc[mi][ni][r] + bv[ni], 0.0f);
                ushort bv16 = f2bf(v);
                x0b[(size_t)row * HH + col] = bv16;
                xb[(size_t)row * HH + col] = bv16;
            }
        }
}

// ---------------- fused centers + rcm + pack: one block per class ----------------
__global__ __launch_bounds__(64) void cr_kernel(const float* __restrict__ sumsx,
                                                const float* __restrict__ sums0,
                                                const float* __restrict__ cnt,
                                                const float* __restrict__ cm,
                                                ushort* __restrict__ rlp) {
    __shared__ float cs[CC * HH];
    int i = blockIdx.x, lane = threadIdx.x;
    for (int idx = lane; idx < CC * HH; idx += 64) {
        int c = idx >> 7;
        cs[idx] = (sumsx[idx] + 0.1f * sums0[idx]) / fmaxf(cnt[c], 1.0f);
    }
    __syncthreads();
    float ci0 = cs[i * HH + lane];
    float ci1 = cs[i * HH + 64 + lane];
    float acc0 = 0.0f, acc1 = 0.0f;
    for (int j = 0; j < CC; j++) {
        float d0 = ci0 - cs[j * HH + lane];
        float d1 = ci1 - cs[j * HH + 64 + lane];
        float s = d0 * d0 + d1 * d1;
        #pragma unroll
        for (int off = 32; off >= 1; off >>= 1) s += __shfl_xor(s, off);
        float nrm = sqrtf(s);
        if (nrm == 0.0f) nrm = 1.0f;
        float w = cm[i * CC + j] / nrm;
        acc0 = fmaf(w, d0, acc0);
        acc1 = fmaf(w, d1, acc1);
    }
    rlp[(i >> 3) * 1024 + lane * 8 + (i & 7)] = f2bf(acc0);
    rlp[(i >> 3) * 1024 + (lane + 64) * 8 + (i & 7)] = f2bf(acc1);
}

// ---------------- fused layer: pr MFMA + gather/combine + conv MFMA (+ final GEMM) ----------------
template <int FINAL>
__global__ __launch_bounds__(512, 8) void layer_kernel(
    const ushort* __restrict__ xin, const ushort* __restrict__ x0b,
    const float* __restrict__ p, const ushort* __restrict__ rlp,
    const int* __restrict__ rowptr, const int2* __restrict__ csr,
    const ushort* __restrict__ Wp,
    const ushort* __restrict__ Wp1, const float* __restrict__ b1,
    ushort* __restrict__ xout, float* __restrict__ out, float beta) {
    __shared__ ushort ts[32 * 128];   // 8 KB combined-t tile (swizzled)
    __shared__ ushort ps[32 * 64];    // 4 KB p A-tile (K padded to 64)
    __shared__ ushort prs[32 * 128];  // 8 KB pr result tile (swizzled)
    const int lane = threadIdx.x & 63;
    const int wv = __builtin_amdgcn_readfirstlane(threadIdx.x >> 6);
    const int rowbase = blockIdx.x * 32;
    const int sub = lane >> 4, r16 = lane & 15;
    const int sw = (r16 & 7) << 4;
    // ---- stage p A-tile (threads 0..255: one per (row, 8-k chunk)) ----
    if (threadIdx.x < 256) {
        int t = threadIdx.x;
        int r = t >> 3, kc = (t & 7) * 8;
        const float* prow = p + (size_t)(rowbase + r) * CC;
        short8v v;
        #pragma unroll
        for (int j = 0; j < 8; j++) {
            int k = kc + j;
            v[j] = (short)((k < CC) ? f2bf(prow[k]) : (ushort)0);
        }
        int off = (r * 128 + kc * 2) ^ ((r & 7) << 4);
        *(short8v*)((char*)ps + off) = v;
    }
    __syncthreads();
    // ---- pr MFMA: wave wv owns cols [16wv,16wv+16); B-frags from global rlp ----
    {
        const char* psc = (const char*)ps;
        float4v pacc[2] = {};
        #pragma unroll
        for (int ks = 0; ks < 2; ks++) {
            short8v a0 = *(const short8v*)(psc + ((r16 * 128 + ks * 64 + sub * 16) ^ sw));
            short8v a1 = *(const short8v*)(psc + (((16 + r16) * 128 + ks * 64 + sub * 16) ^ sw));
            short8v bb = *(const short8v*)(rlp + (ks * 4 + sub) * 1024 + (16 * wv + r16) * 8);
            pacc[0] = __builtin_amdgcn_mfma_f32_16x16x32_bf16(a0, bb, pacc[0], 0, 0, 0);
            pacc[1] = __builtin_amdgcn_mfma_f32_16x16x32_bf16(a1, bb, pacc[1], 0, 0, 0);
        }
        int col = 16 * wv + r16;
        #pragma unroll
        for (int mi = 0; mi < 2; mi++)
            #pragma unroll
            for (int r = 0; r < 4; r++) {
                int rl_ = mi * 16 + sub * 4 + r;
                *(ushort*)((char*)prs + ((rl_ * 256 + col * 2) ^ ((rl_ & 7) << 4))) =
                    f2bf(pacc[mi][r]);
            }
    }
    __syncthreads();
    // ---- gather + combine -> ts (pr read from prs LDS) ----
    const int nn0 = rowbase + 4 * wv;
    int rp0 = __builtin_amdgcn_readfirstlane(rowptr[nn0]);
    int rp1 = __builtin_amdgcn_readfirstlane(rowptr[nn0 + 1]);
    int rp2 = __builtin_amdgcn_readfirstlane(rowptr[nn0 + 2]);
    int rp3 = __builtin_amdgcn_readfirstlane(rowptr[nn0 + 3]);
    int rp4 = __builtin_amdgcn_readfirstlane(rowptr[nn0 + 4]);
    int rps[5] = {rp0, rp1, rp2, rp3, rp4};
    #pragma unroll 1
    for (int k = 0; k < 4; k++) {
        int rloc = 4 * wv + k;
        int nn = nn0 + k;
        int beg = rps[k], end = rps[k + 1];
        float accx = 0.0f, accy = 0.0f;
        int e2 = beg;
        for (; e2 + 8 <= end; e2 += 8) {
            int2 ed[8];
            #pragma unroll
            for (int u = 0; u < 8; u++) ed[u] = csr[e2 + u];
            ushort2 vv[8];
            #pragma unroll
            for (int u = 0; u < 8; u++)
                vv[u] = *(const ushort2*)(xin + (size_t)ed[u].x * HH + 2 * lane);
            #pragma unroll
            for (int u = 0; u < 8; u++) {
                float w = __int_as_float(ed[u].y);
                accx = fmaf(w, b2f(vv[u].x), accx);
                accy = fmaf(w, b2f(vv[u].y), accy);
            }
        }
        for (; e2 + 4 <= end; e2 += 4) {
            int2 ed[4];
            #pragma unroll
            for (int u = 0; u < 4; u++) ed[u] = csr[e2 + u];
            ushort2 vv[4];
            #pragma unroll
            for (int u = 0; u < 4; u++)
                vv[u] = *(const ushort2*)(xin + (size_t)ed[u].x * HH + 2 * lane);
            #pragma unroll
            for (int u = 0; u < 4; u++) {
                float w = __int_as_float(ed[u].y);
                accx = fmaf(w, b2f(vv[u].x), accx);
                accy = fmaf(w, b2f(vv[u].y), accy);
            }
        }
        for (; e2 < end; e2++) {
            int2 ed = csr[e2];
            ushort2 v = *(const ushort2*)(xin + (size_t)ed.x * HH + 2 * lane);
            float w = __int_as_float(ed.y);
            accx = fmaf(w, b2f(v.x), accx);
            accy = fmaf(w, b2f(v.y), accy);
        }
        int poff = (rloc * 256 + lane * 4) ^ ((rloc & 7) << 4);
        ushort2 pv = *(const ushort2*)((const char*)prs + poff);
        ushort2 xc = *(const ushort2*)(xin + (size_t)nn * HH + 2 * lane);
        ushort2 xo = *(const ushort2*)(x0b + (size_t)nn * HH + 2 * lane);
        ushort2 o;
        o.x = f2bf(0.45f * b2f(xc.x) + 0.45f * b2f(pv.x) + 0.45f * accx + 0.1f * b2f(xo.x));
        o.y = f2bf(0.45f * b2f(xc.y) + 0.45f * b2f(pv.y) + 0.45f * accy + 0.1f * b2f(xo.y));
        *(ushort2*)((char*)ts + poff) = o;
    }
    __syncthreads();
    // ---- conv MFMA: wave wv owns cols [16wv,16wv+16); B-frags from global Wp ----
    const char* tsc = (const char*)ts;
    float4v acc[2] = {};
    #pragma unroll
    for (int ks = 0; ks < 4; ks++) {
        short8v a0 = *(const short8v*)(tsc + ((r16 * 256 + ks * 64 + sub * 16) ^ sw));
        short8v a1 = *(const short8v*)(tsc + (((16 + r16) * 256 + ks * 64 + sub * 16) ^ sw));
        short8v bb = *(const short8v*)(Wp + (ks * 4 + sub) * 1024 + (16 * wv + r16) * 8);
        acc[0] = __builtin_amdgcn_mfma_f32_16x16x32_bf16(a0, bb, acc[0], 0, 0, 0);
        acc[1] = __builtin_amdgcn_mfma_f32_16x16x32_bf16(a1, bb, acc[1], 0, 0, 0);
    }
    const float omb = 1.0f - beta;
    const int col = 16 * wv + r16;
    if constexpr (!FINAL) {
        #pragma unroll
        for (int mi = 0; mi < 2; mi++)
            #pragma unroll
            for (int r = 0; r < 4; r++) {
                int rl_ = mi * 16 + sub * 4 + r;
                int toff = (rl_ * 256 + col * 2) ^ ((rl_ & 7) << 4);
                float tv = b2f(*(const ushort*)(tsc + toff));
                float v = fmaxf(omb * tv + beta * acc[mi][r], 0.0f);
                xout[(size_t)(rowbase + rl_) * HH + col] = f2bf(v);
            }
    } else {
        __syncthreads();
        #pragma unroll
        for (int mi = 0; mi < 2; mi++)
            #pragma unroll
            for (int r = 0; r < 4; r++) {
                int rl_ = mi * 16 + sub * 4 + r;
                int toff = (rl_ * 256 + col * 2) ^ ((rl_ & 7) << 4);
                ushort* slot = (ushort*)((char*)ts + toff);
                float tv = b2f(*slot);
                float v = fmaxf(omb * tv + beta * acc[mi][r], 0.0f);
                *slot = f2bf(v);
            }
        __syncthreads();
        if (wv < 3) {
            float4v a2[2] = {};
            #pragma unroll
            for (int ks = 0; ks < 4; ks++) {
                short8v a0 = *(const short8v*)(tsc + ((r16 * 256 + ks * 64 + sub * 16) ^ sw));
                short8v a1 = *(const short8v*)(tsc + (((16 + r16) * 256 + ks * 64 + sub * 16) ^ sw));
                short8v bb = *(const short8v*)(Wp1 + (ks * 4 + sub) * 384 + (wv * 16 + r16) * 8);
                a2[0] = __builtin_amdgcn_mfma_f32_16x16x32_bf16(a0, bb, a2[0], 0, 0, 0);
                a2[1] = __builtin_amdgcn_mfma_f32_16x16x32_bf16(a1, bb, a2[1], 0, 0, 0);
            }
            int col2 = wv * 16 + r16;
            if (col2 < CC) {
                float bias = b1[col2];
                #pragma unroll
                for (int mi = 0; mi < 2; mi++)
                    #pragma unroll
                    for (int r = 0; r < 4; r++) {
                        int row = rowbase + mi * 16 + sub * 4 + r;
                        out[(size_t)row * CC + col2] = a2[mi][r] + bias;
                    }
            }
        }
    }
}

extern "C" void kernel_launch(void* const* d_in, const int* in_sizes, int n_in,
                              void* d_out, int out_size, void* d_ws, size_t ws_size,
                              hipStream_t stream) {
    const float* x_in   = (const float*)d_in[0];
    const int*   ei     = (const int*)d_in[1];
    const float* ew     = (const float*)d_in[2];
    const int*   label  = (const int*)d_in[3];
    const float* p      = (const float*)d_in[4];
    const float* cm     = (const float*)d_in[5];
    const float* lin0_w = (const float*)d_in[6];
    const float* lin0_b = (const float*)d_in[7];
    const float* lin1_w = (const float*)d_in[8];
    const float* lin1_b = (const float*)d_in[9];
    const float* conv_w = (const float*)d_in[10];
    float* out = (float*)d_out;

    const int* src = ei;
    const int* dst = ei + EE;

    const size_t NH = (size_t)NN * HH;
    float* ws = (float*)d_ws;
    float* cnt   = ws;                       // 64
    float* sums0 = cnt + 64;                 // CC*HH
    float* sumsx = sums0 + CC * HH;          // CC*HH
    int*   deg    = (int*)(sumsx + CC * HH); // NN
    int*   rowptr = deg + NN;                // NN+1 (+pad)
    int*   bsum   = rowptr + NN + 64;        // 256
    int*   bcur   = bsum + 256;              // 512
    int*   lcnt   = bcur + 512;              // 64
    int*   lbase  = lcnt + 64;               // 64
    int*   gcur   = lbase + 64;              // 64
    int*   perm   = gcur + 64;               // NN
    int2*  csr    = (int2*)(perm + NN);      // EE
    int2*  stage  = csr + EE;                // EE
    ushort* x0b   = (ushort*)(stage + EE);   // NH bf16
    ushort* xbA   = x0b + NH;                // NH bf16
    ushort* xbB   = xbA + NH;                // NH bf16
    ushort* wp0   = xbB + NH;                // 16384
    ushort* wpc   = wp0 + 16384;             // 4*16384
    ushort* wp1   = wpc + 4 * 16384;         // 6144 (pad to 8192)
    ushort* rlp   = wp1 + 8192;              // 8192

    // ---- edge CSR build ----
    hipMemsetAsync(deg, 0, NN * sizeof(int), stream);
    hist_kernel<<<(EE + 255) / 256, 256, 0, stream>>>(dst, deg, EE);
    const int NBLK = (NN + 511) / 512;
    scan_block_kernel<<<NBLK, 256, 0, stream>>>(deg, rowptr, bsum, NN);
    scan_bsum_kernel<<<1, 256, 0, stream>>>(bsum, NBLK);
    add_off_kernel<<<(NN + 255) / 256, 256, 0, stream>>>(rowptr, bsum, NN);
    init_bcur_kernel<<<2, 256, 0, stream>>>(rowptr, bcur);
    coarse_fill_kernel<<<(EE + CHUNK - 1) / CHUNK, 256, 0, stream>>>(src, dst, ew, bcur, stage, EE);
    fine_fill_kernel<<<NB, 256, 0, stream>>>(stage, rowptr, csr, NN);

    // ---- label sort ----
    hipMemsetAsync(lcnt, 0, CC * sizeof(int), stream);
    lhist_kernel<<<256, 256, 0, stream>>>(label, lcnt, NN);
    lscan_kernel<<<1, 64, 0, stream>>>(lcnt, lbase, gcur, cnt);
    lfill_kernel<<<256, 256, 0, stream>>>(label, lbase, gcur, perm, NN);

    // ---- pack weights ----
    pack_w_kernel<<<64, 256, 0, stream>>>(lin0_w, wp0);
    for (int i = 0; i < 4; i++)
        pack_w_kernel<<<64, 256, 0, stream>>>(conv_w + (size_t)i * HH * HH, wpc + (size_t)i * 16384);
    pack_w1_kernel<<<24, 256, 0, stream>>>(lin1_w, wp1);
    hipMemsetAsync(rlp, 0, 8192 * sizeof(ushort), stream);  // zero-pad rows kk>=47 once

    // input linear + relu
    lin0_mfma_kernel<<<NN / 32, 256, 0, stream>>>(x_in, wp0, lin0_b, x0b, xbA);

    // sums0 = sum_label x0
    hipMemsetAsync(sums0, 0, CC * HH * sizeof(float), stream);
    psum_kernel<<<2048, 256, 0, stream>>>(x0b, perm, sums0, NN);

    const float betas[4] = {logf(0.5f / 1.0f + 1.0f), logf(0.5f / 2.0f + 1.0f),
                            logf(0.5f / 3.0f + 1.0f), logf(0.5f / 4.0f + 1.0f)};

    ushort* xin_b = xbA;
    ushort* xout_b = xbB;
    for (int i = 0; i < 4; i++) {
        if (i == 0) {
            cr_kernel<<<CC, 64, 0, stream>>>(sums0, sums0, cnt, cm, rlp);
        } else {
            hipMemsetAsync(sumsx, 0, CC * HH * sizeof(float), stream);
            psum_kernel<<<2048, 256, 0, stream>>>(xin_b, perm, sumsx, NN);
            cr_kernel<<<CC, 64, 0, stream>>>(sumsx, sums0, cnt, cm, rlp);
        }
        if (i < 3) {
            layer_kernel<0><<<NN / 32, 512, 0, stream>>>(xin_b, x0b, p, rlp, rowptr, csr,
                                                         wpc + (size_t)i * 16384, wp1, lin1_b,
                                                         xout_b, out, betas[i]);
            ushort* tmp = xin_b; xin_b = xout_b; xout_b = tmp;
        } else {
            layer_kernel<1><<<NN / 32, 512, 0, stream>>>(xin_b, x0b, p, rlp, rowptr, csr,
                                                         wpc + 3 * 16384, wp1, lin1_b,
                                                         xout_b, out, betas[3]);
        }
    }
}

// Round 11
// 527.162 us; speedup vs baseline: 5.9505x; 1.0586x over previous
//
#include <hip/hip_runtime.h>
#include <math.h>

#define NN 100000
#define EE 800000
#define CC 47
#define HH 128
#define NB 391      // node buckets of 256
#define CHUNK 2000  // edges per coarse block
#define CH (CC * HH)

typedef __attribute__((ext_vector_type(8))) short short8v;
typedef __attribute__((ext_vector_type(4))) float float4v;

__device__ inline ushort f2bf(float f) {
    unsigned u = __float_as_uint(f);
    unsigned r = (u + 0x7fffu + ((u >> 16) & 1u)) >> 16;  // RNE
    return (ushort)r;
}
__device__ inline float b2f(ushort u) { return __uint_as_float(((unsigned)u) << 16); }

// ---------------- one-shot zeroing of all accumulation buffers ----------------
__global__ __launch_bounds__(256) void zero_kernel(int* __restrict__ z, int n) {
    for (int i = blockIdx.x * 256 + threadIdx.x; i < n; i += gridDim.x * 256) z[i] = 0;
}

// ---------------- node-degree histogram + rowptr scan ----------------
__global__ __launch_bounds__(256) void hist_kernel(const int* __restrict__ dst,
                                                   int* __restrict__ deg, int e) {
    int i = blockIdx.x * 256 + threadIdx.x;
    if (i < e) atomicAdd(&deg[dst[i]], 1);
}

__global__ __launch_bounds__(256) void scan_block_kernel(const int* __restrict__ deg,
                                                         int* __restrict__ rowptr,
                                                         int* __restrict__ bsum, int n) {
    __shared__ int ls[256];
    int b = blockIdx.x, t = threadIdx.x;
    int i0 = b * 512 + 2 * t;
    int a0 = (i0 < n) ? deg[i0] : 0;
    int a1 = (i0 + 1 < n) ? deg[i0 + 1] : 0;
    int val = a0 + a1;
    ls[t] = val;
    __syncthreads();
    for (int off = 1; off < 256; off <<= 1) {
        int add = (t >= off) ? ls[t - off] : 0;
        __syncthreads();
        val += add;
        ls[t] = val;
        __syncthreads();
    }
    int incl1 = val;
    int incl0 = val - a1;
    if (i0 < n) rowptr[i0 + 1] = incl0;
    if (i0 + 1 < n) rowptr[i0 + 2] = incl1;
    if (t == 255) bsum[b] = val;
}

__global__ __launch_bounds__(256) void scan_bsum_kernel(int* __restrict__ bsum, int nb) {
    __shared__ int ls[256];
    int t = threadIdx.x;
    int v = (t < nb) ? bsum[t] : 0;
    int orig = v;
    ls[t] = v;
    __syncthreads();
    for (int off = 1; off < 256; off <<= 1) {
        int add = (t >= off) ? ls[t - off] : 0;
        __syncthreads();
        v += add;
        ls[t] = v;
        __syncthreads();
    }
    if (t < nb) bsum[t] = v - orig;
}

__global__ __launch_bounds__(256) void add_off_kernel(int* __restrict__ rowptr,
                                                      const int* __restrict__ bsum, int n) {
    int i = blockIdx.x * 256 + threadIdx.x;
    if (i < n) rowptr[i + 1] += bsum[i >> 9];
    if (i == 0) rowptr[0] = 0;
}

// ---------------- binned CSR fill ----------------
__global__ __launch_bounds__(256) void init_bcur_kernel(const int* __restrict__ rowptr,
                                                        int* __restrict__ bcur) {
    int b = blockIdx.x * 256 + threadIdx.x;
    if (b < 512) bcur[b] = rowptr[min(b * 256, NN)];
}

__global__ __launch_bounds__(256) void coarse_fill_kernel(const int* __restrict__ src,
                                                          const int* __restrict__ dst,
                                                          const float* __restrict__ ew,
                                                          int* __restrict__ bcur,
                                                          int2* __restrict__ stage, int e) {
    __shared__ int hist[512];
    __shared__ int base_local[512];
    __shared__ int gbase[512];
    __shared__ int lc[512];
    __shared__ int ls[256];
    __shared__ int2 le[CHUNK];
    __shared__ ushort lb[CHUNK];
    int t = threadIdx.x;
    int beg = blockIdx.x * CHUNK, end = min(e, beg + CHUNK);
    int cnt = end - beg;
    for (int i = t; i < 512; i += 256) { hist[i] = 0; lc[i] = 0; }
    __syncthreads();
    for (int i = beg + t; i < end; i += 256) atomicAdd(&hist[((unsigned)dst[i]) >> 8], 1);
    __syncthreads();
    int a0 = hist[2 * t], a1 = hist[2 * t + 1];
    int val = a0 + a1;
    ls[t] = val;
    __syncthreads();
    for (int off = 1; off < 256; off <<= 1) {
        int add = (t >= off) ? ls[t - off] : 0;
        __syncthreads();
        val += add;
        ls[t] = val;
        __syncthreads();
    }
    base_local[2 * t] = val - a0 - a1;
    base_local[2 * t + 1] = val - a1;
    __syncthreads();
    for (int b = t; b < 512; b += 256)
        if (hist[b] > 0) gbase[b] = atomicAdd(&bcur[b], hist[b]);
    __syncthreads();
    for (int i = beg + t; i < end; i += 256) {
        int d = dst[i];
        int bk = ((unsigned)d) >> 8;
        int slot = base_local[bk] + atomicAdd(&lc[bk], 1);
        le[slot] = make_int2(((d & 255) << 24) | src[i], __float_as_int(ew[i]));
        lb[slot] = (ushort)bk;
    }
    __syncthreads();
    for (int s = t; s < cnt; s += 256) {
        int bk = lb[s];
        stage[gbase[bk] + (s - base_local[bk])] = le[s];
    }
}

__global__ __launch_bounds__(256) void fine_fill_kernel(const int2* __restrict__ stage,
                                                        const int* __restrict__ rowptr,
                                                        int2* __restrict__ csr, int n) {
    __shared__ int cur[256];
    __shared__ int rp[257];
    int b = blockIdx.x, t = threadIdx.x;
    int node0 = b * 256;
    int nodes = min(256, n - node0);
    cur[t] = 0;
    rp[t] = rowptr[min(node0 + t, n)];
    if (t == 0) rp[256] = rowptr[min(node0 + 256, n)];
    __syncthreads();
    int S = rp[0], E = rp[nodes];
    for (int i = S + t; i < E; i += 256) {
        int2 en = stage[i];
        int dl = ((unsigned)en.x) >> 24;
        int pos = rp[dl] + atomicAdd(&cur[dl], 1);
        csr[pos] = make_int2(en.x & 0xFFFFFF, en.y);
    }
}

// ---------------- label sort (once) ----------------
__global__ __launch_bounds__(256) void lhist_kernel(const int* __restrict__ label,
                                                    int* __restrict__ lcnt, int n) {
    __shared__ int lh[CC];
    if (threadIdx.x < CC) lh[threadIdx.x] = 0;
    __syncthreads();
    for (int i = blockIdx.x * 256 + threadIdx.x; i < n; i += gridDim.x * 256)
        atomicAdd(&lh[label[i]], 1);
    __syncthreads();
    if (threadIdx.x < CC) atomicAdd(&lcnt[threadIdx.x], lh[threadIdx.x]);
}

__global__ __launch_bounds__(64) void lscan_kernel(const int* __restrict__ lcnt,
                                                   int* __restrict__ lbase,
                                                   int* __restrict__ gcur,
                                                   float* __restrict__ cntf) {
    __shared__ int ls[CC];
    int t = threadIdx.x;
    if (t < CC) {
        int v = lcnt[t];
        cntf[t] = (float)v;
        gcur[t] = 0;
        ls[t] = v;
    }
    __syncthreads();
    if (t == 0) {
        int run = 0;
        for (int c = 0; c < CC; c++) { int x = ls[c]; ls[c] = run; run += x; }
    }
    __syncthreads();
    if (t < CC) lbase[t] = ls[t];
}

__global__ __launch_bounds__(256) void lfill_kernel(const int* __restrict__ label,
                                                    const int* __restrict__ lbase,
                                                    int* __restrict__ gcur,
                                                    int* __restrict__ perm, int n) {
    __shared__ int lh[CC], lbs[CC], lc[CC];
    int t = threadIdx.x;
    if (t < CC) lh[t] = 0;
    __syncthreads();
    int chunk = (n + gridDim.x - 1) / gridDim.x;
    int beg = blockIdx.x * chunk, end = min(n, beg + chunk);
    for (int i = beg + t; i < end; i += 256) atomicAdd(&lh[label[i]], 1);
    __syncthreads();
    if (t < CC) {
        lbs[t] = (lh[t] > 0) ? atomicAdd(&gcur[t], lh[t]) : 0;
        lc[t] = 0;
    }
    __syncthreads();
    for (int i = beg + t; i < end; i += 256) {
        int c = label[i];
        int pos = atomicAdd(&lc[c], 1);
        perm[lbase[c] + lbs[c] + pos] = (c << 24) | i;
    }
}

// ---------------- segment sums via sorted perm ----------------
__global__ __launch_bounds__(256) void psum_kernel(const ushort* __restrict__ xb,
                                                   const int* __restrict__ perm,
                                                   float* __restrict__ sums, int n) {
    const int lane = threadIdx.x & 63;
    const int wid = threadIdx.x >> 6;
    int gw = blockIdx.x * 4 + wid;
    int nw = gridDim.x * 4;
    int per = (n + nw - 1) / nw;
    int beg = gw * per, end = min(n, beg + per);
    if (beg >= end) return;
    float ax = 0.0f, ay = 0.0f;
    int ccur = __builtin_amdgcn_readfirstlane(perm[beg]) >> 24;
    int i = beg;
    while (i < end) {
        if (i + 4 <= end) {
            int p0 = __builtin_amdgcn_readfirstlane(perm[i]);
            int p1 = __builtin_amdgcn_readfirstlane(perm[i + 1]);
            int p2 = __builtin_amdgcn_readfirstlane(perm[i + 2]);
            int p3 = __builtin_amdgcn_readfirstlane(perm[i + 3]);
            if ((p0 >> 24) == (p3 >> 24)) {
                int c = p0 >> 24;
                if (c != ccur) {
                    atomicAdd(&sums[ccur * HH + 2 * lane], ax);
                    atomicAdd(&sums[ccur * HH + 2 * lane + 1], ay);
                    ax = ay = 0.0f;
                    ccur = c;
                }
                ushort2 v0 = *(const ushort2*)(xb + (size_t)(p0 & 0xFFFFFF) * HH + 2 * lane);
                ushort2 v1 = *(const ushort2*)(xb + (size_t)(p1 & 0xFFFFFF) * HH + 2 * lane);
                ushort2 v2 = *(const ushort2*)(xb + (size_t)(p2 & 0xFFFFFF) * HH + 2 * lane);
                ushort2 v3 = *(const ushort2*)(xb + (size_t)(p3 & 0xFFFFFF) * HH + 2 * lane);
                ax += b2f(v0.x) + b2f(v1.x) + b2f(v2.x) + b2f(v3.x);
                ay += b2f(v0.y) + b2f(v1.y) + b2f(v2.y) + b2f(v3.y);
                i += 4;
                continue;
            }
        }
        int pe = __builtin_amdgcn_readfirstlane(perm[i]);
        int c = pe >> 24;
        if (c != ccur) {
            atomicAdd(&sums[ccur * HH + 2 * lane], ax);
            atomicAdd(&sums[ccur * HH + 2 * lane + 1], ay);
            ax = ay = 0.0f;
            ccur = c;
        }
        ushort2 v = *(const ushort2*)(xb + (size_t)(pe & 0xFFFFFF) * HH + 2 * lane);
        ax += b2f(v.x);
        ay += b2f(v.y);
        i += 1;
    }
    atomicAdd(&sums[ccur * HH + 2 * lane], ax);
    atomicAdd(&sums[ccur * HH + 2 * lane + 1], ay);
}

// ---------------- pack all weights in one launch ----------------
// layout: idx<5*16384 -> lin0_w / conv_w[m-1] into wp0/wpc; else W1 into wp1
__global__ __launch_bounds__(256) void pack_all_kernel(const float* __restrict__ lin0_w,
                                                       const float* __restrict__ conv_w,
                                                       const float* __restrict__ W1,
                                                       ushort* __restrict__ wp0,
                                                       ushort* __restrict__ wpc,
                                                       ushort* __restrict__ wp1) {
    int idx = blockIdx.x * 256 + threadIdx.x;
    if (idx < 5 * 16384) {
        int m = idx >> 14;
        int r = idx & 16383;
        int k = r >> 7, c = r & 127;
        const float* W = (m == 0) ? lin0_w : conv_w + (size_t)(m - 1) * 16384;
        ushort* Wp = (m == 0) ? wp0 : wpc + (size_t)(m - 1) * 16384;
        Wp[(k >> 3) * 1024 + c * 8 + (k & 7)] = f2bf(W[r]);
    } else {
        int j = idx - 5 * 16384;
        if (j < 6144) {
            int ksub = j / 384, rem = j - ksub * 384;
            int c = rem >> 3, kk = ksub * 8 + (rem & 7);
            wp1[j] = (c < CC) ? f2bf(W1[kk * CC + c]) : (ushort)0;
        }
    }
}

// ---------------- lin0 (B-frags from L2, no LDS weight staging) ----------------
__global__ __launch_bounds__(256) void lin0_mfma_kernel(const float* __restrict__ xin,
                                                        const ushort* __restrict__ Wp,
                                                        const float* __restrict__ bias,
                                                        ushort* __restrict__ x0b,
                                                        ushort* __restrict__ xb) {
    __shared__ ushort ts[32 * 128];
    const int lane = threadIdx.x & 63, wv = threadIdx.x >> 6;
    const int sub = lane >> 4, r16 = lane & 15;
    const int wbase = wv * 32;
    const int rowbase = blockIdx.x * 32;
    const float* tp = xin + (size_t)rowbase * HH;
    #pragma unroll
    for (int j = 0; j < 4; j++) {
        int e = 4 * threadIdx.x + j * 1024;
        float4 f = *(const float4*)(tp + e);
        int r = e >> 7, c = e & 127;
        ushort4 b4 = make_ushort4(f2bf(f.x), f2bf(f.y), f2bf(f.z), f2bf(f.w));
        int off = (r * 256 + c * 2) ^ ((r & 7) << 4);
        *(ushort4*)((char*)ts + off) = b4;
    }
    __syncthreads();
    float4v acc[2][2] = {};
    {
        const char* tsc = (const char*)ts;
        const int sw = (r16 & 7) << 4;
        #pragma unroll
        for (int ks = 0; ks < 4; ks++) {
            short8v a0 = *(const short8v*)(tsc + ((r16 * 256 + ks * 64 + sub * 16) ^ sw));
            short8v a1 = *(const short8v*)(tsc + (((16 + r16) * 256 + ks * 64 + sub * 16) ^ sw));
            int kb = (ks * 4 + sub) * 1024;
            short8v b0 = *(const short8v*)(Wp + kb + (wbase + r16) * 8);
            short8v b1 = *(const short8v*)(Wp + kb + (wbase + 16 + r16) * 8);
            acc[0][0] = __builtin_amdgcn_mfma_f32_16x16x32_bf16(a0, b0, acc[0][0], 0, 0, 0);
            acc[0][1] = __builtin_amdgcn_mfma_f32_16x16x32_bf16(a0, b1, acc[0][1], 0, 0, 0);
            acc[1][0] = __builtin_amdgcn_mfma_f32_16x16x32_bf16(a1, b0, acc[1][0], 0, 0, 0);
            acc[1][1] = __builtin_amdgcn_mfma_f32_16x16x32_bf16(a1, b1, acc[1][1], 0, 0, 0);
        }
    }
    float bv[2] = {bias[wbase + r16], bias[wbase + 16 + r16]};
    #pragma unroll
    for (int mi = 0; mi < 2; mi++)
        #pragma unroll
        for (int ni = 0; ni < 2; ni++) {
            int col = wbase + ni * 16 + r16;
            #pragma unroll
            for (int r = 0; r < 4; r++) {
                int row = rowbase + mi * 16 + sub * 4 + r;
                float v = fmaxf(acc[mi][ni][r] + bv[ni], 0.0f);
                ushort bv16 = f2bf(v);
                x0b[(size_t)row * HH + col] = bv16;
                xb[(size_t)row * HH + col] = bv16;
            }
        }
}

// ---------------- fused centers + rcm + pack: one block per class ----------------
__global__ __launch_bounds__(64) void cr_kernel(const float* __restrict__ sumsx,
                                                const float* __restrict__ sums0,
                                                const float* __restrict__ cnt,
                                                const float* __restrict__ cm,
                                                ushort* __restrict__ rlp) {
    __shared__ float cs[CC * HH];
    int i = blockIdx.x, lane = threadIdx.x;
    for (int idx = lane; idx < CC * HH; idx += 64) {
        int c = idx >> 7;
        cs[idx] = (sumsx[idx] + 0.1f * sums0[idx]) / fmaxf(cnt[c], 1.0f);
    }
    __syncthreads();
    float ci0 = cs[i * HH + lane];
    float ci1 = cs[i * HH + 64 + lane];
    float acc0 = 0.0f, acc1 = 0.0f;
    for (int j = 0; j < CC; j++) {
        float d0 = ci0 - cs[j * HH + lane];
        float d1 = ci1 - cs[j * HH + 64 + lane];
        float s = d0 * d0 + d1 * d1;
        #pragma unroll
        for (int off = 32; off >= 1; off >>= 1) s += __shfl_xor(s, off);
        float nrm = sqrtf(s);
        if (nrm == 0.0f) nrm = 1.0f;
        float w = cm[i * CC + j] / nrm;
        acc0 = fmaf(w, d0, acc0);
        acc1 = fmaf(w, d1, acc1);
    }
    rlp[(i >> 3) * 1024 + lane * 8 + (i & 7)] = f2bf(acc0);
    rlp[(i >> 3) * 1024 + (lane + 64) * 8 + (i & 7)] = f2bf(acc1);
}

// ---------------- fused layer: pr MFMA + edge-stream gather/combine + conv MFMA ----------------
template <int FINAL>
__global__ __launch_bounds__(512, 8) void layer_kernel(
    const ushort* __restrict__ xin, const ushort* __restrict__ x0b,
    const float* __restrict__ p, const ushort* __restrict__ rlp,
    const int* __restrict__ rowptr, const int2* __restrict__ csr,
    const ushort* __restrict__ Wp,
    const ushort* __restrict__ Wp1, const float* __restrict__ b1,
    ushort* __restrict__ xout, float* __restrict__ out, float beta) {
    __shared__ ushort ts[32 * 128];   // combined-t tile (swizzled)
    __shared__ ushort ps[32 * 64];    // p A-tile (K padded to 64)
    __shared__ ushort prs[32 * 128];  // pr result tile (swizzled)
    const int lane = threadIdx.x & 63;
    const int wv = __builtin_amdgcn_readfirstlane(threadIdx.x >> 6);
    const int rowbase = blockIdx.x * 32;
    const int sub = lane >> 4, r16 = lane & 15;
    const int sw = (r16 & 7) << 4;
    // ---- stage p A-tile ----
    if (threadIdx.x < 256) {
        int t = threadIdx.x;
        int r = t >> 3, kc = (t & 7) * 8;
        const float* prow = p + (size_t)(rowbase + r) * CC;
        short8v v;
        #pragma unroll
        for (int j = 0; j < 8; j++) {
            int k = kc + j;
            v[j] = (short)((k < CC) ? f2bf(prow[k]) : (ushort)0);
        }
        int off = (r * 128 + kc * 2) ^ ((r & 7) << 4);
        *(short8v*)((char*)ps + off) = v;
    }
    __syncthreads();
    // ---- pr MFMA ----
    {
        const char* psc = (const char*)ps;
        float4v pacc[2] = {};
        #pragma unroll
        for (int ks = 0; ks < 2; ks++) {
            short8v a0 = *(const short8v*)(psc + ((r16 * 128 + ks * 64 + sub * 16) ^ sw));
            short8v a1 = *(const short8v*)(psc + (((16 + r16) * 128 + ks * 64 + sub * 16) ^ sw));
            short8v bb = *(const short8v*)(rlp + (ks * 4 + sub) * 1024 + (16 * wv + r16) * 8);
            pacc[0] = __builtin_amdgcn_mfma_f32_16x16x32_bf16(a0, bb, pacc[0], 0, 0, 0);
            pacc[1] = __builtin_amdgcn_mfma_f32_16x16x32_bf16(a1, bb, pacc[1], 0, 0, 0);
        }
        int col = 16 * wv + r16;
        #pragma unroll
        for (int mi = 0; mi < 2; mi++)
            #pragma unroll
            for (int r = 0; r < 4; r++) {
                int rl_ = mi * 16 + sub * 4 + r;
                *(ushort*)((char*)prs + ((rl_ * 256 + col * 2) ^ ((rl_ & 7) << 4))) =
                    f2bf(pacc[mi][r]);
            }
    }
    __syncthreads();
    // ---- edge-stream gather over the wave's contiguous CSR span [rp0, rp4) ----
    const int nn0 = rowbase + 4 * wv;
    int rp0 = __builtin_amdgcn_readfirstlane(rowptr[nn0]);
    int rp1 = __builtin_amdgcn_readfirstlane(rowptr[nn0 + 1]);
    int rp2 = __builtin_amdgcn_readfirstlane(rowptr[nn0 + 2]);
    int rp3 = __builtin_amdgcn_readfirstlane(rowptr[nn0 + 3]);
    int rp4 = __builtin_amdgcn_readfirstlane(rowptr[nn0 + 4]);
    float ax0 = 0, ay0 = 0, ax1 = 0, ay1 = 0, ax2 = 0, ay2 = 0, ax3 = 0, ay3 = 0;
#define ACC_EDGE(IDX, W, FX, FY)                                          \
    if ((IDX) < rp1) { ax0 = fmaf(W, FX, ax0); ay0 = fmaf(W, FY, ay0); }  \
    else if ((IDX) < rp2) { ax1 = fmaf(W, FX, ax1); ay1 = fmaf(W, FY, ay1); } \
    else if ((IDX) < rp3) { ax2 = fmaf(W, FX, ax2); ay2 = fmaf(W, FY, ay2); } \
    else { ax3 = fmaf(W, FX, ax3); ay3 = fmaf(W, FY, ay3); }
    int e2 = rp0;
    for (; e2 + 8 <= rp4; e2 += 8) {
        int2 ed[8];
        #pragma unroll
        for (int u = 0; u < 8; u++) ed[u] = csr[e2 + u];
        ushort2 vv[8];
        #pragma unroll
        for (int u = 0; u < 8; u++)
            vv[u] = *(const ushort2*)(xin + (size_t)ed[u].x * HH + 2 * lane);
        #pragma unroll
        for (int u = 0; u < 8; u++) {
            float w = __int_as_float(ed[u].y);
            float fx = b2f(vv[u].x), fy = b2f(vv[u].y);
            ACC_EDGE(e2 + u, w, fx, fy)
        }
    }
    for (; e2 < rp4; e2++) {
        int2 ed = csr[e2];
        ushort2 v = *(const ushort2*)(xin + (size_t)ed.x * HH + 2 * lane);
        float w = __int_as_float(ed.y);
        float fx = b2f(v.x), fy = b2f(v.y);
        ACC_EDGE(e2, w, fx, fy)
    }
#undef ACC_EDGE
    // ---- combine -> ts ----
    {
        float axs[4] = {ax0, ax1, ax2, ax3};
        float ays[4] = {ay0, ay1, ay2, ay3};
        #pragma unroll
        for (int k = 0; k < 4; k++) {
            int rloc = 4 * wv + k;
            int nn = nn0 + k;
            int poff = (rloc * 256 + lane * 4) ^ ((rloc & 7) << 4);
            ushort2 pv = *(const ushort2*)((const char*)prs + poff);
            ushort2 xc = *(const ushort2*)(xin + (size_t)nn * HH + 2 * lane);
            ushort2 xo = *(const ushort2*)(x0b + (size_t)nn * HH + 2 * lane);
            ushort2 o;
            o.x = f2bf(0.45f * b2f(xc.x) + 0.45f * b2f(pv.x) + 0.45f * axs[k] + 0.1f * b2f(xo.x));
            o.y = f2bf(0.45f * b2f(xc.y) + 0.45f * b2f(pv.y) + 0.45f * ays[k] + 0.1f * b2f(xo.y));
            *(ushort2*)((char*)ts + poff) = o;
        }
    }
    __syncthreads();
    // ---- conv MFMA: wave wv owns cols [16wv,16wv+16); B-frags from L2 ----
    const char* tsc = (const char*)ts;
    float4v acc[2] = {};
    #pragma unroll
    for (int ks = 0; ks < 4; ks++) {
        short8v a0 = *(const short8v*)(tsc + ((r16 * 256 + ks * 64 + sub * 16) ^ sw));
        short8v a1 = *(const short8v*)(tsc + (((16 + r16) * 256 + ks * 64 + sub * 16) ^ sw));
        short8v bb = *(const short8v*)(Wp + (ks * 4 + sub) * 1024 + (16 * wv + r16) * 8);
        acc[0] = __builtin_amdgcn_mfma_f32_16x16x32_bf16(a0, bb, acc[0], 0, 0, 0);
        acc[1] = __builtin_amdgcn_mfma_f32_16x16x32_bf16(a1, bb, acc[1], 0, 0, 0);
    }
    const float omb = 1.0f - beta;
    const int col = 16 * wv + r16;
    if constexpr (!FINAL) {
        #pragma unroll
        for (int mi = 0; mi < 2; mi++)
            #pragma unroll
            for (int r = 0; r < 4; r++) {
                int rl_ = mi * 16 + sub * 4 + r;
                int toff = (rl_ * 256 + col * 2) ^ ((rl_ & 7) << 4);
                float tv = b2f(*(const ushort*)(tsc + toff));
                float v = fmaxf(omb * tv + beta * acc[mi][r], 0.0f);
                xout[(size_t)(rowbase + rl_) * HH + col] = f2bf(v);
            }
    } else {
        __syncthreads();
        #pragma unroll
        for (int mi = 0; mi < 2; mi++)
            #pragma unroll
            for (int r = 0; r < 4; r++) {
                int rl_ = mi * 16 + sub * 4 + r;
                int toff = (rl_ * 256 + col * 2) ^ ((rl_ & 7) << 4);
                ushort* slot = (ushort*)((char*)ts + toff);
                float tv = b2f(*slot);
                float v = fmaxf(omb * tv + beta * acc[mi][r], 0.0f);
                *slot = f2bf(v);
            }
        __syncthreads();
        if (wv < 3) {
            float4v a2[2] = {};
            #pragma unroll
            for (int ks = 0; ks < 4; ks++) {
                short8v a0 = *(const short8v*)(tsc + ((r16 * 256 + ks * 64 + sub * 16) ^ sw));
                short8v a1 = *(const short8v*)(tsc + (((16 + r16) * 256 + ks * 64 + sub * 16) ^ sw));
                short8v bb = *(const short8v*)(Wp1 + (ks * 4 + sub) * 384 + (wv * 16 + r16) * 8);
                a2[0] = __builtin_amdgcn_mfma_f32_16x16x32_bf16(a0, bb, a2[0], 0, 0, 0);
                a2[1] = __builtin_amdgcn_mfma_f32_16x16x32_bf16(a1, bb, a2[1], 0, 0, 0);
            }
            int col2 = wv * 16 + r16;
            if (col2 < CC) {
                float bias = b1[col2];
                #pragma unroll
                for (int mi = 0; mi < 2; mi++)
                    #pragma unroll
                    for (int r = 0; r < 4; r++) {
                        int row = rowbase + mi * 16 + sub * 4 + r;
                        out[(size_t)row * CC + col2] = a2[mi][r] + bias;
                    }
            }
        }
    }
}

extern "C" void kernel_launch(void* const* d_in, const int* in_sizes, int n_in,
                              void* d_out, int out_size, void* d_ws, size_t ws_size,
                              hipStream_t stream) {
    const float* x_in   = (const float*)d_in[0];
    const int*   ei     = (const int*)d_in[1];
    const float* ew     = (const float*)d_in[2];
    const int*   label  = (const int*)d_in[3];
    const float* p      = (const float*)d_in[4];
    const float* cm     = (const float*)d_in[5];
    const float* lin0_w = (const float*)d_in[6];
    const float* lin0_b = (const float*)d_in[7];
    const float* lin1_w = (const float*)d_in[8];
    const float* lin1_b = (const float*)d_in[9];
    const float* conv_w = (const float*)d_in[10];
    float* out = (float*)d_out;

    const int* src = ei;
    const int* dst = ei + EE;

    const size_t NH = (size_t)NN * HH;
    float* ws = (float*)d_ws;
    // ---- zero zone (contiguous): sums0, sumsxs[3], rlp, deg, lcnt ----
    float* sums0  = ws;                        // CH
    float* sumsxs = sums0 + CH;                // 3*CH
    ushort* rlp   = (ushort*)(sumsxs + 3 * CH);// 8192 ushorts = 4096 f32
    int*   deg    = (int*)(rlp + 8192);        // NN
    int*   lcnt   = deg + NN;                  // 64
    const int ZTOT = CH + 3 * CH + 4096 + NN + 64;
    // ---- rest ----
    float* cnt    = (float*)(lcnt + 64);       // 64
    int*   rowptr = (int*)(cnt + 64);          // NN+1 (+pad)
    int*   bsum   = rowptr + NN + 64;          // 256
    int*   bcur   = bsum + 256;                // 512
    int*   lbase  = bcur + 512;                // 64
    int*   gcur   = lbase + 64;                // 64
    int*   perm   = gcur + 64;                 // NN
    int2*  csr    = (int2*)(perm + NN);        // EE
    int2*  stage  = csr + EE;                  // EE
    ushort* x0b   = (ushort*)(stage + EE);     // NH bf16
    ushort* xbA   = x0b + NH;                  // NH bf16
    ushort* xbB   = xbA + NH;                  // NH bf16
    ushort* wp0   = xbB + NH;                  // 16384
    ushort* wpc   = wp0 + 16384;               // 4*16384
    ushort* wp1   = wpc + 4 * 16384;           // 6144 (pad to 8192)

    // ---- zero all accumulation buffers in one launch ----
    zero_kernel<<<512, 256, 0, stream>>>((int*)ws, ZTOT);

    // ---- edge CSR build ----
    hist_kernel<<<(EE + 255) / 256, 256, 0, stream>>>(dst, deg, EE);
    const int NBLK = (NN + 511) / 512;
    scan_block_kernel<<<NBLK, 256, 0, stream>>>(deg, rowptr, bsum, NN);
    scan_bsum_kernel<<<1, 256, 0, stream>>>(bsum, NBLK);
    add_off_kernel<<<(NN + 255) / 256, 256, 0, stream>>>(rowptr, bsum, NN);
    init_bcur_kernel<<<2, 256, 0, stream>>>(rowptr, bcur);
    coarse_fill_kernel<<<(EE + CHUNK - 1) / CHUNK, 256, 0, stream>>>(src, dst, ew, bcur, stage, EE);
    fine_fill_kernel<<<NB, 256, 0, stream>>>(stage, rowptr, csr, NN);

    // ---- label sort ----
    lhist_kernel<<<256, 256, 0, stream>>>(label, lcnt, NN);
    lscan_kernel<<<1, 64, 0, stream>>>(lcnt, lbase, gcur, cnt);
    lfill_kernel<<<256, 256, 0, stream>>>(label, lbase, gcur, perm, NN);

    // ---- pack all weights ----
    pack_all_kernel<<<(5 * 16384 + 6144 + 255) / 256, 256, 0, stream>>>(
        lin0_w, conv_w, lin1_w, wp0, wpc, wp1);

    // input linear + relu
    lin0_mfma_kernel<<<NN / 32, 256, 0, stream>>>(x_in, wp0, lin0_b, x0b, xbA);

    // sums0 = sum_label x0
    psum_kernel<<<2048, 256, 0, stream>>>(x0b, perm, sums0, NN);

    const float betas[4] = {logf(0.5f / 1.0f + 1.0f), logf(0.5f / 2.0f + 1.0f),
                            logf(0.5f / 3.0f + 1.0f), logf(0.5f / 4.0f + 1.0f)};

    ushort* xin_b = xbA;
    ushort* xout_b = xbB;
    for (int i = 0; i < 4; i++) {
        if (i == 0) {
            cr_kernel<<<CC, 64, 0, stream>>>(sums0, sums0, cnt, cm, rlp);
        } else {
            float* sx = sumsxs + (size_t)(i - 1) * CH;
            psum_kernel<<<2048, 256, 0, stream>>>(xin_b, perm, sx, NN);
            cr_kernel<<<CC, 64, 0, stream>>>(sx, sums0, cnt, cm, rlp);
        }
        if (i < 3) {
            layer_kernel<0><<<NN / 32, 512, 0, stream>>>(xin_b, x0b, p, rlp, rowptr, csr,
                                                         wpc + (size_t)i * 16384, wp1, lin1_b,
                                                         xout_b, out, betas[i]);
            ushort* tmp = xin_b; xin_b = xout_b; xout_b = tmp;
        } else {
            layer_kernel<1><<<NN / 32, 512, 0, stream>>>(xin_b, x0b, p, rlp, rowptr, csr,
                                                         wpc + 3 * 16384, wp1, lin1_b,
                                                         xout_b, out, betas[3]);
        }
    }
}